// Round 1
// baseline (206.828 us; speedup 1.0000x reference)
//
#include <hip/hip_runtime.h>
#include <math.h>

#define NB 2
#define NPTS 4096
#define NQ 16384
#define QTOT (NB * NQ)   // 32768 queries, batch folded into row index
#define FCATC 448        // 64+128+256 concatenated feature channels per point

typedef _Float16 h8 __attribute__((ext_vector_type(8)));
typedef float v4f __attribute__((ext_vector_type(4)));

// ---------------- k_pre: weight casts + GM zero ----------------
__global__ __launch_bounds__(256) void k_pre(
        const float* __restrict__ r1, const float* __restrict__ r2,
        const float* __restrict__ r3, const float* __restrict__ w2,
        const float* __restrict__ w3,
        _Float16* __restrict__ Rw1, _Float16* __restrict__ Rw2,
        _Float16* __restrict__ Rw3, _Float16* __restrict__ Ew2,
        _Float16* __restrict__ Ew3, float* __restrict__ GM) {
    int blk = blockIdx.x;
    int t = threadIdx.x;
    if (blk < 768) {
        int g = blk * 256 + t;
        if (g < 114688) {                       // Rw1 = r1[:,3:451] (256 x 448)
            int o = g / FCATC, k = g - o * FCATC;
            Rw1[g] = (_Float16)r1[(size_t)o * 707 + 3 + k];
        } else if (g < 147456) {                // Rw2 = r2 (128x256)
            int i = g - 114688;
            Rw2[i] = (_Float16)r2[i];
        } else if (g < 155648) {                // Rw3 = r3 (64x128)
            int i = g - 147456;
            Rw3[i] = (_Float16)r3[i];
        } else if (g < 163840) {                // Ew2 = w2 (128x64)
            int i = g - 155648;
            Ew2[i] = (_Float16)w2[i];
        } else {                                // Ew3 = w3 (256x128)
            int i = g - 163840;
            Ew3[i] = (_Float16)w3[i];
        }
    } else {
        GM[t] = 0.f;
        GM[256 + t] = 0.f;
    }
}

// ---------------- k_fe: fused l1 + l2 + l3 + global-max, 128 points/block ----------------
// Writes Fcat[pt][0:448] fp16 and per-channel max of f3 into GM (atomic).
__global__ __launch_bounds__(256) void k_fe(const float* __restrict__ pts,
        const float* __restrict__ w1, const float* __restrict__ b1,
        const _Float16* __restrict__ Ew2, const float* __restrict__ b2,
        const _Float16* __restrict__ Ew3, const float* __restrict__ b3,
        _Float16* __restrict__ Fcat, unsigned* __restrict__ GM) {
    __shared__ __align__(16) unsigned char arena[81920];
    _Float16* sF1  = (_Float16*)arena;            // [128][72]  = 18432 B
    _Float16* sF2  = (_Float16*)(arena + 18432);  // [128][136] = 34816 B
    _Float16* sBst = (_Float16*)(arena + 53248);  // up to [256][56] = 28672 B
    __shared__ float sW1[192];
    __shared__ float sB1[64];
    __shared__ unsigned smax[256];
    int t = threadIdx.x;
    int w = t >> 6, lane = t & 63;
    int m = lane & 15, quad = lane >> 4;
    int wq = w & 1, wn = w >> 1;
    int P0 = blockIdx.x * 128;          // global point row
    int bb = P0 >> 12;
    int p0in = P0 & (NPTS - 1);

    if (t < 192) sW1[t] = w1[t];
    if (t < 64)  sB1[t] = b1[t];
    smax[t] = 0u;
    __syncthreads();

    // ---- l1: f1 = relu(W1 @ pts + b1) -> sF1 + Fcat[:,0:64] ----
    {
        int pt = t >> 1;
        int cs = (t & 1) * 32;
        const float* pb = pts + (size_t)bb * 3 * NPTS + p0in;
        float px = pb[pt], py = pb[NPTS + pt], pz = pb[2 * NPTS + pt];
        _Float16* fcrow = Fcat + (size_t)(P0 + pt) * FCATC;
        #pragma unroll 8
        for (int c = cs; c < cs + 32; c++) {
            float v = fmaf(sW1[c*3+0], px,
                      fmaf(sW1[c*3+1], py,
                      fmaf(sW1[c*3+2], pz, sB1[c])));
            _Float16 h = (_Float16)fmaxf(v, 0.f);
            sF1[pt * 72 + c] = h;
            fcrow[c] = h;
        }
    }

    // ---- l2: f2(128pt x 128ch) = relu(Ew2 @ f1 + b2) -> sF2 + Fcat[:,64:192] ----
    {
        v4f acc[4][4];
        #pragma unroll
        for (int i = 0; i < 4; i++)
            #pragma unroll
            for (int j = 0; j < 4; j++)
                acc[i][j] = (v4f){0.f, 0.f, 0.f, 0.f};
        for (int kc = 0; kc < 64; kc += 32) {
            __syncthreads();    // first iter: covers sF1 writes; later: sBst reuse
            {
                int idx = t + 0;        // 128 rows x 4 segs = 512; 2 per thread
                #pragma unroll
                for (int i = 0; i < 2; i++) {
                    int e = idx + i * 256;
                    int r = e >> 2, p = e & 3;
                    *(float4*)&sBst[r * 56 + p * 8] =
                        *(const float4*)&Ew2[(size_t)r * 64 + kc + p * 8];
                }
            }
            __syncthreads();
            h8 af[4], bf[4];
            #pragma unroll
            for (int mt = 0; mt < 4; mt++)
                af[mt] = *(const h8*)&sF1[(wq * 64 + mt * 16 + m) * 72 + kc + quad * 8];
            #pragma unroll
            for (int nt = 0; nt < 4; nt++)
                bf[nt] = *(const h8*)&sBst[(wn * 64 + nt * 16 + m) * 56 + quad * 8];
            #pragma unroll
            for (int mt = 0; mt < 4; mt++)
                #pragma unroll
                for (int nt = 0; nt < 4; nt++)
                    acc[mt][nt] = __builtin_amdgcn_mfma_f32_16x16x32_f16(
                            af[mt], bf[nt], acc[mt][nt], 0, 0, 0);
        }
        #pragma unroll
        for (int nt = 0; nt < 4; nt++) {
            int ch = wn * 64 + nt * 16 + m;
            float bb2 = b2[ch];
            #pragma unroll
            for (int mt = 0; mt < 4; mt++) {
                #pragma unroll
                for (int r = 0; r < 4; r++) {
                    int ptl = wq * 64 + mt * 16 + quad * 4 + r;
                    _Float16 h = (_Float16)fmaxf(acc[mt][nt][r] + bb2, 0.f);
                    sF2[ptl * 136 + ch] = h;
                    Fcat[(size_t)(P0 + ptl) * FCATC + 64 + ch] = h;
                }
            }
        }
    }

    // ---- l3: f3(128pt x 256ch) = relu(Ew3 @ f2 + b3) -> Fcat[:,192:448] + max ----
    {
        v4f acc[4][8];
        #pragma unroll
        for (int i = 0; i < 4; i++)
            #pragma unroll
            for (int j = 0; j < 8; j++)
                acc[i][j] = (v4f){0.f, 0.f, 0.f, 0.f};
        for (int kc = 0; kc < 128; kc += 32) {
            __syncthreads();    // first iter: covers sF2 writes; later: sBst reuse
            {
                #pragma unroll
                for (int i = 0; i < 4; i++) {   // 256 rows x 4 segs = 1024; 4/thread
                    int e = t + i * 256;
                    int r = e >> 2, p = e & 3;
                    *(float4*)&sBst[r * 56 + p * 8] =
                        *(const float4*)&Ew3[(size_t)r * 128 + kc + p * 8];
                }
            }
            __syncthreads();
            h8 af[4], bf[8];
            #pragma unroll
            for (int mt = 0; mt < 4; mt++)
                af[mt] = *(const h8*)&sF2[(wq * 64 + mt * 16 + m) * 136 + kc + quad * 8];
            #pragma unroll
            for (int nt = 0; nt < 8; nt++)
                bf[nt] = *(const h8*)&sBst[(wn * 128 + nt * 16 + m) * 56 + quad * 8];
            #pragma unroll
            for (int mt = 0; mt < 4; mt++)
                #pragma unroll
                for (int nt = 0; nt < 8; nt++)
                    acc[mt][nt] = __builtin_amdgcn_mfma_f32_16x16x32_f16(
                            af[mt], bf[nt], acc[mt][nt], 0, 0, 0);
        }
        #pragma unroll
        for (int nt = 0; nt < 8; nt++) {
            int ch = wn * 128 + nt * 16 + m;
            float bb3 = b3[ch];
            float vmax = 0.f;
            #pragma unroll
            for (int mt = 0; mt < 4; mt++) {
                #pragma unroll
                for (int r = 0; r < 4; r++) {
                    int ptl = wq * 64 + mt * 16 + quad * 4 + r;
                    float v = fmaxf(acc[mt][nt][r] + bb3, 0.f);
                    vmax = fmaxf(vmax, v);
                    Fcat[(size_t)(P0 + ptl) * FCATC + 192 + ch] = (_Float16)v;
                }
            }
            atomicMax(&smax[ch], __float_as_uint(vmax));
        }
        __syncthreads();
        atomicMax(GM + bb * 256 + t, smax[t]);
    }
}

// ---------------- Generic fp16 MFMA GEMM (G precompute) + cb rider block ----------------
template<int KD, int WQ, int NCH>
__global__ __launch_bounds__(256, 3) void k_gemm(
        const _Float16* __restrict__ A, const _Float16* __restrict__ W,
        _Float16* __restrict__ Hout,
        const float* __restrict__ r1, const float* __restrict__ rb1,
        const float* __restrict__ gm, float* __restrict__ cb) {
    if (blockIdx.x == gridDim.x - 1) {
        // cb[b][o] = rb1[o] + r1[o,451:707] . gmax[b]
        int t = threadIdx.x;
        for (int b = 0; b < NB; b++) {
            const float* wrow = r1 + (size_t)t * 707 + 451;
            const float* g = gm + b * 256;
            float acc = rb1[t];
            #pragma unroll 8
            for (int c = 0; c < 256; c++) acc = fmaf(wrow[c], g[c], acc);
            cb[b * 256 + t] = acc;
        }
        return;
    }
    constexpr int QB = WQ * 64;
    __shared__ __align__(16) _Float16 sA[QB * 56];
    __shared__ __align__(16) _Float16 sB[NCH * 56];
    int t = threadIdx.x;
    int w = t >> 6, lane = t & 63;
    int m = lane & 15, quad = lane >> 4;
    int wq = w % WQ, wn = w / WQ;
    int q0 = blockIdx.x * QB;

    v4f acc[4][4];
    #pragma unroll
    for (int i = 0; i < 4; i++)
        #pragma unroll
        for (int j = 0; j < 4; j++)
            acc[i][j] = (v4f){0.f, 0.f, 0.f, 0.f};

    for (int kc = 0; kc < KD; kc += 32) {
        __syncthreads();
        #pragma unroll
        for (int i = 0; i < QB / 64; i++) {
            int idx = t + i * 256;
            int r = idx >> 2, p = idx & 3;
            *(float4*)&sA[r * 56 + p * 8] =
                *(const float4*)&A[(size_t)(q0 + r) * KD + kc + p * 8];
        }
        #pragma unroll
        for (int i = 0; i < NCH / 64; i++) {
            int idx = t + i * 256;
            int r = idx >> 2, p = idx & 3;
            *(float4*)&sB[r * 56 + p * 8] =
                *(const float4*)&W[(size_t)r * KD + kc + p * 8];
        }
        __syncthreads();
        h8 af[4], bf[4];
        #pragma unroll
        for (int mt = 0; mt < 4; mt++)
            af[mt] = *(const h8*)&sA[(wq * 64 + mt * 16 + m) * 56 + quad * 8];
        #pragma unroll
        for (int nt = 0; nt < 4; nt++)
            bf[nt] = *(const h8*)&sB[(wn * 64 + nt * 16 + m) * 56 + quad * 8];
        #pragma unroll
        for (int mt = 0; mt < 4; mt++)
            #pragma unroll
            for (int nt = 0; nt < 4; nt++)
                acc[mt][nt] = __builtin_amdgcn_mfma_f32_16x16x32_f16(
                        af[mt], bf[nt], acc[mt][nt], 0, 0, 0);
    }
    #pragma unroll
    for (int nt = 0; nt < 4; nt++) {
        int ch = wn * 64 + nt * 16 + m;
        #pragma unroll
        for (int mt = 0; mt < 4; mt++) {
            #pragma unroll
            for (int r = 0; r < 4; r++) {
                int q = q0 + wq * 64 + mt * 16 + quad * 4 + r;
                Hout[(size_t)q * NCH + ch] = (_Float16)acc[mt][nt][r];
            }
        }
    }
}

// ---------------- KNN: branchless top-3 via med3/cndmask ----------------
// sp holds (2x, 2y, 2z, o2). rn(qx*2px)=2*rn(qx*px) exactly (pow2 scaling
// commutes with round-to-nearest), so da = (q2+o2) - 2*cross is BIT-EXACT
// vs the previous formulation. Insertion uses strict < (scan in ascending
// index order => earlier index kept on ties), identical to the branchy chain.
__global__ __launch_bounds__(512) void k_knn(const float* __restrict__ opts,
        const float* __restrict__ qpts, int* __restrict__ knn_idx,
        float* __restrict__ knn_w) {
    __shared__ float4 sp[NPTS];       // 64 KB
    __shared__ float spd[3][8][64];
    __shared__ int   spi[3][8][64];
    int t = threadIdx.x;
    int b = blockIdx.x >> 8;
    int q0 = (blockIdx.x & 255) << 6;
    const float* ob = opts + b * 3 * NPTS;
    for (int i = t; i < NPTS; i += 512) {
        float x = ob[i], y = ob[NPTS + i], z = ob[2 * NPTS + i];
        float o2 = __fadd_rn(__fadd_rn(__fmul_rn(x, x), __fmul_rn(y, y)), __fmul_rn(z, z));
        sp[i] = make_float4(x + x, y + y, z + z, o2);   // doubled coords, exact
    }
    __syncthreads();
    int lane = t & 63;
    int w = t >> 6;
    int q = q0 + lane;
    float qx = qpts[b * 3 * NQ + q];
    float qy = qpts[b * 3 * NQ + NQ + q];
    float qz = qpts[b * 3 * NQ + 2 * NQ + q];
    float q2 = __fadd_rn(__fadd_rn(__fmul_rn(qx, qx), __fmul_rn(qy, qy)), __fmul_rn(qz, qz));

    int base = w << 9;
    float d0 = 1e30f, d1 = 1e30f, d2v = 1e30f;
    int i0 = 0, i1 = 0, i2 = 0;
    float e0 = 1e30f, e1 = 1e30f, e2v = 1e30f;
    int j0 = 0, j1 = 0, j2 = 0;
    #pragma unroll 2
    for (int k = 0; k < 256; k++) {
        int na = base + k, nb2 = base + 256 + k;
        float4 pa = sp[na];
        float4 pb = sp[nb2];
        // cra2 == 2*cross, bit-exact (each product and sum scaled by exact 2)
        float cra2 = __fadd_rn(__fadd_rn(__fmul_rn(qx, pa.x), __fmul_rn(qy, pa.y)), __fmul_rn(qz, pa.z));
        float da = __fsub_rn(__fadd_rn(q2, pa.w), cra2);
        float crb2 = __fadd_rn(__fadd_rn(__fmul_rn(qx, pb.x), __fmul_rn(qy, pb.y)), __fmul_rn(qz, pb.z));
        float db = __fsub_rn(__fadd_rn(q2, pb.w), crb2);
        // branchless sorted insert, chain A
        {
            bool c0 = da < d0, c1 = da < d1, c2 = da < d2v;
            int t1 = c1 ? i1 : na;
            i2 = c2 ? t1 : i2;
            int t0 = c0 ? i0 : na;
            i1 = c1 ? t0 : i1;
            i0 = c0 ? na : i0;
            d2v = __builtin_amdgcn_fmed3f(d1, d2v, da);
            d1  = __builtin_amdgcn_fmed3f(d0, d1, da);
            d0  = fminf(d0, da);
        }
        // branchless sorted insert, chain B
        {
            bool c0 = db < e0, c1 = db < e1, c2 = db < e2v;
            int t1 = c1 ? j1 : nb2;
            j2 = c2 ? t1 : j2;
            int t0 = c0 ? j0 : nb2;
            j1 = c1 ? t0 : j1;
            j0 = c0 ? nb2 : j0;
            e2v = __builtin_amdgcn_fmed3f(e1, e2v, db);
            e1  = __builtin_amdgcn_fmed3f(e0, e1, db);
            e0  = fminf(e0, db);
        }
    }
    // merge chain B into A (lexicographic (d, idx) preserves top_k stability)
    {
        float md[3] = {e0, e1, e2v};
        int   mi[3] = {j0, j1, j2};
        #pragma unroll
        for (int m = 0; m < 3; m++) {
            float d = md[m]; int i = mi[m];
            if (d < d2v || (d == d2v && i < i2)) {
                if (d < d1 || (d == d1 && i < i1)) {
                    d2v = d1; i2 = i1;
                    if (d < d0 || (d == d0 && i < i0)) { d1 = d0; i1 = i0; d0 = d; i0 = i; }
                    else { d1 = d; i1 = i; }
                } else { d2v = d; i2 = i; }
            }
        }
    }
    spd[0][w][lane] = d0;  spi[0][w][lane] = i0;
    spd[1][w][lane] = d1;  spi[1][w][lane] = i1;
    spd[2][w][lane] = d2v; spi[2][w][lane] = i2;
    __syncthreads();
    if (t < 64) {
        d0 = spd[0][0][t]; i0 = spi[0][0][t];
        d1 = spd[1][0][t]; i1 = spi[1][0][t];
        d2v = spd[2][0][t]; i2 = spi[2][0][t];
        for (int p = 1; p < 8; p++) {
            #pragma unroll
            for (int m = 0; m < 3; m++) {
                float d = spd[m][p][t]; int i = spi[m][p][t];
                if (d < d2v || (d == d2v && i < i2)) {
                    if (d < d1 || (d == d1 && i < i1)) {
                        d2v = d1; i2 = i1;
                        if (d < d0 || (d == d0 && i < i0)) { d1 = d0; i1 = i0; d0 = d; i0 = i; }
                        else { d1 = d; i1 = i; }
                    } else { d2v = d; i2 = i; }
                }
            }
        }
        int ids[3] = {i0, i1, i2};
        float r[3];
        float s = 0.f;
        #pragma unroll
        for (int m = 0; m < 3; m++) {
            float4 p = sp[ids[m]];
            // halve back the doubled coords (exact)
            float px = __fmul_rn(p.x, 0.5f);
            float py = __fmul_rn(p.y, 0.5f);
            float pz = __fmul_rn(p.z, 0.5f);
            float dx = __fsub_rn(px, qx), dy = __fsub_rn(py, qy), dz = __fsub_rn(pz, qz);
            float dd = __fadd_rn(__fadd_rn(__fmul_rn(dx, dx), __fmul_rn(dy, dy)), __fmul_rn(dz, dz));
            float dist = sqrtf(dd);
            r[m] = 1.f / (__fadd_rn(dist, 1e-8f));
            s += r[m];
        }
        int basei = (b * NQ + q) * 3;
        #pragma unroll
        for (int m = 0; m < 3; m++) {
            knn_idx[basei + m] = ids[m];
            knn_w[basei + m]   = r[m] / s;
        }
    }
}

// ---------------- k_tail: fused interp(r1-gather) + r2 + r3 + r4, 64 queries/block ----
__global__ __launch_bounds__(256) void k_tail(
        const float* __restrict__ qpts, const _Float16* __restrict__ G,
        const float* __restrict__ CB, const int* __restrict__ knn_idx,
        const float* __restrict__ knn_w, const float* __restrict__ r1,
        const _Float16* __restrict__ Rw2, const float* __restrict__ rb2,
        const _Float16* __restrict__ Rw3, const float* __restrict__ rb3,
        const float* __restrict__ r4, const float* __restrict__ rb4,
        float* __restrict__ out) {
    __shared__ __align__(16) unsigned char arena[48128];
    _Float16* sH1  = (_Float16*)arena;             // [64][264] = 33792 B
    _Float16* sBst = (_Float16*)(arena + 33792);   // r2 B-stage [128][56] = 14336 B
    _Float16* sH2  = (_Float16*)arena;             // [64][136] = 17408 (aliases sH1)
    _Float16* sH3  = (_Float16*)(arena + 17408);   // [64][72]  = 9216
    _Float16* sW3  = (_Float16*)(arena + 33792);   // r3 W-stage [64][56] = 7168
    __shared__ int   s_id[192];
    __shared__ float s_wt[192];
    __shared__ float s_qp[3][64];
    __shared__ float s_wq[3][256];
    __shared__ float s_cb[256];
    __shared__ float sw4[64];
    int t = threadIdx.x;
    int w = t >> 6, lane = t & 63;
    int m = lane & 15, quad = lane >> 4;
    int q0 = blockIdx.x * 64;
    int b = q0 >> 14;
    int qin = q0 & (NQ - 1);

    if (t < 192) {
        s_id[t] = knn_idx[q0 * 3 + t];
        s_wt[t] = knn_w[q0 * 3 + t];
        int d = t >> 6, j = t & 63;
        s_qp[d][j] = qpts[(size_t)b * 3 * NQ + d * NQ + qin + j];
    }
    s_wq[0][t] = r1[(size_t)t * 707 + 0];
    s_wq[1][t] = r1[(size_t)t * 707 + 1];
    s_wq[2][t] = r1[(size_t)t * 707 + 2];
    s_cb[t] = CB[b * 256 + t];
    if (t < 64) sw4[t] = r4[t];
    __syncthreads();

    // ---- interp: build h1 tile [64 q][256 ch] in LDS (same fmaf order as before) ----
    {
        int cg = (t & 31) * 8;
        int js = t >> 5;
        float wq0[8], wq1[8], wq2[8], cbv[8];
        #pragma unroll
        for (int u = 0; u < 8; u++) {
            wq0[u] = s_wq[0][cg + u];
            wq1[u] = s_wq[1][cg + u];
            wq2[u] = s_wq[2][cg + u];
            cbv[u] = s_cb[cg + u];
        }
        const _Float16* Gb = G + (size_t)b * NPTS * 256;
        #pragma unroll
        for (int jj = 0; jj < 8; jj++) {
            int j = js + jj * 8;
            int i0 = s_id[j * 3 + 0], i1 = s_id[j * 3 + 1], i2 = s_id[j * 3 + 2];
            float w0 = s_wt[j * 3 + 0], w1 = s_wt[j * 3 + 1], w2 = s_wt[j * 3 + 2];
            float qx = s_qp[0][j], qy = s_qp[1][j], qz = s_qp[2][j];
            h8 g0 = *(const h8*)&Gb[(size_t)i0 * 256 + cg];
            h8 g1 = *(const h8*)&Gb[(size_t)i1 * 256 + cg];
            h8 g2 = *(const h8*)&Gb[(size_t)i2 * 256 + cg];
            h8 hv;
            #pragma unroll
            for (int u = 0; u < 8; u++) {
                float acc = cbv[u];
                acc = fmaf(wq0[u], qx, acc);
                acc = fmaf(wq1[u], qy, acc);
                acc = fmaf(wq2[u], qz, acc);
                acc = fmaf(w0, (float)g0[u], acc);
                acc = fmaf(w1, (float)g1[u], acc);
                acc = fmaf(w2, (float)g2[u], acc);
                hv[u] = (_Float16)fmaxf(acc, 0.f);
            }
            *(h8*)&sH1[j * 264 + cg] = hv;
        }
    }

    // ---- r2: h2(64q x 128ch) = relu(Rw2 @ h1); A-frags straight from sH1 ----
    float h2v[4][2][4];
    {
        v4f acc[4][2];
        #pragma unroll
        for (int i = 0; i < 4; i++)
            #pragma unroll
            for (int j = 0; j < 2; j++)
                acc[i][j] = (v4f){0.f, 0.f, 0.f, 0.f};
        for (int kc = 0; kc < 256; kc += 32) {
            __syncthreads();   // first: sH1 writes; later: sBst reuse
            #pragma unroll
            for (int i = 0; i < 2; i++) {
                int e = t + i * 256;
                int r = e >> 2, p = e & 3;
                *(float4*)&sBst[r * 56 + p * 8] =
                    *(const float4*)&Rw2[(size_t)r * 256 + kc + p * 8];
            }
            __syncthreads();
            h8 af[4], bf[2];
            #pragma unroll
            for (int mt = 0; mt < 4; mt++)
                af[mt] = *(const h8*)&sH1[(mt * 16 + m) * 264 + kc + quad * 8];
            #pragma unroll
            for (int nt = 0; nt < 2; nt++)
                bf[nt] = *(const h8*)&sBst[(w * 32 + nt * 16 + m) * 56 + quad * 8];
            #pragma unroll
            for (int mt = 0; mt < 4; mt++)
                #pragma unroll
                for (int nt = 0; nt < 2; nt++)
                    acc[mt][nt] = __builtin_amdgcn_mfma_f32_16x16x32_f16(
                            af[mt], bf[nt], acc[mt][nt], 0, 0, 0);
        }
        #pragma unroll
        for (int nt = 0; nt < 2; nt++) {
            int ch = w * 32 + nt * 16 + m;
            float bb2 = rb2[ch];
            #pragma unroll
            for (int mt = 0; mt < 4; mt++)
                #pragma unroll
                for (int r = 0; r < 4; r++)
                    h2v[mt][nt][r] = fmaxf(acc[mt][nt][r] + bb2, 0.f);
        }
    }
    __syncthreads();   // all sH1 reads done -> safe to overwrite with sH2
    {
        #pragma unroll
        for (int nt = 0; nt < 2; nt++) {
            int ch = w * 32 + nt * 16 + m;
            #pragma unroll
            for (int mt = 0; mt < 4; mt++)
                #pragma unroll
                for (int r = 0; r < 4; r++) {
                    int ql = mt * 16 + quad * 4 + r;
                    sH2[ql * 136 + ch] = (_Float16)h2v[mt][nt][r];
                }
        }
    }

    // ---- r3: h3(64q x 64ch) = relu(Rw3 @ h2) ----
    float h3v[4][4];
    {
        v4f acc[4];
        #pragma unroll
        for (int i = 0; i < 4; i++) acc[i] = (v4f){0.f, 0.f, 0.f, 0.f};
        for (int kc = 0; kc < 128; kc += 32) {
            __syncthreads();   // first: sH2 writes; later: sW3 reuse
            if (t < 256) {     // 64 rows x 4 segs = 256; 1 per thread
                int r = t >> 2, p = t & 3;
                *(float4*)&sW3[r * 56 + p * 8] =
                    *(const float4*)&Rw3[(size_t)r * 128 + kc + p * 8];
            }
            __syncthreads();
            h8 af[4], bf;
            #pragma unroll
            for (int mt = 0; mt < 4; mt++)
                af[mt] = *(const h8*)&sH2[(mt * 16 + m) * 136 + kc + quad * 8];
            bf = *(const h8*)&sW3[(w * 16 + m) * 56 + quad * 8];
            #pragma unroll
            for (int mt = 0; mt < 4; mt++)
                acc[mt] = __builtin_amdgcn_mfma_f32_16x16x32_f16(
                        af[mt], bf, acc[mt], 0, 0, 0);
        }
        int ch = w * 16 + m;
        float bb3 = rb3[ch];
        #pragma unroll
        for (int mt = 0; mt < 4; mt++)
            #pragma unroll
            for (int r = 0; r < 4; r++)
                h3v[mt][r] = fmaxf(acc[mt][r] + bb3, 0.f);
    }
    __syncthreads();
    {
        int ch = w * 16 + m;
        #pragma unroll
        for (int mt = 0; mt < 4; mt++)
            #pragma unroll
            for (int r = 0; r < 4; r++) {
                int ql = mt * 16 + quad * 4 + r;
                sH3[ch * 72 + ql] = (_Float16)h3v[mt][r];
            }
    }
    __syncthreads();

    // ---- r4: out = r4 . h3 + rb4 ----
    if (t < 64) {
        float acc = rb4[0];
        #pragma unroll 16
        for (int c = 0; c < 64; c++)
            acc = fmaf((float)sH3[c * 72 + t], sw4[c], acc);
        out[q0 + t] = acc;
    }
}

extern "C" void kernel_launch(void* const* d_in, const int* in_sizes, int n_in,
                              void* d_out, int out_size, void* d_ws, size_t ws_size,
                              hipStream_t stream) {
    const float* opts = (const float*)d_in[0];
    const float* qpts = (const float*)d_in[1];
    const float* w1  = (const float*)d_in[2];
    const float* b1  = (const float*)d_in[3];
    const float* w2  = (const float*)d_in[4];
    const float* b2  = (const float*)d_in[5];
    const float* w3  = (const float*)d_in[6];
    const float* b3  = (const float*)d_in[7];
    const float* r1  = (const float*)d_in[8];
    const float* rb1 = (const float*)d_in[9];
    const float* r2  = (const float*)d_in[10];
    const float* rb2 = (const float*)d_in[11];
    const float* r3  = (const float*)d_in[12];
    const float* rb3 = (const float*)d_in[13];
    const float* r4  = (const float*)d_in[14];
    const float* rb4 = (const float*)d_in[15];
    float* out = (float*)d_out;

    unsigned char* p = (unsigned char*)d_ws;
    float* GM = (float*)p;          p += (size_t)NB * 256 * 4;
    float* CB = (float*)p;          p += (size_t)NB * 256 * 4;
    int*   IDX = (int*)p;           p += (size_t)NB * NQ * 3 * 4;
    float* WT = (float*)p;          p += (size_t)NB * NQ * 3 * 4;
    _Float16* Fcat = (_Float16*)p;  p += (size_t)NB * NPTS * FCATC * 2;
    _Float16* Rw1 = (_Float16*)p;   p += (size_t)256 * FCATC * 2;
    _Float16* Rw2 = (_Float16*)p;   p += (size_t)128 * 256 * 2;
    _Float16* Rw3 = (_Float16*)p;   p += (size_t)64 * 128 * 2;
    _Float16* Ew2 = (_Float16*)p;   p += (size_t)128 * 64 * 2;
    _Float16* Ew3 = (_Float16*)p;   p += (size_t)256 * 128 * 2;
    _Float16* G = (_Float16*)p;     p += (size_t)NB * NPTS * 256 * 2;

    k_pre<<<769, 256, 0, stream>>>(r1, r2, r3, w2, w3, Rw1, Rw2, Rw3, Ew2, Ew3, GM);
    k_fe<<<NB * NPTS / 128, 256, 0, stream>>>(opts, w1, b1, Ew2, b2, Ew3, b3,
                                              Fcat, (unsigned*)GM);
    // G[n][256] = Rw1 @ Fcat[n]; last block computes CB from GM
    k_gemm<FCATC, 1, 256><<<NB * NPTS / 64 + 1, 256, 0, stream>>>(
            Fcat, Rw1, G, r1, rb1, GM, CB);
    k_knn<<<512, 512, 0, stream>>>(opts, qpts, IDX, WT);
    k_tail<<<QTOT / 64, 256, 0, stream>>>(qpts, G, CB, IDX, WT, r1,
                                          Rw2, rb2, Rw3, rb3, r4, rb4, out);
}

// Round 2
// 192.630 us; speedup vs baseline: 1.0737x; 1.0737x over previous
//
#include <hip/hip_runtime.h>
#include <math.h>

#define NB 2
#define NPTS 4096
#define NQ 16384
#define QTOT (NB * NQ)   // 32768 queries, batch folded into row index
#define FCATC 448        // 64+128+256 concatenated feature channels per point

typedef _Float16 h8 __attribute__((ext_vector_type(8)));
typedef float v4f __attribute__((ext_vector_type(4)));

// ---------------- k_pre: weight casts + GM zero ----------------
__global__ __launch_bounds__(256) void k_pre(
        const float* __restrict__ r1, const float* __restrict__ r2,
        const float* __restrict__ r3, const float* __restrict__ w2,
        const float* __restrict__ w3,
        _Float16* __restrict__ Rw1, _Float16* __restrict__ Rw2,
        _Float16* __restrict__ Rw3, _Float16* __restrict__ Ew2,
        _Float16* __restrict__ Ew3, float* __restrict__ GM) {
    int blk = blockIdx.x;
    int t = threadIdx.x;
    if (blk < 768) {
        int g = blk * 256 + t;
        if (g < 114688) {                       // Rw1 = r1[:,3:451] (256 x 448)
            int o = g / FCATC, k = g - o * FCATC;
            Rw1[g] = (_Float16)r1[(size_t)o * 707 + 3 + k];
        } else if (g < 147456) {                // Rw2 = r2 (128x256)
            int i = g - 114688;
            Rw2[i] = (_Float16)r2[i];
        } else if (g < 155648) {                // Rw3 = r3 (64x128)
            int i = g - 147456;
            Rw3[i] = (_Float16)r3[i];
        } else if (g < 163840) {                // Ew2 = w2 (128x64)
            int i = g - 155648;
            Ew2[i] = (_Float16)w2[i];
        } else {                                // Ew3 = w3 (256x128)
            int i = g - 163840;
            Ew3[i] = (_Float16)w3[i];
        }
    } else {
        GM[t] = 0.f;
        GM[256 + t] = 0.f;
    }
}

// ---------------- k_fe: fused l1 + l2 + l3 + global-max + G-GEMM, 128 points/block ----
// Keeps f1/f2/f3 entirely in LDS and computes G[pt][256] = Rw1 @ [f1|f2|f3] in-block
// (bit-identical to the old separate k_gemm: same f16 operands, same kc chunk order).
__global__ __launch_bounds__(256) void k_fe(const float* __restrict__ pts,
        const float* __restrict__ w1, const float* __restrict__ b1,
        const _Float16* __restrict__ Ew2, const float* __restrict__ b2,
        const _Float16* __restrict__ Ew3, const float* __restrict__ b3,
        const _Float16* __restrict__ Rw1, _Float16* __restrict__ G,
        unsigned* __restrict__ GM) {
    __shared__ __align__(16) unsigned char arena[149504];
    _Float16* sF1  = (_Float16*)arena;             // [128][72]  = 18432 B (64 ch)
    _Float16* sF2  = (_Float16*)(arena + 18432);   // [128][136] = 34816 B (128 ch)
    _Float16* sF3  = (_Float16*)(arena + 53248);   // [128][264] = 67584 B (256 ch)
    _Float16* sBst = (_Float16*)(arena + 120832);  // up to [256][56] = 28672 B
    __shared__ float sW1[192];
    __shared__ float sB1[64];
    __shared__ unsigned smax[256];
    int t = threadIdx.x;
    int w = t >> 6, lane = t & 63;
    int m = lane & 15, quad = lane >> 4;
    int wq = w & 1, wn = w >> 1;
    int P0 = blockIdx.x * 128;          // global point row
    int bb = P0 >> 12;
    int p0in = P0 & (NPTS - 1);

    if (t < 192) sW1[t] = w1[t];
    if (t < 64)  sB1[t] = b1[t];
    smax[t] = 0u;
    __syncthreads();

    // ---- l1: f1 = relu(W1 @ pts + b1) -> sF1 ----
    {
        int pt = t >> 1;
        int cs = (t & 1) * 32;
        const float* pb = pts + (size_t)bb * 3 * NPTS + p0in;
        float px = pb[pt], py = pb[NPTS + pt], pz = pb[2 * NPTS + pt];
        #pragma unroll 8
        for (int c = cs; c < cs + 32; c++) {
            float v = fmaf(sW1[c*3+0], px,
                      fmaf(sW1[c*3+1], py,
                      fmaf(sW1[c*3+2], pz, sB1[c])));
            sF1[pt * 72 + c] = (_Float16)fmaxf(v, 0.f);
        }
    }

    // ---- l2: f2(128pt x 128ch) = relu(Ew2 @ f1 + b2) -> sF2 ----
    {
        v4f acc[4][4];
        #pragma unroll
        for (int i = 0; i < 4; i++)
            #pragma unroll
            for (int j = 0; j < 4; j++)
                acc[i][j] = (v4f){0.f, 0.f, 0.f, 0.f};
        for (int kc = 0; kc < 64; kc += 32) {
            __syncthreads();    // first iter: covers sF1 writes; later: sBst reuse
            {
                #pragma unroll
                for (int i = 0; i < 2; i++) {   // 128 rows x 4 segs = 512; 2/thread
                    int e = t + i * 256;
                    int r = e >> 2, p = e & 3;
                    *(float4*)&sBst[r * 56 + p * 8] =
                        *(const float4*)&Ew2[(size_t)r * 64 + kc + p * 8];
                }
            }
            __syncthreads();
            h8 af[4], bf[4];
            #pragma unroll
            for (int mt = 0; mt < 4; mt++)
                af[mt] = *(const h8*)&sF1[(wq * 64 + mt * 16 + m) * 72 + kc + quad * 8];
            #pragma unroll
            for (int nt = 0; nt < 4; nt++)
                bf[nt] = *(const h8*)&sBst[(wn * 64 + nt * 16 + m) * 56 + quad * 8];
            #pragma unroll
            for (int mt = 0; mt < 4; mt++)
                #pragma unroll
                for (int nt = 0; nt < 4; nt++)
                    acc[mt][nt] = __builtin_amdgcn_mfma_f32_16x16x32_f16(
                            af[mt], bf[nt], acc[mt][nt], 0, 0, 0);
        }
        #pragma unroll
        for (int nt = 0; nt < 4; nt++) {
            int ch = wn * 64 + nt * 16 + m;
            float bb2 = b2[ch];
            #pragma unroll
            for (int mt = 0; mt < 4; mt++) {
                #pragma unroll
                for (int r = 0; r < 4; r++) {
                    int ptl = wq * 64 + mt * 16 + quad * 4 + r;
                    sF2[ptl * 136 + ch] = (_Float16)fmaxf(acc[mt][nt][r] + bb2, 0.f);
                }
            }
        }
    }

    // ---- l3: f3(128pt x 256ch) = relu(Ew3 @ f2 + b3) -> sF3 + max ----
    {
        v4f acc[4][8];
        #pragma unroll
        for (int i = 0; i < 4; i++)
            #pragma unroll
            for (int j = 0; j < 8; j++)
                acc[i][j] = (v4f){0.f, 0.f, 0.f, 0.f};
        for (int kc = 0; kc < 128; kc += 32) {
            __syncthreads();    // first iter: covers sF2 writes; later: sBst reuse
            {
                #pragma unroll
                for (int i = 0; i < 4; i++) {   // 256 rows x 4 segs = 1024; 4/thread
                    int e = t + i * 256;
                    int r = e >> 2, p = e & 3;
                    *(float4*)&sBst[r * 56 + p * 8] =
                        *(const float4*)&Ew3[(size_t)r * 128 + kc + p * 8];
                }
            }
            __syncthreads();
            h8 af[4], bf[8];
            #pragma unroll
            for (int mt = 0; mt < 4; mt++)
                af[mt] = *(const h8*)&sF2[(wq * 64 + mt * 16 + m) * 136 + kc + quad * 8];
            #pragma unroll
            for (int nt = 0; nt < 8; nt++)
                bf[nt] = *(const h8*)&sBst[(wn * 128 + nt * 16 + m) * 56 + quad * 8];
            #pragma unroll
            for (int mt = 0; mt < 4; mt++)
                #pragma unroll
                for (int nt = 0; nt < 8; nt++)
                    acc[mt][nt] = __builtin_amdgcn_mfma_f32_16x16x32_f16(
                            af[mt], bf[nt], acc[mt][nt], 0, 0, 0);
        }
        #pragma unroll
        for (int nt = 0; nt < 8; nt++) {
            int ch = wn * 128 + nt * 16 + m;
            float bb3 = b3[ch];
            float vmax = 0.f;
            #pragma unroll
            for (int mt = 0; mt < 4; mt++) {
                #pragma unroll
                for (int r = 0; r < 4; r++) {
                    int ptl = wq * 64 + mt * 16 + quad * 4 + r;
                    float v = fmaxf(acc[mt][nt][r] + bb3, 0.f);
                    vmax = fmaxf(vmax, v);
                    sF3[ptl * 264 + ch] = (_Float16)v;
                }
            }
            atomicMax(&smax[ch], __float_as_uint(vmax));
        }
        __syncthreads();
        atomicMax(GM + bb * 256 + t, smax[t]);
    }

    // ---- G-GEMM: G[128pt][256] = Rw1[256x448] @ [sF1|sF2|sF3], kc chunks of 32 ----
    {
        v4f acc[4][8];
        #pragma unroll
        for (int i = 0; i < 4; i++)
            #pragma unroll
            for (int j = 0; j < 8; j++)
                acc[i][j] = (v4f){0.f, 0.f, 0.f, 0.f};
        #pragma unroll
        for (int kc = 0; kc < FCATC; kc += 32) {
            __syncthreads();    // sBst reuse (first iter: already synced above)
            #pragma unroll
            for (int i = 0; i < 4; i++) {       // 256 rows x 4 segs = 1024; 4/thread
                int e = t + i * 256;
                int r = e >> 2, p = e & 3;
                *(float4*)&sBst[r * 56 + p * 8] =
                    *(const float4*)&Rw1[(size_t)r * FCATC + kc + p * 8];
            }
            __syncthreads();
            h8 af[4], bf[8];
            #pragma unroll
            for (int mt = 0; mt < 4; mt++) {
                int row = wq * 64 + mt * 16 + m;
                if (kc < 64)
                    af[mt] = *(const h8*)&sF1[row * 72 + kc + quad * 8];
                else if (kc < 192)
                    af[mt] = *(const h8*)&sF2[row * 136 + (kc - 64) + quad * 8];
                else
                    af[mt] = *(const h8*)&sF3[row * 264 + (kc - 192) + quad * 8];
            }
            #pragma unroll
            for (int nt = 0; nt < 8; nt++)
                bf[nt] = *(const h8*)&sBst[(wn * 128 + nt * 16 + m) * 56 + quad * 8];
            #pragma unroll
            for (int mt = 0; mt < 4; mt++)
                #pragma unroll
                for (int nt = 0; nt < 8; nt++)
                    acc[mt][nt] = __builtin_amdgcn_mfma_f32_16x16x32_f16(
                            af[mt], bf[nt], acc[mt][nt], 0, 0, 0);
        }
        #pragma unroll
        for (int nt = 0; nt < 8; nt++) {
            int ch = wn * 128 + nt * 16 + m;
            #pragma unroll
            for (int mt = 0; mt < 4; mt++) {
                #pragma unroll
                for (int r = 0; r < 4; r++) {
                    int ptl = wq * 64 + mt * 16 + quad * 4 + r;
                    G[(size_t)(P0 + ptl) * 256 + ch] = (_Float16)acc[mt][nt][r];
                }
            }
        }
    }
}

// ---------------- KNN: round-0 branchy structure (best measured: 69.0 us) + CB rider ----
__global__ __launch_bounds__(512) void k_knn(const float* __restrict__ opts,
        const float* __restrict__ qpts, int* __restrict__ knn_idx,
        float* __restrict__ knn_w,
        const float* __restrict__ r1, const float* __restrict__ rb1,
        const float* __restrict__ gm, float* __restrict__ cb) {
    if (blockIdx.x == gridDim.x - 1) {
        // cb[b][o] = rb1[o] + r1[o,451:707] . gmax[b]   (verbatim k_gemm rider)
        int t = threadIdx.x;
        if (t < 256) {
            for (int b = 0; b < NB; b++) {
                const float* wrow = r1 + (size_t)t * 707 + 451;
                const float* g = gm + b * 256;
                float acc = rb1[t];
                #pragma unroll 8
                for (int c = 0; c < 256; c++) acc = fmaf(wrow[c], g[c], acc);
                cb[b * 256 + t] = acc;
            }
        }
        return;
    }
    __shared__ float4 sp[NPTS];       // 64 KB
    __shared__ float spd[3][8][64];
    __shared__ int   spi[3][8][64];
    int t = threadIdx.x;
    int b = blockIdx.x >> 8;
    int q0 = (blockIdx.x & 255) << 6;
    const float* ob = opts + b * 3 * NPTS;
    for (int i = t; i < NPTS; i += 512) {
        float x = ob[i], y = ob[NPTS + i], z = ob[2 * NPTS + i];
        float o2 = __fadd_rn(__fadd_rn(__fmul_rn(x, x), __fmul_rn(y, y)), __fmul_rn(z, z));
        sp[i] = make_float4(x, y, z, o2);
    }
    __syncthreads();
    int lane = t & 63;
    int w = t >> 6;
    int q = q0 + lane;
    float qx = qpts[b * 3 * NQ + q];
    float qy = qpts[b * 3 * NQ + NQ + q];
    float qz = qpts[b * 3 * NQ + 2 * NQ + q];
    float q2 = __fadd_rn(__fadd_rn(__fmul_rn(qx, qx), __fmul_rn(qy, qy)), __fmul_rn(qz, qz));

    int base = w << 9;
    float d0 = 1e30f, d1 = 1e30f, d2v = 1e30f;
    int i0 = 0, i1 = 0, i2 = 0;
    float e0 = 1e30f, e1 = 1e30f, e2v = 1e30f;
    int j0 = 0, j1 = 0, j2 = 0;
    #pragma unroll 2
    for (int k = 0; k < 256; k++) {
        int na = base + k, nb2 = base + 256 + k;
        float4 pa = sp[na];
        float4 pb = sp[nb2];
        float cra = __fadd_rn(__fadd_rn(__fmul_rn(qx, pa.x), __fmul_rn(qy, pa.y)), __fmul_rn(qz, pa.z));
        float da = __fsub_rn(__fadd_rn(q2, pa.w), __fmul_rn(2.f, cra));
        float crb = __fadd_rn(__fadd_rn(__fmul_rn(qx, pb.x), __fmul_rn(qy, pb.y)), __fmul_rn(qz, pb.z));
        float db = __fsub_rn(__fadd_rn(q2, pb.w), __fmul_rn(2.f, crb));
        if (da < d2v) {                 // strict <: ascending idx keeps earlier on ties
            if (da < d1) {
                d2v = d1; i2 = i1;
                if (da < d0) { d1 = d0; i1 = i0; d0 = da; i0 = na; }
                else         { d1 = da; i1 = na; }
            } else { d2v = da; i2 = na; }
        }
        if (db < e2v) {
            if (db < e1) {
                e2v = e1; j2 = j1;
                if (db < e0) { e1 = e0; j1 = j0; e0 = db; j0 = nb2; }
                else         { e1 = db; j1 = nb2; }
            } else { e2v = db; j2 = nb2; }
        }
    }
    // merge chain B into A (lexicographic (d, idx) preserves top_k stability)
    {
        float md[3] = {e0, e1, e2v};
        int   mi[3] = {j0, j1, j2};
        #pragma unroll
        for (int m = 0; m < 3; m++) {
            float d = md[m]; int i = mi[m];
            if (d < d2v || (d == d2v && i < i2)) {
                if (d < d1 || (d == d1 && i < i1)) {
                    d2v = d1; i2 = i1;
                    if (d < d0 || (d == d0 && i < i0)) { d1 = d0; i1 = i0; d0 = d; i0 = i; }
                    else { d1 = d; i1 = i; }
                } else { d2v = d; i2 = i; }
            }
        }
    }
    spd[0][w][lane] = d0;  spi[0][w][lane] = i0;
    spd[1][w][lane] = d1;  spi[1][w][lane] = i1;
    spd[2][w][lane] = d2v; spi[2][w][lane] = i2;
    __syncthreads();
    if (t < 64) {
        d0 = spd[0][0][t]; i0 = spi[0][0][t];
        d1 = spd[1][0][t]; i1 = spi[1][0][t];
        d2v = spd[2][0][t]; i2 = spi[2][0][t];
        for (int p = 1; p < 8; p++) {
            #pragma unroll
            for (int m = 0; m < 3; m++) {
                float d = spd[m][p][t]; int i = spi[m][p][t];
                if (d < d2v || (d == d2v && i < i2)) {
                    if (d < d1 || (d == d1 && i < i1)) {
                        d2v = d1; i2 = i1;
                        if (d < d0 || (d == d0 && i < i0)) { d1 = d0; i1 = i0; d0 = d; i0 = i; }
                        else { d1 = d; i1 = i; }
                    } else { d2v = d; i2 = i; }
                }
            }
        }
        int ids[3] = {i0, i1, i2};
        float r[3];
        float s = 0.f;
        #pragma unroll
        for (int m = 0; m < 3; m++) {
            float4 p = sp[ids[m]];
            float dx = __fsub_rn(p.x, qx), dy = __fsub_rn(p.y, qy), dz = __fsub_rn(p.z, qz);
            float dd = __fadd_rn(__fadd_rn(__fmul_rn(dx, dx), __fmul_rn(dy, dy)), __fmul_rn(dz, dz));
            float dist = sqrtf(dd);
            r[m] = 1.f / (__fadd_rn(dist, 1e-8f));
            s += r[m];
        }
        int basei = (b * NQ + q) * 3;
        #pragma unroll
        for (int m = 0; m < 3; m++) {
            knn_idx[basei + m] = ids[m];
            knn_w[basei + m]   = r[m] / s;
        }
    }
}

// ---------------- k_tail: fused interp(r1-gather) + r2 + r3 + r4, 64 queries/block ----
__global__ __launch_bounds__(256) void k_tail(
        const float* __restrict__ qpts, const _Float16* __restrict__ G,
        const float* __restrict__ CB, const int* __restrict__ knn_idx,
        const float* __restrict__ knn_w, const float* __restrict__ r1,
        const _Float16* __restrict__ Rw2, const float* __restrict__ rb2,
        const _Float16* __restrict__ Rw3, const float* __restrict__ rb3,
        const float* __restrict__ r4, const float* __restrict__ rb4,
        float* __restrict__ out) {
    __shared__ __align__(16) unsigned char arena[48128];
    _Float16* sH1  = (_Float16*)arena;             // [64][264] = 33792 B
    _Float16* sBst = (_Float16*)(arena + 33792);   // r2 B-stage [128][56] = 14336 B
    _Float16* sH2  = (_Float16*)arena;             // [64][136] = 17408 (aliases sH1)
    _Float16* sH3  = (_Float16*)(arena + 17408);   // [64][72]  = 9216
    _Float16* sW3  = (_Float16*)(arena + 33792);   // r3 W-stage [64][56] = 7168
    __shared__ int   s_id[192];
    __shared__ float s_wt[192];
    __shared__ float s_qp[3][64];
    __shared__ float s_wq[3][256];
    __shared__ float s_cb[256];
    __shared__ float sw4[64];
    int t = threadIdx.x;
    int w = t >> 6, lane = t & 63;
    int m = lane & 15, quad = lane >> 4;
    int q0 = blockIdx.x * 64;
    int b = q0 >> 14;
    int qin = q0 & (NQ - 1);

    if (t < 192) {
        s_id[t] = knn_idx[q0 * 3 + t];
        s_wt[t] = knn_w[q0 * 3 + t];
        int d = t >> 6, j = t & 63;
        s_qp[d][j] = qpts[(size_t)b * 3 * NQ + d * NQ + qin + j];
    }
    s_wq[0][t] = r1[(size_t)t * 707 + 0];
    s_wq[1][t] = r1[(size_t)t * 707 + 1];
    s_wq[2][t] = r1[(size_t)t * 707 + 2];
    s_cb[t] = CB[b * 256 + t];
    if (t < 64) sw4[t] = r4[t];
    __syncthreads();

    // ---- interp: build h1 tile [64 q][256 ch] in LDS (same fmaf order as before) ----
    {
        int cg = (t & 31) * 8;
        int js = t >> 5;
        float wq0[8], wq1[8], wq2[8], cbv[8];
        #pragma unroll
        for (int u = 0; u < 8; u++) {
            wq0[u] = s_wq[0][cg + u];
            wq1[u] = s_wq[1][cg + u];
            wq2[u] = s_wq[2][cg + u];
            cbv[u] = s_cb[cg + u];
        }
        const _Float16* Gb = G + (size_t)b * NPTS * 256;
        #pragma unroll
        for (int jj = 0; jj < 8; jj++) {
            int j = js + jj * 8;
            int i0 = s_id[j * 3 + 0], i1 = s_id[j * 3 + 1], i2 = s_id[j * 3 + 2];
            float w0 = s_wt[j * 3 + 0], w1 = s_wt[j * 3 + 1], w2 = s_wt[j * 3 + 2];
            float qx = s_qp[0][j], qy = s_qp[1][j], qz = s_qp[2][j];
            h8 g0 = *(const h8*)&Gb[(size_t)i0 * 256 + cg];
            h8 g1 = *(const h8*)&Gb[(size_t)i1 * 256 + cg];
            h8 g2 = *(const h8*)&Gb[(size_t)i2 * 256 + cg];
            h8 hv;
            #pragma unroll
            for (int u = 0; u < 8; u++) {
                float acc = cbv[u];
                acc = fmaf(wq0[u], qx, acc);
                acc = fmaf(wq1[u], qy, acc);
                acc = fmaf(wq2[u], qz, acc);
                acc = fmaf(w0, (float)g0[u], acc);
                acc = fmaf(w1, (float)g1[u], acc);
                acc = fmaf(w2, (float)g2[u], acc);
                hv[u] = (_Float16)fmaxf(acc, 0.f);
            }
            *(h8*)&sH1[j * 264 + cg] = hv;
        }
    }

    // ---- r2: h2(64q x 128ch) = relu(Rw2 @ h1); A-frags straight from sH1 ----
    float h2v[4][2][4];
    {
        v4f acc[4][2];
        #pragma unroll
        for (int i = 0; i < 4; i++)
            #pragma unroll
            for (int j = 0; j < 2; j++)
                acc[i][j] = (v4f){0.f, 0.f, 0.f, 0.f};
        for (int kc = 0; kc < 256; kc += 32) {
            __syncthreads();   // first: sH1 writes; later: sBst reuse
            #pragma unroll
            for (int i = 0; i < 2; i++) {
                int e = t + i * 256;
                int r = e >> 2, p = e & 3;
                *(float4*)&sBst[r * 56 + p * 8] =
                    *(const float4*)&Rw2[(size_t)r * 256 + kc + p * 8];
            }
            __syncthreads();
            h8 af[4], bf[2];
            #pragma unroll
            for (int mt = 0; mt < 4; mt++)
                af[mt] = *(const h8*)&sH1[(mt * 16 + m) * 264 + kc + quad * 8];
            #pragma unroll
            for (int nt = 0; nt < 2; nt++)
                bf[nt] = *(const h8*)&sBst[(w * 32 + nt * 16 + m) * 56 + quad * 8];
            #pragma unroll
            for (int mt = 0; mt < 4; mt++)
                #pragma unroll
                for (int nt = 0; nt < 2; nt++)
                    acc[mt][nt] = __builtin_amdgcn_mfma_f32_16x16x32_f16(
                            af[mt], bf[nt], acc[mt][nt], 0, 0, 0);
        }
        #pragma unroll
        for (int nt = 0; nt < 2; nt++) {
            int ch = w * 32 + nt * 16 + m;
            float bb2 = rb2[ch];
            #pragma unroll
            for (int mt = 0; mt < 4; mt++)
                #pragma unroll
                for (int r = 0; r < 4; r++)
                    h2v[mt][nt][r] = fmaxf(acc[mt][nt][r] + bb2, 0.f);
        }
    }
    __syncthreads();   // all sH1 reads done -> safe to overwrite with sH2
    {
        #pragma unroll
        for (int nt = 0; nt < 2; nt++) {
            int ch = w * 32 + nt * 16 + m;
            #pragma unroll
            for (int mt = 0; mt < 4; mt++)
                #pragma unroll
                for (int r = 0; r < 4; r++) {
                    int ql = mt * 16 + quad * 4 + r;
                    sH2[ql * 136 + ch] = (_Float16)h2v[mt][nt][r];
                }
        }
    }

    // ---- r3: h3(64q x 64ch) = relu(Rw3 @ h2) ----
    float h3v[4][4];
    {
        v4f acc[4];
        #pragma unroll
        for (int i = 0; i < 4; i++) acc[i] = (v4f){0.f, 0.f, 0.f, 0.f};
        for (int kc = 0; kc < 128; kc += 32) {
            __syncthreads();   // first: sH2 writes; later: sW3 reuse
            if (t < 256) {     // 64 rows x 4 segs = 256; 1 per thread
                int r = t >> 2, p = t & 3;
                *(float4*)&sW3[r * 56 + p * 8] =
                    *(const float4*)&Rw3[(size_t)r * 128 + kc + p * 8];
            }
            __syncthreads();
            h8 af[4], bf;
            #pragma unroll
            for (int mt = 0; mt < 4; mt++)
                af[mt] = *(const h8*)&sH2[(mt * 16 + m) * 136 + kc + quad * 8];
            bf = *(const h8*)&sW3[(w * 16 + m) * 56 + quad * 8];
            #pragma unroll
            for (int mt = 0; mt < 4; mt++)
                acc[mt] = __builtin_amdgcn_mfma_f32_16x16x32_f16(
                        af[mt], bf, acc[mt], 0, 0, 0);
        }
        int ch = w * 16 + m;
        float bb3 = rb3[ch];
        #pragma unroll
        for (int mt = 0; mt < 4; mt++)
            #pragma unroll
            for (int r = 0; r < 4; r++)
                h3v[mt][r] = fmaxf(acc[mt][r] + bb3, 0.f);
    }
    __syncthreads();
    {
        int ch = w * 16 + m;
        #pragma unroll
        for (int mt = 0; mt < 4; mt++)
            #pragma unroll
            for (int r = 0; r < 4; r++) {
                int ql = mt * 16 + quad * 4 + r;
                sH3[ch * 72 + ql] = (_Float16)h3v[mt][r];
            }
    }
    __syncthreads();

    // ---- r4: out = r4 . h3 + rb4 ----
    if (t < 64) {
        float acc = rb4[0];
        #pragma unroll 16
        for (int c = 0; c < 64; c++)
            acc = fmaf((float)sH3[c * 72 + t], sw4[c], acc);
        out[q0 + t] = acc;
    }
}

extern "C" void kernel_launch(void* const* d_in, const int* in_sizes, int n_in,
                              void* d_out, int out_size, void* d_ws, size_t ws_size,
                              hipStream_t stream) {
    const float* opts = (const float*)d_in[0];
    const float* qpts = (const float*)d_in[1];
    const float* w1  = (const float*)d_in[2];
    const float* b1  = (const float*)d_in[3];
    const float* w2  = (const float*)d_in[4];
    const float* b2  = (const float*)d_in[5];
    const float* w3  = (const float*)d_in[6];
    const float* b3  = (const float*)d_in[7];
    const float* r1  = (const float*)d_in[8];
    const float* rb1 = (const float*)d_in[9];
    const float* r2  = (const float*)d_in[10];
    const float* rb2 = (const float*)d_in[11];
    const float* r3  = (const float*)d_in[12];
    const float* rb3 = (const float*)d_in[13];
    const float* r4  = (const float*)d_in[14];
    const float* rb4 = (const float*)d_in[15];
    float* out = (float*)d_out;

    unsigned char* p = (unsigned char*)d_ws;
    float* GM = (float*)p;          p += (size_t)NB * 256 * 4;
    float* CB = (float*)p;          p += (size_t)NB * 256 * 4;
    int*   IDX = (int*)p;           p += (size_t)NB * NQ * 3 * 4;
    float* WT = (float*)p;          p += (size_t)NB * NQ * 3 * 4;
    _Float16* Rw1 = (_Float16*)p;   p += (size_t)256 * FCATC * 2;
    _Float16* Rw2 = (_Float16*)p;   p += (size_t)128 * 256 * 2;
    _Float16* Rw3 = (_Float16*)p;   p += (size_t)64 * 128 * 2;
    _Float16* Ew2 = (_Float16*)p;   p += (size_t)128 * 64 * 2;
    _Float16* Ew3 = (_Float16*)p;   p += (size_t)256 * 128 * 2;
    _Float16* G = (_Float16*)p;     p += (size_t)NB * NPTS * 256 * 2;

    k_pre<<<769, 256, 0, stream>>>(r1, r2, r3, w2, w3, Rw1, Rw2, Rw3, Ew2, Ew3, GM);
    // fe now also produces G (old k_gemm folded in); Fcat never touches global
    k_fe<<<NB * NPTS / 128, 256, 0, stream>>>(opts, w1, b1, Ew2, b2, Ew3, b3,
                                              Rw1, G, (unsigned*)GM);
    // knn + CB rider block (needs GM from k_fe, runs after it in-stream)
    k_knn<<<513, 512, 0, stream>>>(opts, qpts, IDX, WT, r1, rb1, GM, CB);
    k_tail<<<QTOT / 64, 256, 0, stream>>>(qpts, G, CB, IDX, WT, r1,
                                          Rw2, rb2, Rw3, rb3, r4, rb4, out);
}

// Round 3
// 184.819 us; speedup vs baseline: 1.1191x; 1.0423x over previous
//
#include <hip/hip_runtime.h>
#include <math.h>

#define NB 2
#define NPTS 4096
#define NQ 16384
#define QTOT (NB * NQ)   // 32768 queries, batch folded into row index
#define FCATC 448        // 64+128+256 concatenated feature channels per point

typedef _Float16 h8 __attribute__((ext_vector_type(8)));
typedef float v4f __attribute__((ext_vector_type(4)));

// ---------------- k_pre: weight casts + GM zero ----------------
__global__ __launch_bounds__(256) void k_pre(
        const float* __restrict__ r1, const float* __restrict__ r2,
        const float* __restrict__ r3, const float* __restrict__ w2,
        const float* __restrict__ w3,
        _Float16* __restrict__ Rw1, _Float16* __restrict__ Rw2,
        _Float16* __restrict__ Rw3, _Float16* __restrict__ Ew2,
        _Float16* __restrict__ Ew3, float* __restrict__ GM) {
    int blk = blockIdx.x;
    int t = threadIdx.x;
    if (blk < 768) {
        int g = blk * 256 + t;
        if (g < 114688) {                       // Rw1 = r1[:,3:451] (256 x 448)
            int o = g / FCATC, k = g - o * FCATC;
            Rw1[g] = (_Float16)r1[(size_t)o * 707 + 3 + k];
        } else if (g < 147456) {                // Rw2 = r2 (128x256)
            int i = g - 114688;
            Rw2[i] = (_Float16)r2[i];
        } else if (g < 155648) {                // Rw3 = r3 (64x128)
            int i = g - 147456;
            Rw3[i] = (_Float16)r3[i];
        } else if (g < 163840) {                // Ew2 = w2 (128x64)
            int i = g - 155648;
            Ew2[i] = (_Float16)w2[i];
        } else {                                // Ew3 = w3 (256x128)
            int i = g - 163840;
            Ew3[i] = (_Float16)w3[i];
        }
    } else {
        GM[t] = 0.f;
        GM[256 + t] = 0.f;
    }
}

// ---------------- k_fe: fused l1 + l2 + l3 + global-max + G-GEMM, 128 points/block ----
// Keeps f1/f2/f3 entirely in LDS and computes G[pt][256] = Rw1 @ [f1|f2|f3] in-block
// (bit-identical to the old separate k_gemm: same f16 operands, same kc chunk order).
__global__ __launch_bounds__(256) void k_fe(const float* __restrict__ pts,
        const float* __restrict__ w1, const float* __restrict__ b1,
        const _Float16* __restrict__ Ew2, const float* __restrict__ b2,
        const _Float16* __restrict__ Ew3, const float* __restrict__ b3,
        const _Float16* __restrict__ Rw1, _Float16* __restrict__ G,
        unsigned* __restrict__ GM) {
    __shared__ __align__(16) unsigned char arena[149504];
    _Float16* sF1  = (_Float16*)arena;             // [128][72]  = 18432 B (64 ch)
    _Float16* sF2  = (_Float16*)(arena + 18432);   // [128][136] = 34816 B (128 ch)
    _Float16* sF3  = (_Float16*)(arena + 53248);   // [128][264] = 67584 B (256 ch)
    _Float16* sBst = (_Float16*)(arena + 120832);  // up to [256][56] = 28672 B
    __shared__ float sW1[192];
    __shared__ float sB1[64];
    __shared__ unsigned smax[256];
    int t = threadIdx.x;
    int w = t >> 6, lane = t & 63;
    int m = lane & 15, quad = lane >> 4;
    int wq = w & 1, wn = w >> 1;
    int P0 = blockIdx.x * 128;          // global point row
    int bb = P0 >> 12;
    int p0in = P0 & (NPTS - 1);

    if (t < 192) sW1[t] = w1[t];
    if (t < 64)  sB1[t] = b1[t];
    smax[t] = 0u;
    __syncthreads();

    // ---- l1: f1 = relu(W1 @ pts + b1) -> sF1 ----
    {
        int pt = t >> 1;
        int cs = (t & 1) * 32;
        const float* pb = pts + (size_t)bb * 3 * NPTS + p0in;
        float px = pb[pt], py = pb[NPTS + pt], pz = pb[2 * NPTS + pt];
        #pragma unroll 8
        for (int c = cs; c < cs + 32; c++) {
            float v = fmaf(sW1[c*3+0], px,
                      fmaf(sW1[c*3+1], py,
                      fmaf(sW1[c*3+2], pz, sB1[c])));
            sF1[pt * 72 + c] = (_Float16)fmaxf(v, 0.f);
        }
    }

    // ---- l2: f2(128pt x 128ch) = relu(Ew2 @ f1 + b2) -> sF2 ----
    {
        v4f acc[4][4];
        #pragma unroll
        for (int i = 0; i < 4; i++)
            #pragma unroll
            for (int j = 0; j < 4; j++)
                acc[i][j] = (v4f){0.f, 0.f, 0.f, 0.f};
        for (int kc = 0; kc < 64; kc += 32) {
            __syncthreads();    // first iter: covers sF1 writes; later: sBst reuse
            {
                #pragma unroll
                for (int i = 0; i < 2; i++) {   // 128 rows x 4 segs = 512; 2/thread
                    int e = t + i * 256;
                    int r = e >> 2, p = e & 3;
                    *(float4*)&sBst[r * 56 + p * 8] =
                        *(const float4*)&Ew2[(size_t)r * 64 + kc + p * 8];
                }
            }
            __syncthreads();
            h8 af[4], bf[4];
            #pragma unroll
            for (int mt = 0; mt < 4; mt++)
                af[mt] = *(const h8*)&sF1[(wq * 64 + mt * 16 + m) * 72 + kc + quad * 8];
            #pragma unroll
            for (int nt = 0; nt < 4; nt++)
                bf[nt] = *(const h8*)&sBst[(wn * 64 + nt * 16 + m) * 56 + quad * 8];
            #pragma unroll
            for (int mt = 0; mt < 4; mt++)
                #pragma unroll
                for (int nt = 0; nt < 4; nt++)
                    acc[mt][nt] = __builtin_amdgcn_mfma_f32_16x16x32_f16(
                            af[mt], bf[nt], acc[mt][nt], 0, 0, 0);
        }
        #pragma unroll
        for (int nt = 0; nt < 4; nt++) {
            int ch = wn * 64 + nt * 16 + m;
            float bb2 = b2[ch];
            #pragma unroll
            for (int mt = 0; mt < 4; mt++) {
                #pragma unroll
                for (int r = 0; r < 4; r++) {
                    int ptl = wq * 64 + mt * 16 + quad * 4 + r;
                    sF2[ptl * 136 + ch] = (_Float16)fmaxf(acc[mt][nt][r] + bb2, 0.f);
                }
            }
        }
    }

    // ---- l3: f3(128pt x 256ch) = relu(Ew3 @ f2 + b3) -> sF3 + max ----
    {
        v4f acc[4][8];
        #pragma unroll
        for (int i = 0; i < 4; i++)
            #pragma unroll
            for (int j = 0; j < 8; j++)
                acc[i][j] = (v4f){0.f, 0.f, 0.f, 0.f};
        for (int kc = 0; kc < 128; kc += 32) {
            __syncthreads();    // first iter: covers sF2 writes; later: sBst reuse
            {
                #pragma unroll
                for (int i = 0; i < 4; i++) {   // 256 rows x 4 segs = 1024; 4/thread
                    int e = t + i * 256;
                    int r = e >> 2, p = e & 3;
                    *(float4*)&sBst[r * 56 + p * 8] =
                        *(const float4*)&Ew3[(size_t)r * 128 + kc + p * 8];
                }
            }
            __syncthreads();
            h8 af[4], bf[8];
            #pragma unroll
            for (int mt = 0; mt < 4; mt++)
                af[mt] = *(const h8*)&sF2[(wq * 64 + mt * 16 + m) * 136 + kc + quad * 8];
            #pragma unroll
            for (int nt = 0; nt < 8; nt++)
                bf[nt] = *(const h8*)&sBst[(wn * 128 + nt * 16 + m) * 56 + quad * 8];
            #pragma unroll
            for (int mt = 0; mt < 4; mt++)
                #pragma unroll
                for (int nt = 0; nt < 8; nt++)
                    acc[mt][nt] = __builtin_amdgcn_mfma_f32_16x16x32_f16(
                            af[mt], bf[nt], acc[mt][nt], 0, 0, 0);
        }
        #pragma unroll
        for (int nt = 0; nt < 8; nt++) {
            int ch = wn * 128 + nt * 16 + m;
            float bb3 = b3[ch];
            float vmax = 0.f;
            #pragma unroll
            for (int mt = 0; mt < 4; mt++) {
                #pragma unroll
                for (int r = 0; r < 4; r++) {
                    int ptl = wq * 64 + mt * 16 + quad * 4 + r;
                    float v = fmaxf(acc[mt][nt][r] + bb3, 0.f);
                    vmax = fmaxf(vmax, v);
                    sF3[ptl * 264 + ch] = (_Float16)v;
                }
            }
            atomicMax(&smax[ch], __float_as_uint(vmax));
        }
        __syncthreads();
        atomicMax(GM + bb * 256 + t, smax[t]);
    }

    // ---- G-GEMM: G[128pt][256] = Rw1[256x448] @ [sF1|sF2|sF3], kc chunks of 32 ----
    {
        v4f acc[4][8];
        #pragma unroll
        for (int i = 0; i < 4; i++)
            #pragma unroll
            for (int j = 0; j < 8; j++)
                acc[i][j] = (v4f){0.f, 0.f, 0.f, 0.f};
        #pragma unroll
        for (int kc = 0; kc < FCATC; kc += 32) {
            __syncthreads();    // sBst reuse (first iter: already synced above)
            #pragma unroll
            for (int i = 0; i < 4; i++) {       // 256 rows x 4 segs = 1024; 4/thread
                int e = t + i * 256;
                int r = e >> 2, p = e & 3;
                *(float4*)&sBst[r * 56 + p * 8] =
                    *(const float4*)&Rw1[(size_t)r * FCATC + kc + p * 8];
            }
            __syncthreads();
            h8 af[4], bf[8];
            #pragma unroll
            for (int mt = 0; mt < 4; mt++) {
                int row = wq * 64 + mt * 16 + m;
                if (kc < 64)
                    af[mt] = *(const h8*)&sF1[row * 72 + kc + quad * 8];
                else if (kc < 192)
                    af[mt] = *(const h8*)&sF2[row * 136 + (kc - 64) + quad * 8];
                else
                    af[mt] = *(const h8*)&sF3[row * 264 + (kc - 192) + quad * 8];
            }
            #pragma unroll
            for (int nt = 0; nt < 8; nt++)
                bf[nt] = *(const h8*)&sBst[(wn * 128 + nt * 16 + m) * 56 + quad * 8];
            #pragma unroll
            for (int mt = 0; mt < 4; mt++)
                #pragma unroll
                for (int nt = 0; nt < 8; nt++)
                    acc[mt][nt] = __builtin_amdgcn_mfma_f32_16x16x32_f16(
                            af[mt], bf[nt], acc[mt][nt], 0, 0, 0);
        }
        #pragma unroll
        for (int nt = 0; nt < 8; nt++) {
            int ch = wn * 128 + nt * 16 + m;
            #pragma unroll
            for (int mt = 0; mt < 4; mt++) {
                #pragma unroll
                for (int r = 0; r < 4; r++) {
                    int ptl = wq * 64 + mt * 16 + quad * 4 + r;
                    G[(size_t)(P0 + ptl) * 256 + ch] = (_Float16)acc[mt][nt][r];
                }
            }
        }
    }
}

// ---------------- KNN: round-0 branchy structure + DISTRIBUTED CB rider ----------------
// Grid is exactly 512 blocks = (b, o) pairs; each block computes its own cb[b][o]
// (one coalesced 256-dot, reduced in spd scratch before the main loop uses it).
// No extra block -> no slot-starved tail (2 blocks/CU x 256 CU = 512 slots).
__global__ __launch_bounds__(512) void k_knn(const float* __restrict__ opts,
        const float* __restrict__ qpts, int* __restrict__ knn_idx,
        float* __restrict__ knn_w,
        const float* __restrict__ r1, const float* __restrict__ rb1,
        const float* __restrict__ gm, float* __restrict__ cb) {
    __shared__ float4 sp[NPTS];       // 64 KB
    __shared__ float spd[3][8][64];
    __shared__ int   spi[3][8][64];
    int t = threadIdx.x;
    int b = blockIdx.x >> 8;
    int q0 = (blockIdx.x & 255) << 6;
    const float* ob = opts + b * 3 * NPTS;
    // CB rider, phase 1: per-thread products into spd scratch (coalesced 1 KB reads)
    {
        int o = blockIdx.x & 255;
        if (t < 256) {
            float pv = r1[(size_t)o * 707 + 451 + t] * gm[b * 256 + t];
            ((float*)spd)[t] = pv;
        }
    }
    for (int i = t; i < NPTS; i += 512) {
        float x = ob[i], y = ob[NPTS + i], z = ob[2 * NPTS + i];
        float o2 = __fadd_rn(__fadd_rn(__fmul_rn(x, x), __fmul_rn(y, y)), __fmul_rn(z, z));
        sp[i] = make_float4(x, y, z, o2);
    }
    __syncthreads();    // covers sp staging AND rider partials
    // CB rider, phase 2: tree reduce (spd not otherwise used until after main loop)
    if (t < 64) {
        const float* pv = (const float*)spd;
        float s = (pv[t] + pv[t + 64]) + (pv[t + 128] + pv[t + 192]);
        #pragma unroll
        for (int off = 32; off > 0; off >>= 1)
            s += __shfl_down(s, off);
        if (t == 0) {
            int o = blockIdx.x & 255;
            cb[b * 256 + o] = rb1[o] + s;
        }
    }
    int lane = t & 63;
    int w = t >> 6;
    int q = q0 + lane;
    float qx = qpts[b * 3 * NQ + q];
    float qy = qpts[b * 3 * NQ + NQ + q];
    float qz = qpts[b * 3 * NQ + 2 * NQ + q];
    float q2 = __fadd_rn(__fadd_rn(__fmul_rn(qx, qx), __fmul_rn(qy, qy)), __fmul_rn(qz, qz));

    int base = w << 9;
    float d0 = 1e30f, d1 = 1e30f, d2v = 1e30f;
    int i0 = 0, i1 = 0, i2 = 0;
    float e0 = 1e30f, e1 = 1e30f, e2v = 1e30f;
    int j0 = 0, j1 = 0, j2 = 0;
    #pragma unroll 2
    for (int k = 0; k < 256; k++) {
        int na = base + k, nb2 = base + 256 + k;
        float4 pa = sp[na];
        float4 pb = sp[nb2];
        float cra = __fadd_rn(__fadd_rn(__fmul_rn(qx, pa.x), __fmul_rn(qy, pa.y)), __fmul_rn(qz, pa.z));
        float da = __fsub_rn(__fadd_rn(q2, pa.w), __fmul_rn(2.f, cra));
        float crb = __fadd_rn(__fadd_rn(__fmul_rn(qx, pb.x), __fmul_rn(qy, pb.y)), __fmul_rn(qz, pb.z));
        float db = __fsub_rn(__fadd_rn(q2, pb.w), __fmul_rn(2.f, crb));
        if (da < d2v) {                 // strict <: ascending idx keeps earlier on ties
            if (da < d1) {
                d2v = d1; i2 = i1;
                if (da < d0) { d1 = d0; i1 = i0; d0 = da; i0 = na; }
                else         { d1 = da; i1 = na; }
            } else { d2v = da; i2 = na; }
        }
        if (db < e2v) {
            if (db < e1) {
                e2v = e1; j2 = j1;
                if (db < e0) { e1 = e0; j1 = j0; e0 = db; j0 = nb2; }
                else         { e1 = db; j1 = nb2; }
            } else { e2v = db; j2 = nb2; }
        }
    }
    // merge chain B into A (lexicographic (d, idx) preserves top_k stability)
    {
        float md[3] = {e0, e1, e2v};
        int   mi[3] = {j0, j1, j2};
        #pragma unroll
        for (int m = 0; m < 3; m++) {
            float d = md[m]; int i = mi[m];
            if (d < d2v || (d == d2v && i < i2)) {
                if (d < d1 || (d == d1 && i < i1)) {
                    d2v = d1; i2 = i1;
                    if (d < d0 || (d == d0 && i < i0)) { d1 = d0; i1 = i0; d0 = d; i0 = i; }
                    else { d1 = d; i1 = i; }
                } else { d2v = d; i2 = i; }
            }
        }
    }
    __syncthreads();    // rider reduce done reading spd before we overwrite it
    spd[0][w][lane] = d0;  spi[0][w][lane] = i0;
    spd[1][w][lane] = d1;  spi[1][w][lane] = i1;
    spd[2][w][lane] = d2v; spi[2][w][lane] = i2;
    __syncthreads();
    if (t < 64) {
        d0 = spd[0][0][t]; i0 = spi[0][0][t];
        d1 = spd[1][0][t]; i1 = spi[1][0][t];
        d2v = spd[2][0][t]; i2 = spi[2][0][t];
        for (int p = 1; p < 8; p++) {
            #pragma unroll
            for (int m = 0; m < 3; m++) {
                float d = spd[m][p][t]; int i = spi[m][p][t];
                if (d < d2v || (d == d2v && i < i2)) {
                    if (d < d1 || (d == d1 && i < i1)) {
                        d2v = d1; i2 = i1;
                        if (d < d0 || (d == d0 && i < i0)) { d1 = d0; i1 = i0; d0 = d; i0 = i; }
                        else { d1 = d; i1 = i; }
                    } else { d2v = d; i2 = i; }
                }
            }
        }
        int ids[3] = {i0, i1, i2};
        float r[3];
        float s = 0.f;
        #pragma unroll
        for (int m = 0; m < 3; m++) {
            float4 p = sp[ids[m]];
            float dx = __fsub_rn(p.x, qx), dy = __fsub_rn(p.y, qy), dz = __fsub_rn(p.z, qz);
            float dd = __fadd_rn(__fadd_rn(__fmul_rn(dx, dx), __fmul_rn(dy, dy)), __fmul_rn(dz, dz));
            float dist = sqrtf(dd);
            r[m] = 1.f / (__fadd_rn(dist, 1e-8f));
            s += r[m];
        }
        int basei = (b * NQ + q) * 3;
        #pragma unroll
        for (int m = 0; m < 3; m++) {
            knn_idx[basei + m] = ids[m];
            knn_w[basei + m]   = r[m] / s;
        }
    }
}

// ---------------- k_tail: fused interp(r1-gather) + r2 + r3 + r4, 64 queries/block ----
__global__ __launch_bounds__(256) void k_tail(
        const float* __restrict__ qpts, const _Float16* __restrict__ G,
        const float* __restrict__ CB, const int* __restrict__ knn_idx,
        const float* __restrict__ knn_w, const float* __restrict__ r1,
        const _Float16* __restrict__ Rw2, const float* __restrict__ rb2,
        const _Float16* __restrict__ Rw3, const float* __restrict__ rb3,
        const float* __restrict__ r4, const float* __restrict__ rb4,
        float* __restrict__ out) {
    __shared__ __align__(16) unsigned char arena[48128];
    _Float16* sH1  = (_Float16*)arena;             // [64][264] = 33792 B
    _Float16* sBst = (_Float16*)(arena + 33792);   // r2 B-stage [128][56] = 14336 B
    _Float16* sH2  = (_Float16*)arena;             // [64][136] = 17408 (aliases sH1)
    _Float16* sH3  = (_Float16*)(arena + 17408);   // [64][72]  = 9216
    _Float16* sW3  = (_Float16*)(arena + 33792);   // r3 W-stage [64][56] = 7168
    __shared__ int   s_id[192];
    __shared__ float s_wt[192];
    __shared__ float s_qp[3][64];
    __shared__ float s_wq[3][256];
    __shared__ float s_cb[256];
    __shared__ float sw4[64];
    int t = threadIdx.x;
    int w = t >> 6, lane = t & 63;
    int m = lane & 15, quad = lane >> 4;
    int q0 = blockIdx.x * 64;
    int b = q0 >> 14;
    int qin = q0 & (NQ - 1);

    if (t < 192) {
        s_id[t] = knn_idx[q0 * 3 + t];
        s_wt[t] = knn_w[q0 * 3 + t];
        int d = t >> 6, j = t & 63;
        s_qp[d][j] = qpts[(size_t)b * 3 * NQ + d * NQ + qin + j];
    }
    s_wq[0][t] = r1[(size_t)t * 707 + 0];
    s_wq[1][t] = r1[(size_t)t * 707 + 1];
    s_wq[2][t] = r1[(size_t)t * 707 + 2];
    s_cb[t] = CB[b * 256 + t];
    if (t < 64) sw4[t] = r4[t];
    __syncthreads();

    // ---- interp: build h1 tile [64 q][256 ch] in LDS (same fmaf order as before) ----
    {
        int cg = (t & 31) * 8;
        int js = t >> 5;
        float wq0[8], wq1[8], wq2[8], cbv[8];
        #pragma unroll
        for (int u = 0; u < 8; u++) {
            wq0[u] = s_wq[0][cg + u];
            wq1[u] = s_wq[1][cg + u];
            wq2[u] = s_wq[2][cg + u];
            cbv[u] = s_cb[cg + u];
        }
        const _Float16* Gb = G + (size_t)b * NPTS * 256;
        #pragma unroll
        for (int jj = 0; jj < 8; jj++) {
            int j = js + jj * 8;
            int i0 = s_id[j * 3 + 0], i1 = s_id[j * 3 + 1], i2 = s_id[j * 3 + 2];
            float w0 = s_wt[j * 3 + 0], w1 = s_wt[j * 3 + 1], w2 = s_wt[j * 3 + 2];
            float qx = s_qp[0][j], qy = s_qp[1][j], qz = s_qp[2][j];
            h8 g0 = *(const h8*)&Gb[(size_t)i0 * 256 + cg];
            h8 g1 = *(const h8*)&Gb[(size_t)i1 * 256 + cg];
            h8 g2 = *(const h8*)&Gb[(size_t)i2 * 256 + cg];
            h8 hv;
            #pragma unroll
            for (int u = 0; u < 8; u++) {
                float acc = cbv[u];
                acc = fmaf(wq0[u], qx, acc);
                acc = fmaf(wq1[u], qy, acc);
                acc = fmaf(wq2[u], qz, acc);
                acc = fmaf(w0, (float)g0[u], acc);
                acc = fmaf(w1, (float)g1[u], acc);
                acc = fmaf(w2, (float)g2[u], acc);
                hv[u] = (_Float16)fmaxf(acc, 0.f);
            }
            *(h8*)&sH1[j * 264 + cg] = hv;
        }
    }

    // ---- r2: h2(64q x 128ch) = relu(Rw2 @ h1); A-frags straight from sH1 ----
    float h2v[4][2][4];
    {
        v4f acc[4][2];
        #pragma unroll
        for (int i = 0; i < 4; i++)
            #pragma unroll
            for (int j = 0; j < 2; j++)
                acc[i][j] = (v4f){0.f, 0.f, 0.f, 0.f};
        for (int kc = 0; kc < 256; kc += 32) {
            __syncthreads();   // first: sH1 writes; later: sBst reuse
            #pragma unroll
            for (int i = 0; i < 2; i++) {
                int e = t + i * 256;
                int r = e >> 2, p = e & 3;
                *(float4*)&sBst[r * 56 + p * 8] =
                    *(const float4*)&Rw2[(size_t)r * 256 + kc + p * 8];
            }
            __syncthreads();
            h8 af[4], bf[2];
            #pragma unroll
            for (int mt = 0; mt < 4; mt++)
                af[mt] = *(const h8*)&sH1[(mt * 16 + m) * 264 + kc + quad * 8];
            #pragma unroll
            for (int nt = 0; nt < 2; nt++)
                bf[nt] = *(const h8*)&sBst[(w * 32 + nt * 16 + m) * 56 + quad * 8];
            #pragma unroll
            for (int mt = 0; mt < 4; mt++)
                #pragma unroll
                for (int nt = 0; nt < 2; nt++)
                    acc[mt][nt] = __builtin_amdgcn_mfma_f32_16x16x32_f16(
                            af[mt], bf[nt], acc[mt][nt], 0, 0, 0);
        }
        #pragma unroll
        for (int nt = 0; nt < 2; nt++) {
            int ch = w * 32 + nt * 16 + m;
            float bb2 = rb2[ch];
            #pragma unroll
            for (int mt = 0; mt < 4; mt++)
                #pragma unroll
                for (int r = 0; r < 4; r++)
                    h2v[mt][nt][r] = fmaxf(acc[mt][nt][r] + bb2, 0.f);
        }
    }
    __syncthreads();   // all sH1 reads done -> safe to overwrite with sH2
    {
        #pragma unroll
        for (int nt = 0; nt < 2; nt++) {
            int ch = w * 32 + nt * 16 + m;
            #pragma unroll
            for (int mt = 0; mt < 4; mt++)
                #pragma unroll
                for (int r = 0; r < 4; r++) {
                    int ql = mt * 16 + quad * 4 + r;
                    sH2[ql * 136 + ch] = (_Float16)h2v[mt][nt][r];
                }
        }
    }

    // ---- r3: h3(64q x 64ch) = relu(Rw3 @ h2) ----
    float h3v[4][4];
    {
        v4f acc[4];
        #pragma unroll
        for (int i = 0; i < 4; i++) acc[i] = (v4f){0.f, 0.f, 0.f, 0.f};
        for (int kc = 0; kc < 128; kc += 32) {
            __syncthreads();   // first: sH2 writes; later: sW3 reuse
            if (t < 256) {     // 64 rows x 4 segs = 256; 1 per thread
                int r = t >> 2, p = t & 3;
                *(float4*)&sW3[r * 56 + p * 8] =
                    *(const float4*)&Rw3[(size_t)r * 128 + kc + p * 8];
            }
            __syncthreads();
            h8 af[4], bf;
            #pragma unroll
            for (int mt = 0; mt < 4; mt++)
                af[mt] = *(const h8*)&sH2[(mt * 16 + m) * 136 + kc + quad * 8];
            bf = *(const h8*)&sW3[(w * 16 + m) * 56 + quad * 8];
            #pragma unroll
            for (int mt = 0; mt < 4; mt++)
                acc[mt] = __builtin_amdgcn_mfma_f32_16x16x32_f16(
                        af[mt], bf, acc[mt], 0, 0, 0);
        }
        int ch = w * 16 + m;
        float bb3 = rb3[ch];
        #pragma unroll
        for (int mt = 0; mt < 4; mt++)
            #pragma unroll
            for (int r = 0; r < 4; r++)
                h3v[mt][r] = fmaxf(acc[mt][r] + bb3, 0.f);
    }
    __syncthreads();
    {
        int ch = w * 16 + m;
        #pragma unroll
        for (int mt = 0; mt < 4; mt++)
            #pragma unroll
            for (int r = 0; r < 4; r++) {
                int ql = mt * 16 + quad * 4 + r;
                sH3[ch * 72 + ql] = (_Float16)h3v[mt][r];
            }
    }
    __syncthreads();

    // ---- r4: out = r4 . h3 + rb4 ----
    if (t < 64) {
        float acc = rb4[0];
        #pragma unroll 16
        for (int c = 0; c < 64; c++)
            acc = fmaf((float)sH3[c * 72 + t], sw4[c], acc);
        out[q0 + t] = acc;
    }
}

extern "C" void kernel_launch(void* const* d_in, const int* in_sizes, int n_in,
                              void* d_out, int out_size, void* d_ws, size_t ws_size,
                              hipStream_t stream) {
    const float* opts = (const float*)d_in[0];
    const float* qpts = (const float*)d_in[1];
    const float* w1  = (const float*)d_in[2];
    const float* b1  = (const float*)d_in[3];
    const float* w2  = (const float*)d_in[4];
    const float* b2  = (const float*)d_in[5];
    const float* w3  = (const float*)d_in[6];
    const float* b3  = (const float*)d_in[7];
    const float* r1  = (const float*)d_in[8];
    const float* rb1 = (const float*)d_in[9];
    const float* r2  = (const float*)d_in[10];
    const float* rb2 = (const float*)d_in[11];
    const float* r3  = (const float*)d_in[12];
    const float* rb3 = (const float*)d_in[13];
    const float* r4  = (const float*)d_in[14];
    const float* rb4 = (const float*)d_in[15];
    float* out = (float*)d_out;

    unsigned char* p = (unsigned char*)d_ws;
    float* GM = (float*)p;          p += (size_t)NB * 256 * 4;
    float* CB = (float*)p;          p += (size_t)NB * 256 * 4;
    int*   IDX = (int*)p;           p += (size_t)NB * NQ * 3 * 4;
    float* WT = (float*)p;          p += (size_t)NB * NQ * 3 * 4;
    _Float16* Rw1 = (_Float16*)p;   p += (size_t)256 * FCATC * 2;
    _Float16* Rw2 = (_Float16*)p;   p += (size_t)128 * 256 * 2;
    _Float16* Rw3 = (_Float16*)p;   p += (size_t)64 * 128 * 2;
    _Float16* Ew2 = (_Float16*)p;   p += (size_t)128 * 64 * 2;
    _Float16* Ew3 = (_Float16*)p;   p += (size_t)256 * 128 * 2;
    _Float16* G = (_Float16*)p;     p += (size_t)NB * NPTS * 256 * 2;

    k_pre<<<769, 256, 0, stream>>>(r1, r2, r3, w2, w3, Rw1, Rw2, Rw3, Ew2, Ew3, GM);
    // fe also produces G (old k_gemm folded in); Fcat never touches global
    k_fe<<<NB * NPTS / 128, 256, 0, stream>>>(opts, w1, b1, Ew2, b2, Ew3, b3,
                                              Rw1, G, (unsigned*)GM);
    // knn with distributed per-block CB rider (grid exactly 512 = 2 blocks/CU slots)
    k_knn<<<512, 512, 0, stream>>>(opts, qpts, IDX, WT, r1, rb1, GM, CB);
    k_tail<<<QTOT / 64, 256, 0, stream>>>(qpts, G, CB, IDX, WT, r1,
                                          Rw2, rb2, Rw3, rb3, r4, rb4, out);
}

// Round 4
// 180.672 us; speedup vs baseline: 1.1448x; 1.0230x over previous
//
#include <hip/hip_runtime.h>
#include <math.h>

#define NB 2
#define NPTS 4096
#define NQ 16384
#define QTOT (NB * NQ)   // 32768 queries, batch folded into row index
#define FCATC 448        // 64+128+256 concatenated feature channels per point

typedef _Float16 h8 __attribute__((ext_vector_type(8)));
typedef float v4f __attribute__((ext_vector_type(4)));

// ---------------- k_pre: weight casts + GM zero + knn A-table build ----------------
// Atab[b][p][32] f16 MFMA A-slot vector per point:
//  k0..2 = -2*ph, k3..5 = -2*pl, k6..8 = -2*ph, k9 = o2h, k10 = o2l, k11 = k12 = 1, rest 0
// paired with query B-slots [qh,qh,ql(.,.,z),1,1,q2h,q2l] so acc = q2+o2-2*cross (~1e-5 err).
__global__ __launch_bounds__(256) void k_pre(
        const float* __restrict__ r1, const float* __restrict__ r2,
        const float* __restrict__ r3, const float* __restrict__ w2,
        const float* __restrict__ w3, const float* __restrict__ opts,
        _Float16* __restrict__ Rw1, _Float16* __restrict__ Rw2,
        _Float16* __restrict__ Rw3, _Float16* __restrict__ Ew2,
        _Float16* __restrict__ Ew3, _Float16* __restrict__ Atab,
        float* __restrict__ GM) {
    int blk = blockIdx.x;
    int t = threadIdx.x;
    if (blk < 768) {
        int g = blk * 256 + t;
        if (g < 114688) {                       // Rw1 = r1[:,3:451] (256 x 448)
            int o = g / FCATC, k = g - o * FCATC;
            Rw1[g] = (_Float16)r1[(size_t)o * 707 + 3 + k];
        } else if (g < 147456) {                // Rw2 = r2 (128x256)
            int i = g - 114688;
            Rw2[i] = (_Float16)r2[i];
        } else if (g < 155648) {                // Rw3 = r3 (64x128)
            int i = g - 147456;
            Rw3[i] = (_Float16)r3[i];
        } else if (g < 163840) {                // Ew2 = w2 (128x64)
            int i = g - 155648;
            Ew2[i] = (_Float16)w2[i];
        } else {                                // Ew3 = w3 (256x128)
            int i = g - 163840;
            Ew3[i] = (_Float16)w3[i];
        }
    } else if (blk == 768) {
        GM[t] = 0.f;
        GM[256 + t] = 0.f;
    } else {                                    // blocks 769..800: Atab (8192 points)
        int gi = (blk - 769) * 256 + t;
        int bb = gi >> 12, pp = gi & (NPTS - 1);
        const float* ob = opts + (size_t)bb * 3 * NPTS;
        float x = ob[pp], y = ob[NPTS + pp], z = ob[2 * NPTS + pp];
        float o2 = __fadd_rn(__fadd_rn(__fmul_rn(x, x), __fmul_rn(y, y)), __fmul_rn(z, z));
        _Float16 xh = (_Float16)x, yh = (_Float16)y, zh = (_Float16)z;
        _Float16 xl = (_Float16)(x - (float)xh);
        _Float16 yl = (_Float16)(y - (float)yh);
        _Float16 zl = (_Float16)(z - (float)zh);
        _Float16 o2h = (_Float16)o2;
        _Float16 o2l = (_Float16)(o2 - (float)o2h);
        _Float16 nxh = (_Float16)(-2.f * (float)xh);   // exact pow2 scale
        _Float16 nyh = (_Float16)(-2.f * (float)yh);
        _Float16 nzh = (_Float16)(-2.f * (float)zh);
        _Float16 nxl = (_Float16)(-2.f * (float)xl);
        _Float16 nyl = (_Float16)(-2.f * (float)yl);
        _Float16 nzl = (_Float16)(-2.f * (float)zl);
        h8 v0, v1, vz;
        v0[0] = nxh; v0[1] = nyh; v0[2] = nzh; v0[3] = nxl;
        v0[4] = nyl; v0[5] = nzl; v0[6] = nxh; v0[7] = nyh;
        v1[0] = nzh; v1[1] = o2h; v1[2] = o2l; v1[3] = (_Float16)1.f;
        v1[4] = (_Float16)1.f; v1[5] = (_Float16)0.f; v1[6] = (_Float16)0.f; v1[7] = (_Float16)0.f;
        #pragma unroll
        for (int i = 0; i < 8; i++) vz[i] = (_Float16)0.f;
        _Float16* dst = Atab + (size_t)gi * 32;
        *(h8*)dst = v0;
        *(h8*)(dst + 8) = v1;
        *(h8*)(dst + 16) = vz;
        *(h8*)(dst + 24) = vz;
    }
}

// ---------------- k_fe: fused l1 + l2 + l3 + global-max + G-GEMM, 128 points/block ----
// Keeps f1/f2/f3 entirely in LDS and computes G[pt][256] = Rw1 @ [f1|f2|f3] in-block
// (bit-identical to the old separate k_gemm: same f16 operands, same kc chunk order).
__global__ __launch_bounds__(256) void k_fe(const float* __restrict__ pts,
        const float* __restrict__ w1, const float* __restrict__ b1,
        const _Float16* __restrict__ Ew2, const float* __restrict__ b2,
        const _Float16* __restrict__ Ew3, const float* __restrict__ b3,
        const _Float16* __restrict__ Rw1, _Float16* __restrict__ G,
        unsigned* __restrict__ GM) {
    __shared__ __align__(16) unsigned char arena[149504];
    _Float16* sF1  = (_Float16*)arena;             // [128][72]  = 18432 B (64 ch)
    _Float16* sF2  = (_Float16*)(arena + 18432);   // [128][136] = 34816 B (128 ch)
    _Float16* sF3  = (_Float16*)(arena + 53248);   // [128][264] = 67584 B (256 ch)
    _Float16* sBst = (_Float16*)(arena + 120832);  // up to [256][56] = 28672 B
    __shared__ float sW1[192];
    __shared__ float sB1[64];
    __shared__ unsigned smax[256];
    int t = threadIdx.x;
    int w = t >> 6, lane = t & 63;
    int m = lane & 15, quad = lane >> 4;
    int wq = w & 1, wn = w >> 1;
    int P0 = blockIdx.x * 128;          // global point row
    int bb = P0 >> 12;
    int p0in = P0 & (NPTS - 1);

    if (t < 192) sW1[t] = w1[t];
    if (t < 64)  sB1[t] = b1[t];
    smax[t] = 0u;
    __syncthreads();

    // ---- l1: f1 = relu(W1 @ pts + b1) -> sF1 ----
    {
        int pt = t >> 1;
        int cs = (t & 1) * 32;
        const float* pb = pts + (size_t)bb * 3 * NPTS + p0in;
        float px = pb[pt], py = pb[NPTS + pt], pz = pb[2 * NPTS + pt];
        #pragma unroll 8
        for (int c = cs; c < cs + 32; c++) {
            float v = fmaf(sW1[c*3+0], px,
                      fmaf(sW1[c*3+1], py,
                      fmaf(sW1[c*3+2], pz, sB1[c])));
            sF1[pt * 72 + c] = (_Float16)fmaxf(v, 0.f);
        }
    }

    // ---- l2: f2(128pt x 128ch) = relu(Ew2 @ f1 + b2) -> sF2 ----
    {
        v4f acc[4][4];
        #pragma unroll
        for (int i = 0; i < 4; i++)
            #pragma unroll
            for (int j = 0; j < 4; j++)
                acc[i][j] = (v4f){0.f, 0.f, 0.f, 0.f};
        for (int kc = 0; kc < 64; kc += 32) {
            __syncthreads();    // first iter: covers sF1 writes; later: sBst reuse
            {
                #pragma unroll
                for (int i = 0; i < 2; i++) {   // 128 rows x 4 segs = 512; 2/thread
                    int e = t + i * 256;
                    int r = e >> 2, p = e & 3;
                    *(float4*)&sBst[r * 56 + p * 8] =
                        *(const float4*)&Ew2[(size_t)r * 64 + kc + p * 8];
                }
            }
            __syncthreads();
            h8 af[4], bf[4];
            #pragma unroll
            for (int mt = 0; mt < 4; mt++)
                af[mt] = *(const h8*)&sF1[(wq * 64 + mt * 16 + m) * 72 + kc + quad * 8];
            #pragma unroll
            for (int nt = 0; nt < 4; nt++)
                bf[nt] = *(const h8*)&sBst[(wn * 64 + nt * 16 + m) * 56 + quad * 8];
            #pragma unroll
            for (int mt = 0; mt < 4; mt++)
                #pragma unroll
                for (int nt = 0; nt < 4; nt++)
                    acc[mt][nt] = __builtin_amdgcn_mfma_f32_16x16x32_f16(
                            af[mt], bf[nt], acc[mt][nt], 0, 0, 0);
        }
        #pragma unroll
        for (int nt = 0; nt < 4; nt++) {
            int ch = wn * 64 + nt * 16 + m;
            float bb2 = b2[ch];
            #pragma unroll
            for (int mt = 0; mt < 4; mt++) {
                #pragma unroll
                for (int r = 0; r < 4; r++) {
                    int ptl = wq * 64 + mt * 16 + quad * 4 + r;
                    sF2[ptl * 136 + ch] = (_Float16)fmaxf(acc[mt][nt][r] + bb2, 0.f);
                }
            }
        }
    }

    // ---- l3: f3(128pt x 256ch) = relu(Ew3 @ f2 + b3) -> sF3 + max ----
    {
        v4f acc[4][8];
        #pragma unroll
        for (int i = 0; i < 4; i++)
            #pragma unroll
            for (int j = 0; j < 8; j++)
                acc[i][j] = (v4f){0.f, 0.f, 0.f, 0.f};
        for (int kc = 0; kc < 128; kc += 32) {
            __syncthreads();    // first iter: covers sF2 writes; later: sBst reuse
            {
                #pragma unroll
                for (int i = 0; i < 4; i++) {   // 256 rows x 4 segs = 1024; 4/thread
                    int e = t + i * 256;
                    int r = e >> 2, p = e & 3;
                    *(float4*)&sBst[r * 56 + p * 8] =
                        *(const float4*)&Ew3[(size_t)r * 128 + kc + p * 8];
                }
            }
            __syncthreads();
            h8 af[4], bf[8];
            #pragma unroll
            for (int mt = 0; mt < 4; mt++)
                af[mt] = *(const h8*)&sF2[(wq * 64 + mt * 16 + m) * 136 + kc + quad * 8];
            #pragma unroll
            for (int nt = 0; nt < 8; nt++)
                bf[nt] = *(const h8*)&sBst[(wn * 128 + nt * 16 + m) * 56 + quad * 8];
            #pragma unroll
            for (int mt = 0; mt < 4; mt++)
                #pragma unroll
                for (int nt = 0; nt < 8; nt++)
                    acc[mt][nt] = __builtin_amdgcn_mfma_f32_16x16x32_f16(
                            af[mt], bf[nt], acc[mt][nt], 0, 0, 0);
        }
        #pragma unroll
        for (int nt = 0; nt < 8; nt++) {
            int ch = wn * 128 + nt * 16 + m;
            float bb3 = b3[ch];
            float vmax = 0.f;
            #pragma unroll
            for (int mt = 0; mt < 4; mt++) {
                #pragma unroll
                for (int r = 0; r < 4; r++) {
                    int ptl = wq * 64 + mt * 16 + quad * 4 + r;
                    float v = fmaxf(acc[mt][nt][r] + bb3, 0.f);
                    vmax = fmaxf(vmax, v);
                    sF3[ptl * 264 + ch] = (_Float16)v;
                }
            }
            atomicMax(&smax[ch], __float_as_uint(vmax));
        }
        __syncthreads();
        atomicMax(GM + bb * 256 + t, smax[t]);
    }

    // ---- G-GEMM: G[128pt][256] = Rw1[256x448] @ [sF1|sF2|sF3], kc chunks of 32 ----
    {
        v4f acc[4][8];
        #pragma unroll
        for (int i = 0; i < 4; i++)
            #pragma unroll
            for (int j = 0; j < 8; j++)
                acc[i][j] = (v4f){0.f, 0.f, 0.f, 0.f};
        #pragma unroll
        for (int kc = 0; kc < FCATC; kc += 32) {
            __syncthreads();    // sBst reuse (first iter: already synced above)
            #pragma unroll
            for (int i = 0; i < 4; i++) {       // 256 rows x 4 segs = 1024; 4/thread
                int e = t + i * 256;
                int r = e >> 2, p = e & 3;
                *(float4*)&sBst[r * 56 + p * 8] =
                    *(const float4*)&Rw1[(size_t)r * FCATC + kc + p * 8];
            }
            __syncthreads();
            h8 af[4], bf[8];
            #pragma unroll
            for (int mt = 0; mt < 4; mt++) {
                int row = wq * 64 + mt * 16 + m;
                if (kc < 64)
                    af[mt] = *(const h8*)&sF1[row * 72 + kc + quad * 8];
                else if (kc < 192)
                    af[mt] = *(const h8*)&sF2[row * 136 + (kc - 64) + quad * 8];
                else
                    af[mt] = *(const h8*)&sF3[row * 264 + (kc - 192) + quad * 8];
            }
            #pragma unroll
            for (int nt = 0; nt < 8; nt++)
                bf[nt] = *(const h8*)&sBst[(wn * 128 + nt * 16 + m) * 56 + quad * 8];
            #pragma unroll
            for (int mt = 0; mt < 4; mt++)
                #pragma unroll
                for (int nt = 0; nt < 8; nt++)
                    acc[mt][nt] = __builtin_amdgcn_mfma_f32_16x16x32_f16(
                            af[mt], bf[nt], acc[mt][nt], 0, 0, 0);
        }
        #pragma unroll
        for (int nt = 0; nt < 8; nt++) {
            int ch = wn * 128 + nt * 16 + m;
            #pragma unroll
            for (int mt = 0; mt < 4; mt++) {
                #pragma unroll
                for (int r = 0; r < 4; r++) {
                    int ptl = wq * 64 + mt * 16 + quad * 4 + r;
                    G[(size_t)(P0 + ptl) * 256 + ch] = (_Float16)acc[mt][nt][r];
                }
            }
        }
    }
}

// ---------------- KNN: MFMA distance tiles + per-lane top-3 + exact top-4 re-rank ----
// Block = 512 thr = 8 waves, 16 queries/wave -> 128 q/block; grid 256 = QTOT/128.
// Layout verified by k_fe's working MFMA code: A row=lane&15 (point), k-chunk=(lane>>4)*8;
// B col=lane&15 (query); C row(point)=(lane>>4)*4+r, col(query)=lane&15.
// Approx d2 from MFMA (err ~1e-5); per-lane top-3 (branchy insert, proven fastest),
// lex merge across the 4 lanes/query into top-4, then EXACT f32 re-rank of the 4
// candidates with the reference formula + (d,idx) tie rule -> exact indices.
#define LEXLT(dx, ix, dy, iy) ((dx) < (dy) || ((dx) == (dy) && (ix) < (iy)))
__global__ __launch_bounds__(512) void k_knn(const float* __restrict__ opts,
        const float* __restrict__ qpts, const _Float16* __restrict__ Atab,
        int* __restrict__ knn_idx, float* __restrict__ knn_w,
        const float* __restrict__ r1, const float* __restrict__ rb1,
        const float* __restrict__ gm, float* __restrict__ cb) {
    __shared__ float scr[512];
    int t = threadIdx.x;
    int blk = blockIdx.x;
    int b = blk >> 7;
    int q0b = (blk & 127) << 7;          // 128 queries per block
    // ---- CB rider: this block computes cb[b][2*(blk&127)] and +1 ----
    {
        int g = t >> 8, c = t & 255;
        int o = (blk & 127) * 2 + g;
        scr[t] = r1[(size_t)o * 707 + 451 + c] * gm[b * 256 + c];
    }
    __syncthreads();
    if (t < 128) {
        int g = t >> 6, ln = t & 63;
        const float* s_ = scr + g * 256;
        float s = (s_[ln] + s_[ln + 64]) + (s_[ln + 128] + s_[ln + 192]);
        #pragma unroll
        for (int off = 32; off > 0; off >>= 1) s += __shfl_down(s, off);
        if (ln == 0) {
            int o = (blk & 127) * 2 + g;
            cb[b * 256 + o] = rb1[o] + s;
        }
    }
    // ---- per-lane setup ----
    int w = t >> 6, l = t & 63;
    int qcol = q0b + w * 16 + (l & 15);
    int g4 = (l >> 4) * 4;
    const float* qb = qpts + (size_t)b * 3 * NQ;
    float qx = qb[qcol], qy = qb[NQ + qcol], qz = qb[2 * NQ + qcol];
    float q2 = __fadd_rn(__fadd_rn(__fmul_rn(qx, qx), __fmul_rn(qy, qy)), __fmul_rn(qz, qz));
    h8 bq;
    #pragma unroll
    for (int i = 0; i < 8; i++) bq[i] = (_Float16)0.f;
    {
        _Float16 qh0 = (_Float16)qx, qh1 = (_Float16)qy, qh2 = (_Float16)qz;
        _Float16 ql0 = (_Float16)(qx - (float)qh0);
        _Float16 ql1 = (_Float16)(qy - (float)qh1);
        _Float16 ql2 = (_Float16)(qz - (float)qh2);
        _Float16 q2h = (_Float16)q2;
        _Float16 q2lo = (_Float16)(q2 - (float)q2h);
        int g = l >> 4;
        if (g == 0) {
            bq[0] = qh0; bq[1] = qh1; bq[2] = qh2;
            bq[3] = qh0; bq[4] = qh1; bq[5] = qh2;
            bq[6] = ql0; bq[7] = ql1;
        } else if (g == 1) {
            bq[0] = ql2; bq[1] = (_Float16)1.f; bq[2] = (_Float16)1.f;
            bq[3] = q2h; bq[4] = q2lo;
        }
    }
    v4f zacc = (v4f){0.f, 0.f, 0.f, 0.f};
    float d0 = 1e30f, d1 = 1e30f, d2v = 1e30f;
    int i0 = 0, i1 = 0, i2 = 0;
    // ---- main loop: 256 point-tiles, 2-deep pipelined A loads (coalesced, L2-hot) ----
    const _Float16* ap = Atab + (size_t)b * NPTS * 32
                       + (size_t)(l & 15) * 32 + (size_t)(l >> 4) * 8;
    h8 aA = *(const h8*)ap;
    h8 aB = *(const h8*)(ap + 512);
    for (int pt = 0; pt < 256; pt += 2) {
        v4f dva = __builtin_amdgcn_mfma_f32_16x16x32_f16(aA, bq, zacc, 0, 0, 0);
        int pn = pt + 2 < 256 ? pt + 2 : 254;   // tail: dup load, unused
        aA = *(const h8*)(ap + (size_t)pn * 512);
        #pragma unroll
        for (int r = 0; r < 4; r++) {
            float da = dva[r];
            if (da < d2v) {
                int na = pt * 16 + g4 + r;
                if (da < d1) {
                    d2v = d1; i2 = i1;
                    if (da < d0) { d1 = d0; i1 = i0; d0 = da; i0 = na; }
                    else         { d1 = da; i1 = na; }
                } else { d2v = da; i2 = na; }
            }
        }
        v4f dvb = __builtin_amdgcn_mfma_f32_16x16x32_f16(aB, bq, zacc, 0, 0, 0);
        int pm = pt + 3 < 256 ? pt + 3 : 255;
        aB = *(const h8*)(ap + (size_t)pm * 512);
        #pragma unroll
        for (int r = 0; r < 4; r++) {
            float da = dvb[r];
            if (da < d2v) {
                int na = (pt + 1) * 16 + g4 + r;
                if (da < d1) {
                    d2v = d1; i2 = i1;
                    if (da < d0) { d1 = d0; i1 = i0; d0 = da; i0 = na; }
                    else         { d1 = da; i1 = na; }
                } else { d2v = da; i2 = na; }
            }
        }
    }
    // ---- merge the 4 lanes per query (xor16 then xor32) into lex top-4 ----
    float c0 = d0, c1 = d1, c2 = d2v, c3 = 1e30f;
    int   k0 = i0, k1 = i1, k2 = i2, k3 = 0x7fffffff;
#define INS4(dd, ii) do { float _d = (dd); int _i = (ii);                      \
    if (LEXLT(_d, _i, c3, k3)) {                                              \
        if (LEXLT(_d, _i, c2, k2)) { c3 = c2; k3 = k2;                        \
            if (LEXLT(_d, _i, c1, k1)) { c2 = c1; k2 = k1;                    \
                if (LEXLT(_d, _i, c0, k0)) { c1 = c0; k1 = k0; c0 = _d; k0 = _i; } \
                else { c1 = _d; k1 = _i; }                                    \
            } else { c2 = _d; k2 = _i; }                                      \
        } else { c3 = _d; k3 = _i; }                                          \
    } } while (0)
    {
        float e0 = __shfl_xor(d0, 16), e1 = __shfl_xor(d1, 16), e2 = __shfl_xor(d2v, 16);
        int   j0 = __shfl_xor(i0, 16), j1 = __shfl_xor(i1, 16), j2 = __shfl_xor(i2, 16);
        INS4(e0, j0); INS4(e1, j1); INS4(e2, j2);
    }
    {
        float e0 = __shfl_xor(c0, 32), e1 = __shfl_xor(c1, 32),
              e2 = __shfl_xor(c2, 32), e3 = __shfl_xor(c3, 32);
        int   j0 = __shfl_xor(k0, 32), j1 = __shfl_xor(k1, 32),
              j2 = __shfl_xor(k2, 32), j3 = __shfl_xor(k3, 32);
        INS4(e0, j0); INS4(e1, j1); INS4(e2, j2); INS4(e3, j3);
    }
    // ---- exact re-rank of the 4 candidates (reference f32 formula, lex ties) ----
    const float* ob = opts + (size_t)b * 3 * NPTS;
    float t0 = 1e30f, t1 = 1e30f, t2 = 1e30f;
    int   u0 = 0x7fffffff, u1 = 0x7fffffff, u2 = 0x7fffffff;
#define INS3X(dd, ii) do { float _d = (dd); int _i = (ii);                     \
    if (LEXLT(_d, _i, t2, u2)) {                                              \
        if (LEXLT(_d, _i, t1, u1)) { t2 = t1; u2 = u1;                        \
            if (LEXLT(_d, _i, t0, u0)) { t1 = t0; u1 = u0; t0 = _d; u0 = _i; } \
            else { t1 = _d; u1 = _i; }                                        \
        } else { t2 = _d; u2 = _i; }                                          \
    } } while (0)
#define EXACTD(idx, dout) do { int _p = (idx);                                 \
    float px = ob[_p], py = ob[NPTS + _p], pz = ob[2 * NPTS + _p];             \
    float o2x = __fadd_rn(__fadd_rn(__fmul_rn(px, px), __fmul_rn(py, py)), __fmul_rn(pz, pz)); \
    float cr  = __fadd_rn(__fadd_rn(__fmul_rn(qx, px), __fmul_rn(qy, py)), __fmul_rn(qz, pz)); \
    dout = __fsub_rn(__fadd_rn(q2, o2x), __fmul_rn(2.f, cr)); } while (0)
    {
        float dx0, dx1, dx2, dx3;
        EXACTD(k0, dx0); EXACTD(k1, dx1); EXACTD(k2, dx2); EXACTD(k3, dx3);
        INS3X(dx0, k0); INS3X(dx1, k1); INS3X(dx2, k2); INS3X(dx3, k3);
    }
    // ---- weights + output (lanes 0..15 of each wave; groups hold identical results) ----
    if ((l >> 4) == 0) {
        int ids[3] = {u0, u1, u2};
        float rr[3];
        float s = 0.f;
        #pragma unroll
        for (int mm = 0; mm < 3; mm++) {
            int ii = ids[mm];
            float px = ob[ii], py = ob[NPTS + ii], pz = ob[2 * NPTS + ii];
            float dx = __fsub_rn(px, qx), dy = __fsub_rn(py, qy), dz = __fsub_rn(pz, qz);
            float dd = __fadd_rn(__fadd_rn(__fmul_rn(dx, dx), __fmul_rn(dy, dy)), __fmul_rn(dz, dz));
            float dist = sqrtf(dd);
            rr[mm] = 1.f / (__fadd_rn(dist, 1e-8f));
            s += rr[mm];
        }
        int basei = (b * NQ + qcol) * 3;
        #pragma unroll
        for (int mm = 0; mm < 3; mm++) {
            knn_idx[basei + mm] = ids[mm];
            knn_w[basei + mm]   = rr[mm] / s;
        }
    }
}

// ---------------- k_tail: fused interp(r1-gather) + r2 + r3 + r4, 64 queries/block ----
__global__ __launch_bounds__(256) void k_tail(
        const float* __restrict__ qpts, const _Float16* __restrict__ G,
        const float* __restrict__ CB, const int* __restrict__ knn_idx,
        const float* __restrict__ knn_w, const float* __restrict__ r1,
        const _Float16* __restrict__ Rw2, const float* __restrict__ rb2,
        const _Float16* __restrict__ Rw3, const float* __restrict__ rb3,
        const float* __restrict__ r4, const float* __restrict__ rb4,
        float* __restrict__ out) {
    __shared__ __align__(16) unsigned char arena[48128];
    _Float16* sH1  = (_Float16*)arena;             // [64][264] = 33792 B
    _Float16* sBst = (_Float16*)(arena + 33792);   // r2 B-stage [128][56] = 14336 B
    _Float16* sH2  = (_Float16*)arena;             // [64][136] = 17408 (aliases sH1)
    _Float16* sH3  = (_Float16*)(arena + 17408);   // [64][72]  = 9216
    _Float16* sW3  = (_Float16*)(arena + 33792);   // r3 W-stage [64][56] = 7168
    __shared__ int   s_id[192];
    __shared__ float s_wt[192];
    __shared__ float s_qp[3][64];
    __shared__ float s_wq[3][256];
    __shared__ float s_cb[256];
    __shared__ float sw4[64];
    int t = threadIdx.x;
    int w = t >> 6, lane = t & 63;
    int m = lane & 15, quad = lane >> 4;
    int q0 = blockIdx.x * 64;
    int b = q0 >> 14;
    int qin = q0 & (NQ - 1);

    if (t < 192) {
        s_id[t] = knn_idx[q0 * 3 + t];
        s_wt[t] = knn_w[q0 * 3 + t];
        int d = t >> 6, j = t & 63;
        s_qp[d][j] = qpts[(size_t)b * 3 * NQ + d * NQ + qin + j];
    }
    s_wq[0][t] = r1[(size_t)t * 707 + 0];
    s_wq[1][t] = r1[(size_t)t * 707 + 1];
    s_wq[2][t] = r1[(size_t)t * 707 + 2];
    s_cb[t] = CB[b * 256 + t];
    if (t < 64) sw4[t] = r4[t];
    __syncthreads();

    // ---- interp: build h1 tile [64 q][256 ch] in LDS (same fmaf order as before) ----
    {
        int cg = (t & 31) * 8;
        int js = t >> 5;
        float wq0[8], wq1[8], wq2[8], cbv[8];
        #pragma unroll
        for (int u = 0; u < 8; u++) {
            wq0[u] = s_wq[0][cg + u];
            wq1[u] = s_wq[1][cg + u];
            wq2[u] = s_wq[2][cg + u];
            cbv[u] = s_cb[cg + u];
        }
        const _Float16* Gb = G + (size_t)b * NPTS * 256;
        #pragma unroll
        for (int jj = 0; jj < 8; jj++) {
            int j = js + jj * 8;
            int i0 = s_id[j * 3 + 0], i1 = s_id[j * 3 + 1], i2 = s_id[j * 3 + 2];
            float w0 = s_wt[j * 3 + 0], w1 = s_wt[j * 3 + 1], w2 = s_wt[j * 3 + 2];
            float qx = s_qp[0][j], qy = s_qp[1][j], qz = s_qp[2][j];
            h8 g0 = *(const h8*)&Gb[(size_t)i0 * 256 + cg];
            h8 g1 = *(const h8*)&Gb[(size_t)i1 * 256 + cg];
            h8 g2 = *(const h8*)&Gb[(size_t)i2 * 256 + cg];
            h8 hv;
            #pragma unroll
            for (int u = 0; u < 8; u++) {
                float acc = cbv[u];
                acc = fmaf(wq0[u], qx, acc);
                acc = fmaf(wq1[u], qy, acc);
                acc = fmaf(wq2[u], qz, acc);
                acc = fmaf(w0, (float)g0[u], acc);
                acc = fmaf(w1, (float)g1[u], acc);
                acc = fmaf(w2, (float)g2[u], acc);
                hv[u] = (_Float16)fmaxf(acc, 0.f);
            }
            *(h8*)&sH1[j * 264 + cg] = hv;
        }
    }

    // ---- r2: h2(64q x 128ch) = relu(Rw2 @ h1); A-frags straight from sH1 ----
    float h2v[4][2][4];
    {
        v4f acc[4][2];
        #pragma unroll
        for (int i = 0; i < 4; i++)
            #pragma unroll
            for (int j = 0; j < 2; j++)
                acc[i][j] = (v4f){0.f, 0.f, 0.f, 0.f};
        for (int kc = 0; kc < 256; kc += 32) {
            __syncthreads();   // first: sH1 writes; later: sBst reuse
            #pragma unroll
            for (int i = 0; i < 2; i++) {
                int e = t + i * 256;
                int r = e >> 2, p = e & 3;
                *(float4*)&sBst[r * 56 + p * 8] =
                    *(const float4*)&Rw2[(size_t)r * 256 + kc + p * 8];
            }
            __syncthreads();
            h8 af[4], bf[2];
            #pragma unroll
            for (int mt = 0; mt < 4; mt++)
                af[mt] = *(const h8*)&sH1[(mt * 16 + m) * 264 + kc + quad * 8];
            #pragma unroll
            for (int nt = 0; nt < 2; nt++)
                bf[nt] = *(const h8*)&sBst[(w * 32 + nt * 16 + m) * 56 + quad * 8];
            #pragma unroll
            for (int mt = 0; mt < 4; mt++)
                #pragma unroll
                for (int nt = 0; nt < 2; nt++)
                    acc[mt][nt] = __builtin_amdgcn_mfma_f32_16x16x32_f16(
                            af[mt], bf[nt], acc[mt][nt], 0, 0, 0);
        }
        #pragma unroll
        for (int nt = 0; nt < 2; nt++) {
            int ch = w * 32 + nt * 16 + m;
            float bb2 = rb2[ch];
            #pragma unroll
            for (int mt = 0; mt < 4; mt++)
                #pragma unroll
                for (int r = 0; r < 4; r++)
                    h2v[mt][nt][r] = fmaxf(acc[mt][nt][r] + bb2, 0.f);
        }
    }
    __syncthreads();   // all sH1 reads done -> safe to overwrite with sH2
    {
        #pragma unroll
        for (int nt = 0; nt < 2; nt++) {
            int ch = w * 32 + nt * 16 + m;
            #pragma unroll
            for (int mt = 0; mt < 4; mt++)
                #pragma unroll
                for (int r = 0; r < 4; r++) {
                    int ql = mt * 16 + quad * 4 + r;
                    sH2[ql * 136 + ch] = (_Float16)h2v[mt][nt][r];
                }
        }
    }

    // ---- r3: h3(64q x 64ch) = relu(Rw3 @ h2) ----
    float h3v[4][4];
    {
        v4f acc[4];
        #pragma unroll
        for (int i = 0; i < 4; i++) acc[i] = (v4f){0.f, 0.f, 0.f, 0.f};
        for (int kc = 0; kc < 128; kc += 32) {
            __syncthreads();   // first: sH2 writes; later: sW3 reuse
            if (t < 256) {     // 64 rows x 4 segs = 256; 1 per thread
                int r = t >> 2, p = t & 3;
                *(float4*)&sW3[r * 56 + p * 8] =
                    *(const float4*)&Rw3[(size_t)r * 128 + kc + p * 8];
            }
            __syncthreads();
            h8 af[4], bf;
            #pragma unroll
            for (int mt = 0; mt < 4; mt++)
                af[mt] = *(const h8*)&sH2[(mt * 16 + m) * 136 + kc + quad * 8];
            bf = *(const h8*)&sW3[(w * 16 + m) * 56 + quad * 8];
            #pragma unroll
            for (int mt = 0; mt < 4; mt++)
                acc[mt] = __builtin_amdgcn_mfma_f32_16x16x32_f16(
                        af[mt], bf, acc[mt], 0, 0, 0);
        }
        int ch = w * 16 + m;
        float bb3 = rb3[ch];
        #pragma unroll
        for (int mt = 0; mt < 4; mt++)
            #pragma unroll
            for (int r = 0; r < 4; r++)
                h3v[mt][r] = fmaxf(acc[mt][r] + bb3, 0.f);
    }
    __syncthreads();
    {
        int ch = w * 16 + m;
        #pragma unroll
        for (int mt = 0; mt < 4; mt++)
            #pragma unroll
            for (int r = 0; r < 4; r++) {
                int ql = mt * 16 + quad * 4 + r;
                sH3[ch * 72 + ql] = (_Float16)h3v[mt][r];
            }
    }
    __syncthreads();

    // ---- r4: out = r4 . h3 + rb4 ----
    if (t < 64) {
        float acc = rb4[0];
        #pragma unroll 16
        for (int c = 0; c < 64; c++)
            acc = fmaf((float)sH3[c * 72 + t], sw4[c], acc);
        out[q0 + t] = acc;
    }
}

extern "C" void kernel_launch(void* const* d_in, const int* in_sizes, int n_in,
                              void* d_out, int out_size, void* d_ws, size_t ws_size,
                              hipStream_t stream) {
    const float* opts = (const float*)d_in[0];
    const float* qpts = (const float*)d_in[1];
    const float* w1  = (const float*)d_in[2];
    const float* b1  = (const float*)d_in[3];
    const float* w2  = (const float*)d_in[4];
    const float* b2  = (const float*)d_in[5];
    const float* w3  = (const float*)d_in[6];
    const float* b3  = (const float*)d_in[7];
    const float* r1  = (const float*)d_in[8];
    const float* rb1 = (const float*)d_in[9];
    const float* r2  = (const float*)d_in[10];
    const float* rb2 = (const float*)d_in[11];
    const float* r3  = (const float*)d_in[12];
    const float* rb3 = (const float*)d_in[13];
    const float* r4  = (const float*)d_in[14];
    const float* rb4 = (const float*)d_in[15];
    float* out = (float*)d_out;

    unsigned char* p = (unsigned char*)d_ws;
    float* GM = (float*)p;          p += (size_t)NB * 256 * 4;
    float* CB = (float*)p;          p += (size_t)NB * 256 * 4;
    int*   IDX = (int*)p;           p += (size_t)NB * NQ * 3 * 4;
    float* WT = (float*)p;          p += (size_t)NB * NQ * 3 * 4;
    _Float16* Rw1 = (_Float16*)p;   p += (size_t)256 * FCATC * 2;
    _Float16* Rw2 = (_Float16*)p;   p += (size_t)128 * 256 * 2;
    _Float16* Rw3 = (_Float16*)p;   p += (size_t)64 * 128 * 2;
    _Float16* Ew2 = (_Float16*)p;   p += (size_t)128 * 64 * 2;
    _Float16* Ew3 = (_Float16*)p;   p += (size_t)256 * 128 * 2;
    _Float16* Atab = (_Float16*)p;  p += (size_t)NB * NPTS * 32 * 2;
    _Float16* G = (_Float16*)p;     p += (size_t)NB * NPTS * 256 * 2;

    k_pre<<<801, 256, 0, stream>>>(r1, r2, r3, w2, w3, opts,
                                   Rw1, Rw2, Rw3, Ew2, Ew3, Atab, GM);
    // fe also produces G (old k_gemm folded in); Fcat never touches global
    k_fe<<<NB * NPTS / 128, 256, 0, stream>>>(opts, w1, b1, Ew2, b2, Ew3, b3,
                                              Rw1, G, (unsigned*)GM);
    // MFMA-tiled knn (256 blocks x 512 thr) with distributed CB rider
    k_knn<<<256, 512, 0, stream>>>(opts, qpts, Atab, IDX, WT, r1, rb1, GM, CB);
    k_tail<<<QTOT / 64, 256, 0, stream>>>(qpts, G, CB, IDX, WT, r1,
                                          Rw2, rb2, Rw3, rb3, r4, rb4, out);
}

// Round 5
// 165.571 us; speedup vs baseline: 1.2492x; 1.0912x over previous
//
#include <hip/hip_runtime.h>
#include <math.h>

#define NB 2
#define NPTS 4096
#define NQ 16384
#define QTOT (NB * NQ)   // 32768 queries, batch folded into row index
#define FCATC 448        // 64+128+256 concatenated feature channels per point

typedef _Float16 h8 __attribute__((ext_vector_type(8)));
typedef _Float16 h4 __attribute__((ext_vector_type(4)));
typedef float v4f __attribute__((ext_vector_type(4)));

// ---------------- k_pre: weight casts + GM zero + knn A-table build (K=16) ----------------
// Atab[b][p][16] f16 MFMA A-slot vector per point (16x16x16 layout, 4 slots/lane-group):
//  s0..2=-2ph(xyz) s3=-2xl | s4=-2yl s5=-2zl s6=-2xh s7=-2yh | s8=-2zh s9=o2h s10=o2l s11=1 | s12=1 s13..15=0
// paired with query B-slots [qh qh qh qh | qh qh ql ql | ql 1 1 q2h | q2l 0 0 0]
// so acc = q2+o2-2*cross with only the ql*pl cross terms dropped (~1e-6 err).
__global__ __launch_bounds__(256) void k_pre(
        const float* __restrict__ r1, const float* __restrict__ r2,
        const float* __restrict__ r3, const float* __restrict__ w2,
        const float* __restrict__ w3, const float* __restrict__ opts,
        _Float16* __restrict__ Rw1, _Float16* __restrict__ Rw2,
        _Float16* __restrict__ Rw3, _Float16* __restrict__ Ew2,
        _Float16* __restrict__ Ew3, _Float16* __restrict__ Atab,
        float* __restrict__ GM) {
    int blk = blockIdx.x;
    int t = threadIdx.x;
    if (blk < 768) {
        int g = blk * 256 + t;
        if (g < 114688) {                       // Rw1 = r1[:,3:451] (256 x 448)
            int o = g / FCATC, k = g - o * FCATC;
            Rw1[g] = (_Float16)r1[(size_t)o * 707 + 3 + k];
        } else if (g < 147456) {                // Rw2 = r2 (128x256)
            int i = g - 114688;
            Rw2[i] = (_Float16)r2[i];
        } else if (g < 155648) {                // Rw3 = r3 (64x128)
            int i = g - 147456;
            Rw3[i] = (_Float16)r3[i];
        } else if (g < 163840) {                // Ew2 = w2 (128x64)
            int i = g - 155648;
            Ew2[i] = (_Float16)w2[i];
        } else {                                // Ew3 = w3 (256x128)
            int i = g - 163840;
            Ew3[i] = (_Float16)w3[i];
        }
    } else if (blk == 768) {
        GM[t] = 0.f;
        GM[256 + t] = 0.f;
    } else {                                    // blocks 769..800: Atab (8192 points)
        int gi = (blk - 769) * 256 + t;
        int bb = gi >> 12, pp = gi & (NPTS - 1);
        const float* ob = opts + (size_t)bb * 3 * NPTS;
        float x = ob[pp], y = ob[NPTS + pp], z = ob[2 * NPTS + pp];
        float o2 = __fadd_rn(__fadd_rn(__fmul_rn(x, x), __fmul_rn(y, y)), __fmul_rn(z, z));
        _Float16 xh = (_Float16)x, yh = (_Float16)y, zh = (_Float16)z;
        _Float16 xl = (_Float16)(x - (float)xh);
        _Float16 yl = (_Float16)(y - (float)yh);
        _Float16 zl = (_Float16)(z - (float)zh);
        _Float16 o2h = (_Float16)o2;
        _Float16 o2l = (_Float16)(o2 - (float)o2h);
        _Float16 nxh = (_Float16)(-2.f * (float)xh);   // exact pow2 scale
        _Float16 nyh = (_Float16)(-2.f * (float)yh);
        _Float16 nzh = (_Float16)(-2.f * (float)zh);
        _Float16 nxl = (_Float16)(-2.f * (float)xl);
        _Float16 nyl = (_Float16)(-2.f * (float)yl);
        _Float16 nzl = (_Float16)(-2.f * (float)zl);
        _Float16 one = (_Float16)1.f, zero = (_Float16)0.f;
        h8 v0, v1;
        v0[0] = nxh; v0[1] = nyh; v0[2] = nzh; v0[3] = nxl;
        v0[4] = nyl; v0[5] = nzl; v0[6] = nxh; v0[7] = nyh;
        v1[0] = nzh; v1[1] = o2h; v1[2] = o2l; v1[3] = one;
        v1[4] = one; v1[5] = zero; v1[6] = zero; v1[7] = zero;
        _Float16* dst = Atab + (size_t)gi * 16;
        *(h8*)dst = v0;
        *(h8*)(dst + 8) = v1;
    }
}

// ---------------- k_fe: fused l1 + l2 + l3 + global-max + G-GEMM, 128 points/block ----
__global__ __launch_bounds__(256) void k_fe(const float* __restrict__ pts,
        const float* __restrict__ w1, const float* __restrict__ b1,
        const _Float16* __restrict__ Ew2, const float* __restrict__ b2,
        const _Float16* __restrict__ Ew3, const float* __restrict__ b3,
        const _Float16* __restrict__ Rw1, _Float16* __restrict__ G,
        unsigned* __restrict__ GM) {
    __shared__ __align__(16) unsigned char arena[149504];
    _Float16* sF1  = (_Float16*)arena;             // [128][72]  = 18432 B (64 ch)
    _Float16* sF2  = (_Float16*)(arena + 18432);   // [128][136] = 34816 B (128 ch)
    _Float16* sF3  = (_Float16*)(arena + 53248);   // [128][264] = 67584 B (256 ch)
    _Float16* sBst = (_Float16*)(arena + 120832);  // up to [256][56] = 28672 B
    __shared__ float sW1[192];
    __shared__ float sB1[64];
    __shared__ unsigned smax[256];
    int t = threadIdx.x;
    int w = t >> 6, lane = t & 63;
    int m = lane & 15, quad = lane >> 4;
    int wq = w & 1, wn = w >> 1;
    int P0 = blockIdx.x * 128;          // global point row
    int bb = P0 >> 12;
    int p0in = P0 & (NPTS - 1);

    if (t < 192) sW1[t] = w1[t];
    if (t < 64)  sB1[t] = b1[t];
    smax[t] = 0u;
    __syncthreads();

    // ---- l1: f1 = relu(W1 @ pts + b1) -> sF1 ----
    {
        int pt = t >> 1;
        int cs = (t & 1) * 32;
        const float* pb = pts + (size_t)bb * 3 * NPTS + p0in;
        float px = pb[pt], py = pb[NPTS + pt], pz = pb[2 * NPTS + pt];
        #pragma unroll 8
        for (int c = cs; c < cs + 32; c++) {
            float v = fmaf(sW1[c*3+0], px,
                      fmaf(sW1[c*3+1], py,
                      fmaf(sW1[c*3+2], pz, sB1[c])));
            sF1[pt * 72 + c] = (_Float16)fmaxf(v, 0.f);
        }
    }

    // ---- l2: f2(128pt x 128ch) = relu(Ew2 @ f1 + b2) -> sF2 ----
    {
        v4f acc[4][4];
        #pragma unroll
        for (int i = 0; i < 4; i++)
            #pragma unroll
            for (int j = 0; j < 4; j++)
                acc[i][j] = (v4f){0.f, 0.f, 0.f, 0.f};
        for (int kc = 0; kc < 64; kc += 32) {
            __syncthreads();    // first iter: covers sF1 writes; later: sBst reuse
            {
                #pragma unroll
                for (int i = 0; i < 2; i++) {   // 128 rows x 4 segs = 512; 2/thread
                    int e = t + i * 256;
                    int r = e >> 2, p = e & 3;
                    *(float4*)&sBst[r * 56 + p * 8] =
                        *(const float4*)&Ew2[(size_t)r * 64 + kc + p * 8];
                }
            }
            __syncthreads();
            h8 af[4], bf[4];
            #pragma unroll
            for (int mt = 0; mt < 4; mt++)
                af[mt] = *(const h8*)&sF1[(wq * 64 + mt * 16 + m) * 72 + kc + quad * 8];
            #pragma unroll
            for (int nt = 0; nt < 4; nt++)
                bf[nt] = *(const h8*)&sBst[(wn * 64 + nt * 16 + m) * 56 + quad * 8];
            #pragma unroll
            for (int mt = 0; mt < 4; mt++)
                #pragma unroll
                for (int nt = 0; nt < 4; nt++)
                    acc[mt][nt] = __builtin_amdgcn_mfma_f32_16x16x32_f16(
                            af[mt], bf[nt], acc[mt][nt], 0, 0, 0);
        }
        #pragma unroll
        for (int nt = 0; nt < 4; nt++) {
            int ch = wn * 64 + nt * 16 + m;
            float bb2 = b2[ch];
            #pragma unroll
            for (int mt = 0; mt < 4; mt++) {
                #pragma unroll
                for (int r = 0; r < 4; r++) {
                    int ptl = wq * 64 + mt * 16 + quad * 4 + r;
                    sF2[ptl * 136 + ch] = (_Float16)fmaxf(acc[mt][nt][r] + bb2, 0.f);
                }
            }
        }
    }

    // ---- l3: f3(128pt x 256ch) = relu(Ew3 @ f2 + b3) -> sF3 + max ----
    {
        v4f acc[4][8];
        #pragma unroll
        for (int i = 0; i < 4; i++)
            #pragma unroll
            for (int j = 0; j < 8; j++)
                acc[i][j] = (v4f){0.f, 0.f, 0.f, 0.f};
        for (int kc = 0; kc < 128; kc += 32) {
            __syncthreads();    // first iter: covers sF2 writes; later: sBst reuse
            {
                #pragma unroll
                for (int i = 0; i < 4; i++) {   // 256 rows x 4 segs = 1024; 4/thread
                    int e = t + i * 256;
                    int r = e >> 2, p = e & 3;
                    *(float4*)&sBst[r * 56 + p * 8] =
                        *(const float4*)&Ew3[(size_t)r * 128 + kc + p * 8];
                }
            }
            __syncthreads();
            h8 af[4], bf[8];
            #pragma unroll
            for (int mt = 0; mt < 4; mt++)
                af[mt] = *(const h8*)&sF2[(wq * 64 + mt * 16 + m) * 136 + kc + quad * 8];
            #pragma unroll
            for (int nt = 0; nt < 8; nt++)
                bf[nt] = *(const h8*)&sBst[(wn * 128 + nt * 16 + m) * 56 + quad * 8];
            #pragma unroll
            for (int mt = 0; mt < 4; mt++)
                #pragma unroll
                for (int nt = 0; nt < 8; nt++)
                    acc[mt][nt] = __builtin_amdgcn_mfma_f32_16x16x32_f16(
                            af[mt], bf[nt], acc[mt][nt], 0, 0, 0);
        }
        #pragma unroll
        for (int nt = 0; nt < 8; nt++) {
            int ch = wn * 128 + nt * 16 + m;
            float bb3 = b3[ch];
            float vmax = 0.f;
            #pragma unroll
            for (int mt = 0; mt < 4; mt++) {
                #pragma unroll
                for (int r = 0; r < 4; r++) {
                    int ptl = wq * 64 + mt * 16 + quad * 4 + r;
                    float v = fmaxf(acc[mt][nt][r] + bb3, 0.f);
                    vmax = fmaxf(vmax, v);
                    sF3[ptl * 264 + ch] = (_Float16)v;
                }
            }
            atomicMax(&smax[ch], __float_as_uint(vmax));
        }
        __syncthreads();
        atomicMax(GM + bb * 256 + t, smax[t]);
    }

    // ---- G-GEMM: G[128pt][256] = Rw1[256x448] @ [sF1|sF2|sF3], kc chunks of 32 ----
    {
        v4f acc[4][8];
        #pragma unroll
        for (int i = 0; i < 4; i++)
            #pragma unroll
            for (int j = 0; j < 8; j++)
                acc[i][j] = (v4f){0.f, 0.f, 0.f, 0.f};
        #pragma unroll
        for (int kc = 0; kc < FCATC; kc += 32) {
            __syncthreads();    // sBst reuse (first iter: already synced above)
            #pragma unroll
            for (int i = 0; i < 4; i++) {       // 256 rows x 4 segs = 1024; 4/thread
                int e = t + i * 256;
                int r = e >> 2, p = e & 3;
                *(float4*)&sBst[r * 56 + p * 8] =
                    *(const float4*)&Rw1[(size_t)r * FCATC + kc + p * 8];
            }
            __syncthreads();
            h8 af[4], bf[8];
            #pragma unroll
            for (int mt = 0; mt < 4; mt++) {
                int row = wq * 64 + mt * 16 + m;
                if (kc < 64)
                    af[mt] = *(const h8*)&sF1[row * 72 + kc + quad * 8];
                else if (kc < 192)
                    af[mt] = *(const h8*)&sF2[row * 136 + (kc - 64) + quad * 8];
                else
                    af[mt] = *(const h8*)&sF3[row * 264 + (kc - 192) + quad * 8];
            }
            #pragma unroll
            for (int nt = 0; nt < 8; nt++)
                bf[nt] = *(const h8*)&sBst[(wn * 128 + nt * 16 + m) * 56 + quad * 8];
            #pragma unroll
            for (int mt = 0; mt < 4; mt++)
                #pragma unroll
                for (int nt = 0; nt < 8; nt++)
                    acc[mt][nt] = __builtin_amdgcn_mfma_f32_16x16x32_f16(
                            af[mt], bf[nt], acc[mt][nt], 0, 0, 0);
        }
        #pragma unroll
        for (int nt = 0; nt < 8; nt++) {
            int ch = wn * 128 + nt * 16 + m;
            #pragma unroll
            for (int mt = 0; mt < 4; mt++) {
                #pragma unroll
                for (int r = 0; r < 4; r++) {
                    int ptl = wq * 64 + mt * 16 + quad * 4 + r;
                    G[(size_t)(P0 + ptl) * 256 + ch] = (_Float16)acc[mt][nt][r];
                }
            }
        }
    }
}

// ---------------- KNN: K=16 MFMA tiles, 4-way point-split, 100% occupancy ----------------
// Grid 1024 blocks x 512 thr (4 blocks/CU = 32 waves/CU). Block = 32 queries (2 tiles).
// Wave w: query-tile tw = w>>2, quarter qtr = w&3 (1024 pts = 64 tiles of 16).
// Per-lane top-3 -> intra-wave top-4 (shfl merges) -> 4-way cross-wave LDS merge (top-4)
// -> exact f32 re-rank of 4 candidates (reference formula, lex ties) -> exact indices.
#define LEXLT(dx, ix, dy, iy) ((dx) < (dy) || ((dx) == (dy) && (ix) < (iy)))
__global__ __launch_bounds__(512) void k_knn(const float* __restrict__ opts,
        const float* __restrict__ qpts, const _Float16* __restrict__ Atab,
        int* __restrict__ knn_idx, float* __restrict__ knn_w,
        const float* __restrict__ r1, const float* __restrict__ rb1,
        const float* __restrict__ gm, float* __restrict__ cb) {
    __shared__ float scr[256];
    __shared__ float md_s[8][16][4];
    __shared__ int   mi_s[8][16][4];
    int t = threadIdx.x;
    int blk = blockIdx.x;
    int b = blk >> 9;                   // 512 blocks per batch
    int q0b = (blk & 511) * 32;         // 32 queries per block
    // ---- CB rider: blocks 0..511 each compute one cb[o_global = blk] ----
    if (blk < 512) {
        int br = blk >> 8, o = blk & 255;
        if (t < 256) scr[t] = r1[(size_t)o * 707 + 451 + t] * gm[br * 256 + t];
        __syncthreads();
        if (t < 64) {
            float s = (scr[t] + scr[t + 64]) + (scr[t + 128] + scr[t + 192]);
            #pragma unroll
            for (int off = 32; off > 0; off >>= 1) s += __shfl_down(s, off);
            if (t == 0) cb[br * 256 + o] = rb1[o] + s;
        }
    }
    // ---- per-lane setup ----
    int w = t >> 6, l = t & 63;
    int g = l >> 4;                     // lane group (k-chunk / C-row group)
    int tw = w >> 2;                    // query tile within block (0/1)
    int qtr = w & 3;                    // point quarter
    int qcol = q0b + tw * 16 + (l & 15);
    const float* qb = qpts + (size_t)b * 3 * NQ;
    float qx = qb[qcol], qy = qb[NQ + qcol], qz = qb[2 * NQ + qcol];
    float q2 = __fadd_rn(__fadd_rn(__fmul_rn(qx, qx), __fmul_rn(qy, qy)), __fmul_rn(qz, qz));
    h4 bq;
    {
        _Float16 qh0 = (_Float16)qx, qh1 = (_Float16)qy, qh2 = (_Float16)qz;
        _Float16 ql0 = (_Float16)(qx - (float)qh0);
        _Float16 ql1 = (_Float16)(qy - (float)qh1);
        _Float16 ql2 = (_Float16)(qz - (float)qh2);
        _Float16 q2h = (_Float16)q2;
        _Float16 q2lo = (_Float16)(q2 - (float)q2h);
        _Float16 one = (_Float16)1.f, zero = (_Float16)0.f;
        if (g == 0)      { bq[0] = qh0; bq[1] = qh1; bq[2] = qh2; bq[3] = qh0; }
        else if (g == 1) { bq[0] = qh1; bq[1] = qh2; bq[2] = ql0; bq[3] = ql1; }
        else if (g == 2) { bq[0] = ql2; bq[1] = one; bq[2] = one; bq[3] = q2h; }
        else             { bq[0] = q2lo; bq[1] = zero; bq[2] = zero; bq[3] = zero; }
    }
    v4f zacc = (v4f){0.f, 0.f, 0.f, 0.f};
    float d0 = 1e30f, d1 = 1e30f, d2v = 1e30f;
    int i0 = 0, i1 = 0, i2 = 0;
    int nb0 = qtr * 1024 + g * 4;       // C row r -> point index nb0 + tile*16 + r
#define INS_TILE(dv, nbase) do {                                               \
    _Pragma("unroll")                                                          \
    for (int r = 0; r < 4; r++) {                                              \
        float da = (dv)[r];                                                    \
        if (da < d2v) {                                                        \
            int na = (nbase) + r;                                              \
            if (da < d1) {                                                     \
                d2v = d1; i2 = i1;                                             \
                if (da < d0) { d1 = d0; i1 = i0; d0 = da; i0 = na; }           \
                else         { d1 = da; i1 = na; }                             \
            } else { d2v = da; i2 = na; }                                      \
        }                                                                      \
    } } while (0)
    // ---- main loop: 64 tiles/quarter, 4-deep register prefetch (8 B/lane coalesced) ----
    const _Float16* ap = Atab + ((size_t)b * NPTS + qtr * 1024) * 16
                       + (size_t)(l & 15) * 16 + (size_t)g * 4;
    h4 a0 = *(const h4*)(ap + 0 * 256);
    h4 a1 = *(const h4*)(ap + 1 * 256);
    h4 a2 = *(const h4*)(ap + 2 * 256);
    h4 a3 = *(const h4*)(ap + 3 * 256);
    for (int tl = 0; tl < 64; tl += 4) {
        v4f dv0 = __builtin_amdgcn_mfma_f32_16x16x16f16(a0, bq, zacc, 0, 0, 0);
        v4f dv1 = __builtin_amdgcn_mfma_f32_16x16x16f16(a1, bq, zacc, 0, 0, 0);
        v4f dv2 = __builtin_amdgcn_mfma_f32_16x16x16f16(a2, bq, zacc, 0, 0, 0);
        v4f dv3 = __builtin_amdgcn_mfma_f32_16x16x16f16(a3, bq, zacc, 0, 0, 0);
        int n0 = tl + 4 < 64 ? tl + 4 : 63;
        int n1 = tl + 5 < 64 ? tl + 5 : 63;
        int n2 = tl + 6 < 64 ? tl + 6 : 63;
        int n3 = tl + 7 < 64 ? tl + 7 : 63;
        a0 = *(const h4*)(ap + (size_t)n0 * 256);
        a1 = *(const h4*)(ap + (size_t)n1 * 256);
        a2 = *(const h4*)(ap + (size_t)n2 * 256);
        a3 = *(const h4*)(ap + (size_t)n3 * 256);
        INS_TILE(dv0, nb0 + (tl + 0) * 16);
        INS_TILE(dv1, nb0 + (tl + 1) * 16);
        INS_TILE(dv2, nb0 + (tl + 2) * 16);
        INS_TILE(dv3, nb0 + (tl + 3) * 16);
    }
    // ---- intra-wave merge (xor16 then xor32) into lex top-4; all lanes hold result ----
    float c0 = d0, c1 = d1, c2 = d2v, c3 = 1e30f;
    int   k0 = i0, k1 = i1, k2 = i2, k3 = 0x7fffffff;
#define INS4(dd, ii) do { float _d = (dd); int _i = (ii);                      \
    if (LEXLT(_d, _i, c3, k3)) {                                              \
        if (LEXLT(_d, _i, c2, k2)) { c3 = c2; k3 = k2;                        \
            if (LEXLT(_d, _i, c1, k1)) { c2 = c1; k2 = k1;                    \
                if (LEXLT(_d, _i, c0, k0)) { c1 = c0; k1 = k0; c0 = _d; k0 = _i; } \
                else { c1 = _d; k1 = _i; }                                    \
            } else { c2 = _d; k2 = _i; }                                      \
        } else { c3 = _d; k3 = _i; }                                          \
    } } while (0)
    {
        float e0 = __shfl_xor(d0, 16), e1 = __shfl_xor(d1, 16), e2 = __shfl_xor(d2v, 16);
        int   j0 = __shfl_xor(i0, 16), j1 = __shfl_xor(i1, 16), j2 = __shfl_xor(i2, 16);
        INS4(e0, j0); INS4(e1, j1); INS4(e2, j2);
    }
    {
        float e0 = __shfl_xor(c0, 32), e1 = __shfl_xor(c1, 32),
              e2 = __shfl_xor(c2, 32), e3 = __shfl_xor(c3, 32);
        int   j0 = __shfl_xor(k0, 32), j1 = __shfl_xor(k1, 32),
              j2 = __shfl_xor(k2, 32), j3 = __shfl_xor(k3, 32);
        INS4(e0, j0); INS4(e1, j1); INS4(e2, j2); INS4(e3, j3);
    }
    // ---- cross-wave 4-way merge via LDS (leader wave of each quarter-group) ----
    if (l < 16) {
        md_s[w][l][0] = c0; md_s[w][l][1] = c1; md_s[w][l][2] = c2; md_s[w][l][3] = c3;
        mi_s[w][l][0] = k0; mi_s[w][l][1] = k1; mi_s[w][l][2] = k2; mi_s[w][l][3] = k3;
    }
    __syncthreads();
    if ((w & 3) == 0) {
        int m16 = l & 15;
        #pragma unroll
        for (int pw = 1; pw < 4; pw++) {
            #pragma unroll
            for (int s = 0; s < 4; s++) {
                float dd = md_s[w + pw][m16][s];
                int ii = mi_s[w + pw][m16][s];
                INS4(dd, ii);
            }
        }
        // ---- exact re-rank of the 4 candidates (reference f32 formula, lex ties) ----
        const float* ob = opts + (size_t)b * 3 * NPTS;
        float t0 = 1e30f, t1 = 1e30f, t2 = 1e30f;
        int   u0 = 0x7fffffff, u1 = 0x7fffffff, u2 = 0x7fffffff;
#define INS3X(dd, ii) do { float _d = (dd); int _i = (ii);                     \
    if (LEXLT(_d, _i, t2, u2)) {                                              \
        if (LEXLT(_d, _i, t1, u1)) { t2 = t1; u2 = u1;                        \
            if (LEXLT(_d, _i, t0, u0)) { t1 = t0; u1 = u0; t0 = _d; u0 = _i; } \
            else { t1 = _d; u1 = _i; }                                        \
        } else { t2 = _d; u2 = _i; }                                          \
    } } while (0)
#define EXACTD(idx, dout) do { int _p = (idx);                                 \
    float px = ob[_p], py = ob[NPTS + _p], pz = ob[2 * NPTS + _p];             \
    float o2x = __fadd_rn(__fadd_rn(__fmul_rn(px, px), __fmul_rn(py, py)), __fmul_rn(pz, pz)); \
    float cr  = __fadd_rn(__fadd_rn(__fmul_rn(qx, px), __fmul_rn(qy, py)), __fmul_rn(qz, pz)); \
    dout = __fsub_rn(__fadd_rn(q2, o2x), __fmul_rn(2.f, cr)); } while (0)
        {
            float dx0, dx1, dx2, dx3;
            EXACTD(k0, dx0); EXACTD(k1, dx1); EXACTD(k2, dx2); EXACTD(k3, dx3);
            INS3X(dx0, k0); INS3X(dx1, k1); INS3X(dx2, k2); INS3X(dx3, k3);
        }
        if (l < 16) {
            int ids[3] = {u0, u1, u2};
            float rr[3];
            float s = 0.f;
            #pragma unroll
            for (int mm = 0; mm < 3; mm++) {
                int ii = ids[mm];
                float px = ob[ii], py = ob[NPTS + ii], pz = ob[2 * NPTS + ii];
                float dx = __fsub_rn(px, qx), dy = __fsub_rn(py, qy), dz = __fsub_rn(pz, qz);
                float dd = __fadd_rn(__fadd_rn(__fmul_rn(dx, dx), __fmul_rn(dy, dy)), __fmul_rn(dz, dz));
                float dist = sqrtf(dd);
                rr[mm] = 1.f / (__fadd_rn(dist, 1e-8f));
                s += rr[mm];
            }
            int basei = (b * NQ + qcol) * 3;
            #pragma unroll
            for (int mm = 0; mm < 3; mm++) {
                knn_idx[basei + mm] = ids[mm];
                knn_w[basei + mm]   = rr[mm] / s;
            }
        }
    }
}

// ---------------- k_tail: fused interp(r1-gather) + r2 + r3 + r4, 64 queries/block ----
__global__ __launch_bounds__(256) void k_tail(
        const float* __restrict__ qpts, const _Float16* __restrict__ G,
        const float* __restrict__ CB, const int* __restrict__ knn_idx,
        const float* __restrict__ knn_w, const float* __restrict__ r1,
        const _Float16* __restrict__ Rw2, const float* __restrict__ rb2,
        const _Float16* __restrict__ Rw3, const float* __restrict__ rb3,
        const float* __restrict__ r4, const float* __restrict__ rb4,
        float* __restrict__ out) {
    __shared__ __align__(16) unsigned char arena[48128];
    _Float16* sH1  = (_Float16*)arena;             // [64][264] = 33792 B
    _Float16* sBst = (_Float16*)(arena + 33792);   // r2 B-stage [128][56] = 14336 B
    _Float16* sH2  = (_Float16*)arena;             // [64][136] = 17408 (aliases sH1)
    _Float16* sH3  = (_Float16*)(arena + 17408);   // [64][72]  = 9216
    _Float16* sW3  = (_Float16*)(arena + 33792);   // r3 W-stage [64][56] = 7168
    __shared__ int   s_id[192];
    __shared__ float s_wt[192];
    __shared__ float s_qp[3][64];
    __shared__ float s_wq[3][256];
    __shared__ float s_cb[256];
    __shared__ float sw4[64];
    int t = threadIdx.x;
    int w = t >> 6, lane = t & 63;
    int m = lane & 15, quad = lane >> 4;
    int q0 = blockIdx.x * 64;
    int b = q0 >> 14;
    int qin = q0 & (NQ - 1);

    if (t < 192) {
        s_id[t] = knn_idx[q0 * 3 + t];
        s_wt[t] = knn_w[q0 * 3 + t];
        int d = t >> 6, j = t & 63;
        s_qp[d][j] = qpts[(size_t)b * 3 * NQ + d * NQ + qin + j];
    }
    s_wq[0][t] = r1[(size_t)t * 707 + 0];
    s_wq[1][t] = r1[(size_t)t * 707 + 1];
    s_wq[2][t] = r1[(size_t)t * 707 + 2];
    s_cb[t] = CB[b * 256 + t];
    if (t < 64) sw4[t] = r4[t];
    __syncthreads();

    // ---- interp: build h1 tile [64 q][256 ch] in LDS (same fmaf order as before) ----
    {
        int cg = (t & 31) * 8;
        int js = t >> 5;
        float wq0[8], wq1[8], wq2[8], cbv[8];
        #pragma unroll
        for (int u = 0; u < 8; u++) {
            wq0[u] = s_wq[0][cg + u];
            wq1[u] = s_wq[1][cg + u];
            wq2[u] = s_wq[2][cg + u];
            cbv[u] = s_cb[cg + u];
        }
        const _Float16* Gb = G + (size_t)b * NPTS * 256;
        #pragma unroll
        for (int jj = 0; jj < 8; jj++) {
            int j = js + jj * 8;
            int i0 = s_id[j * 3 + 0], i1 = s_id[j * 3 + 1], i2 = s_id[j * 3 + 2];
            float w0 = s_wt[j * 3 + 0], w1 = s_wt[j * 3 + 1], w2 = s_wt[j * 3 + 2];
            float qx = s_qp[0][j], qy = s_qp[1][j], qz = s_qp[2][j];
            h8 g0 = *(const h8*)&Gb[(size_t)i0 * 256 + cg];
            h8 g1 = *(const h8*)&Gb[(size_t)i1 * 256 + cg];
            h8 g2 = *(const h8*)&Gb[(size_t)i2 * 256 + cg];
            h8 hv;
            #pragma unroll
            for (int u = 0; u < 8; u++) {
                float acc = cbv[u];
                acc = fmaf(wq0[u], qx, acc);
                acc = fmaf(wq1[u], qy, acc);
                acc = fmaf(wq2[u], qz, acc);
                acc = fmaf(w0, (float)g0[u], acc);
                acc = fmaf(w1, (float)g1[u], acc);
                acc = fmaf(w2, (float)g2[u], acc);
                hv[u] = (_Float16)fmaxf(acc, 0.f);
            }
            *(h8*)&sH1[j * 264 + cg] = hv;
        }
    }

    // ---- r2: h2(64q x 128ch) = relu(Rw2 @ h1); A-frags straight from sH1 ----
    float h2v[4][2][4];
    {
        v4f acc[4][2];
        #pragma unroll
        for (int i = 0; i < 4; i++)
            #pragma unroll
            for (int j = 0; j < 2; j++)
                acc[i][j] = (v4f){0.f, 0.f, 0.f, 0.f};
        for (int kc = 0; kc < 256; kc += 32) {
            __syncthreads();   // first: sH1 writes; later: sBst reuse
            #pragma unroll
            for (int i = 0; i < 2; i++) {
                int e = t + i * 256;
                int r = e >> 2, p = e & 3;
                *(float4*)&sBst[r * 56 + p * 8] =
                    *(const float4*)&Rw2[(size_t)r * 256 + kc + p * 8];
            }
            __syncthreads();
            h8 af[4], bf[2];
            #pragma unroll
            for (int mt = 0; mt < 4; mt++)
                af[mt] = *(const h8*)&sH1[(mt * 16 + m) * 264 + kc + quad * 8];
            #pragma unroll
            for (int nt = 0; nt < 2; nt++)
                bf[nt] = *(const h8*)&sBst[(w * 32 + nt * 16 + m) * 56 + quad * 8];
            #pragma unroll
            for (int mt = 0; mt < 4; mt++)
                #pragma unroll
                for (int nt = 0; nt < 2; nt++)
                    acc[mt][nt] = __builtin_amdgcn_mfma_f32_16x16x32_f16(
                            af[mt], bf[nt], acc[mt][nt], 0, 0, 0);
        }
        #pragma unroll
        for (int nt = 0; nt < 2; nt++) {
            int ch = w * 32 + nt * 16 + m;
            float bb2 = rb2[ch];
            #pragma unroll
            for (int mt = 0; mt < 4; mt++)
                #pragma unroll
                for (int r = 0; r < 4; r++)
                    h2v[mt][nt][r] = fmaxf(acc[mt][nt][r] + bb2, 0.f);
        }
    }
    __syncthreads();   // all sH1 reads done -> safe to overwrite with sH2
    {
        #pragma unroll
        for (int nt = 0; nt < 2; nt++) {
            int ch = w * 32 + nt * 16 + m;
            #pragma unroll
            for (int mt = 0; mt < 4; mt++)
                #pragma unroll
                for (int r = 0; r < 4; r++) {
                    int ql = mt * 16 + quad * 4 + r;
                    sH2[ql * 136 + ch] = (_Float16)h2v[mt][nt][r];
                }
        }
    }

    // ---- r3: h3(64q x 64ch) = relu(Rw3 @ h2) ----
    float h3v[4][4];
    {
        v4f acc[4];
        #pragma unroll
        for (int i = 0; i < 4; i++) acc[i] = (v4f){0.f, 0.f, 0.f, 0.f};
        for (int kc = 0; kc < 128; kc += 32) {
            __syncthreads();   // first: sH2 writes; later: sW3 reuse
            if (t < 256) {     // 64 rows x 4 segs = 256; 1 per thread
                int r = t >> 2, p = t & 3;
                *(float4*)&sW3[r * 56 + p * 8] =
                    *(const float4*)&Rw3[(size_t)r * 128 + kc + p * 8];
            }
            __syncthreads();
            h8 af[4], bf;
            #pragma unroll
            for (int mt = 0; mt < 4; mt++)
                af[mt] = *(const h8*)&sH2[(mt * 16 + m) * 136 + kc + quad * 8];
            bf = *(const h8*)&sW3[(w * 16 + m) * 56 + quad * 8];
            #pragma unroll
            for (int mt = 0; mt < 4; mt++)
                acc[mt] = __builtin_amdgcn_mfma_f32_16x16x32_f16(
                        af[mt], bf, acc[mt], 0, 0, 0);
        }
        int ch = w * 16 + m;
        float bb3 = rb3[ch];
        #pragma unroll
        for (int mt = 0; mt < 4; mt++)
            #pragma unroll
            for (int r = 0; r < 4; r++)
                h3v[mt][r] = fmaxf(acc[mt][r] + bb3, 0.f);
    }
    __syncthreads();
    {
        int ch = w * 16 + m;
        #pragma unroll
        for (int mt = 0; mt < 4; mt++)
            #pragma unroll
            for (int r = 0; r < 4; r++) {
                int ql = mt * 16 + quad * 4 + r;
                sH3[ch * 72 + ql] = (_Float16)h3v[mt][r];
            }
    }
    __syncthreads();

    // ---- r4: out = r4 . h3 + rb4 ----
    if (t < 64) {
        float acc = rb4[0];
        #pragma unroll 16
        for (int c = 0; c < 64; c++)
            acc = fmaf((float)sH3[c * 72 + t], sw4[c], acc);
        out[q0 + t] = acc;
    }
}

extern "C" void kernel_launch(void* const* d_in, const int* in_sizes, int n_in,
                              void* d_out, int out_size, void* d_ws, size_t ws_size,
                              hipStream_t stream) {
    const float* opts = (const float*)d_in[0];
    const float* qpts = (const float*)d_in[1];
    const float* w1  = (const float*)d_in[2];
    const float* b1  = (const float*)d_in[3];
    const float* w2  = (const float*)d_in[4];
    const float* b2  = (const float*)d_in[5];
    const float* w3  = (const float*)d_in[6];
    const float* b3  = (const float*)d_in[7];
    const float* r1  = (const float*)d_in[8];
    const float* rb1 = (const float*)d_in[9];
    const float* r2  = (const float*)d_in[10];
    const float* rb2 = (const float*)d_in[11];
    const float* r3  = (const float*)d_in[12];
    const float* rb3 = (const float*)d_in[13];
    const float* r4  = (const float*)d_in[14];
    const float* rb4 = (const float*)d_in[15];
    float* out = (float*)d_out;

    unsigned char* p = (unsigned char*)d_ws;
    float* GM = (float*)p;          p += (size_t)NB * 256 * 4;
    float* CB = (float*)p;          p += (size_t)NB * 256 * 4;
    int*   IDX = (int*)p;           p += (size_t)NB * NQ * 3 * 4;
    float* WT = (float*)p;          p += (size_t)NB * NQ * 3 * 4;
    _Float16* Rw1 = (_Float16*)p;   p += (size_t)256 * FCATC * 2;
    _Float16* Rw2 = (_Float16*)p;   p += (size_t)128 * 256 * 2;
    _Float16* Rw3 = (_Float16*)p;   p += (size_t)64 * 128 * 2;
    _Float16* Ew2 = (_Float16*)p;   p += (size_t)128 * 64 * 2;
    _Float16* Ew3 = (_Float16*)p;   p += (size_t)256 * 128 * 2;
    _Float16* Atab = (_Float16*)p;  p += (size_t)NB * NPTS * 16 * 2;
    _Float16* G = (_Float16*)p;     p += (size_t)NB * NPTS * 256 * 2;

    k_pre<<<801, 256, 0, stream>>>(r1, r2, r3, w2, w3, opts,
                                   Rw1, Rw2, Rw3, Ew2, Ew3, Atab, GM);
    // fe also produces G (old k_gemm folded in); Fcat never touches global
    k_fe<<<NB * NPTS / 128, 256, 0, stream>>>(opts, w1, b1, Ew2, b2, Ew3, b3,
                                              Rw1, G, (unsigned*)GM);
    // K=16 MFMA knn: 1024 blocks x 512 thr (4 blocks/CU), 4-way point split + LDS merge
    k_knn<<<1024, 512, 0, stream>>>(opts, qpts, Atab, IDX, WT, r1, rb1, GM, CB);
    k_tail<<<QTOT / 64, 256, 0, stream>>>(qpts, G, CB, IDX, WT, r1,
                                          Rw2, rb2, Rw3, rb3, r4, rb4, out);
}

// Round 6
// 165.377 us; speedup vs baseline: 1.2506x; 1.0012x over previous
//
#include <hip/hip_runtime.h>
#include <math.h>

#define NB 2
#define NPTS 4096
#define NQ 16384
#define QTOT (NB * NQ)   // 32768 queries, batch folded into row index
#define FCATC 448        // 64+128+256 concatenated feature channels per point

typedef _Float16 h8 __attribute__((ext_vector_type(8)));
typedef _Float16 h4 __attribute__((ext_vector_type(4)));
typedef float v4f __attribute__((ext_vector_type(4)));

// ---------------- k_pre: weight casts + GM zero + knn A-table build (K=16) ----------------
// Atab[b][p][16] f16 MFMA A-slot vector per point (16x16x16 layout, 4 slots/lane-group):
//  s0..2=-2ph(xyz) s3=-2xl | s4=-2yl s5=-2zl s6=-2xh s7=-2yh | s8=-2zh s9=o2h s10=o2l s11=1 | s12=1 s13..15=0
// paired with query B-slots [qh qh qh qh | qh qh ql ql | ql 1 1 q2h | q2l 0 0 0]
// so acc = q2+o2-2*cross with only the ql*pl cross terms dropped (~1e-6 err).
__global__ __launch_bounds__(256) void k_pre(
        const float* __restrict__ r1, const float* __restrict__ r2,
        const float* __restrict__ r3, const float* __restrict__ w2,
        const float* __restrict__ w3, const float* __restrict__ opts,
        _Float16* __restrict__ Rw1, _Float16* __restrict__ Rw2,
        _Float16* __restrict__ Rw3, _Float16* __restrict__ Ew2,
        _Float16* __restrict__ Ew3, _Float16* __restrict__ Atab,
        float* __restrict__ GM) {
    int blk = blockIdx.x;
    int t = threadIdx.x;
    if (blk < 768) {
        int g = blk * 256 + t;
        if (g < 114688) {                       // Rw1 = r1[:,3:451] (256 x 448)
            int o = g / FCATC, k = g - o * FCATC;
            Rw1[g] = (_Float16)r1[(size_t)o * 707 + 3 + k];
        } else if (g < 147456) {                // Rw2 = r2 (128x256)
            int i = g - 114688;
            Rw2[i] = (_Float16)r2[i];
        } else if (g < 155648) {                // Rw3 = r3 (64x128)
            int i = g - 147456;
            Rw3[i] = (_Float16)r3[i];
        } else if (g < 163840) {                // Ew2 = w2 (128x64)
            int i = g - 155648;
            Ew2[i] = (_Float16)w2[i];
        } else {                                // Ew3 = w3 (256x128)
            int i = g - 163840;
            Ew3[i] = (_Float16)w3[i];
        }
    } else if (blk == 768) {
        GM[t] = 0.f;
        GM[256 + t] = 0.f;
    } else {                                    // blocks 769..800: Atab (8192 points)
        int gi = (blk - 769) * 256 + t;
        int bb = gi >> 12, pp = gi & (NPTS - 1);
        const float* ob = opts + (size_t)bb * 3 * NPTS;
        float x = ob[pp], y = ob[NPTS + pp], z = ob[2 * NPTS + pp];
        float o2 = __fadd_rn(__fadd_rn(__fmul_rn(x, x), __fmul_rn(y, y)), __fmul_rn(z, z));
        _Float16 xh = (_Float16)x, yh = (_Float16)y, zh = (_Float16)z;
        _Float16 xl = (_Float16)(x - (float)xh);
        _Float16 yl = (_Float16)(y - (float)yh);
        _Float16 zl = (_Float16)(z - (float)zh);
        _Float16 o2h = (_Float16)o2;
        _Float16 o2l = (_Float16)(o2 - (float)o2h);
        _Float16 nxh = (_Float16)(-2.f * (float)xh);   // exact pow2 scale
        _Float16 nyh = (_Float16)(-2.f * (float)yh);
        _Float16 nzh = (_Float16)(-2.f * (float)zh);
        _Float16 nxl = (_Float16)(-2.f * (float)xl);
        _Float16 nyl = (_Float16)(-2.f * (float)yl);
        _Float16 nzl = (_Float16)(-2.f * (float)zl);
        _Float16 one = (_Float16)1.f, zero = (_Float16)0.f;
        h8 v0, v1;
        v0[0] = nxh; v0[1] = nyh; v0[2] = nzh; v0[3] = nxl;
        v0[4] = nyl; v0[5] = nzl; v0[6] = nxh; v0[7] = nyh;
        v1[0] = nzh; v1[1] = o2h; v1[2] = o2l; v1[3] = one;
        v1[4] = one; v1[5] = zero; v1[6] = zero; v1[7] = zero;
        _Float16* dst = Atab + (size_t)gi * 16;
        *(h8*)dst = v0;
        *(h8*)(dst + 8) = v1;
    }
}

// ---------------- k_fe: fused l1 + l2 + l3 + global-max + G-GEMM, 128 points/block ----
__global__ __launch_bounds__(256) void k_fe(const float* __restrict__ pts,
        const float* __restrict__ w1, const float* __restrict__ b1,
        const _Float16* __restrict__ Ew2, const float* __restrict__ b2,
        const _Float16* __restrict__ Ew3, const float* __restrict__ b3,
        const _Float16* __restrict__ Rw1, _Float16* __restrict__ G,
        unsigned* __restrict__ GM) {
    __shared__ __align__(16) unsigned char arena[149504];
    _Float16* sF1  = (_Float16*)arena;             // [128][72]  = 18432 B (64 ch)
    _Float16* sF2  = (_Float16*)(arena + 18432);   // [128][136] = 34816 B (128 ch)
    _Float16* sF3  = (_Float16*)(arena + 53248);   // [128][264] = 67584 B (256 ch)
    _Float16* sBst = (_Float16*)(arena + 120832);  // up to [256][56] = 28672 B
    __shared__ float sW1[192];
    __shared__ float sB1[64];
    __shared__ unsigned smax[256];
    int t = threadIdx.x;
    int w = t >> 6, lane = t & 63;
    int m = lane & 15, quad = lane >> 4;
    int wq = w & 1, wn = w >> 1;
    int P0 = blockIdx.x * 128;          // global point row
    int bb = P0 >> 12;
    int p0in = P0 & (NPTS - 1);

    if (t < 192) sW1[t] = w1[t];
    if (t < 64)  sB1[t] = b1[t];
    smax[t] = 0u;
    __syncthreads();

    // ---- l1: f1 = relu(W1 @ pts + b1) -> sF1 ----
    {
        int pt = t >> 1;
        int cs = (t & 1) * 32;
        const float* pb = pts + (size_t)bb * 3 * NPTS + p0in;
        float px = pb[pt], py = pb[NPTS + pt], pz = pb[2 * NPTS + pt];
        #pragma unroll 8
        for (int c = cs; c < cs + 32; c++) {
            float v = fmaf(sW1[c*3+0], px,
                      fmaf(sW1[c*3+1], py,
                      fmaf(sW1[c*3+2], pz, sB1[c])));
            sF1[pt * 72 + c] = (_Float16)fmaxf(v, 0.f);
        }
    }

    // ---- l2: f2(128pt x 128ch) = relu(Ew2 @ f1 + b2) -> sF2 ----
    {
        v4f acc[4][4];
        #pragma unroll
        for (int i = 0; i < 4; i++)
            #pragma unroll
            for (int j = 0; j < 4; j++)
                acc[i][j] = (v4f){0.f, 0.f, 0.f, 0.f};
        for (int kc = 0; kc < 64; kc += 32) {
            __syncthreads();    // first iter: covers sF1 writes; later: sBst reuse
            {
                #pragma unroll
                for (int i = 0; i < 2; i++) {   // 128 rows x 4 segs = 512; 2/thread
                    int e = t + i * 256;
                    int r = e >> 2, p = e & 3;
                    *(float4*)&sBst[r * 56 + p * 8] =
                        *(const float4*)&Ew2[(size_t)r * 64 + kc + p * 8];
                }
            }
            __syncthreads();
            h8 af[4], bf[4];
            #pragma unroll
            for (int mt = 0; mt < 4; mt++)
                af[mt] = *(const h8*)&sF1[(wq * 64 + mt * 16 + m) * 72 + kc + quad * 8];
            #pragma unroll
            for (int nt = 0; nt < 4; nt++)
                bf[nt] = *(const h8*)&sBst[(wn * 64 + nt * 16 + m) * 56 + quad * 8];
            #pragma unroll
            for (int mt = 0; mt < 4; mt++)
                #pragma unroll
                for (int nt = 0; nt < 4; nt++)
                    acc[mt][nt] = __builtin_amdgcn_mfma_f32_16x16x32_f16(
                            af[mt], bf[nt], acc[mt][nt], 0, 0, 0);
        }
        #pragma unroll
        for (int nt = 0; nt < 4; nt++) {
            int ch = wn * 64 + nt * 16 + m;
            float bb2 = b2[ch];
            #pragma unroll
            for (int mt = 0; mt < 4; mt++) {
                #pragma unroll
                for (int r = 0; r < 4; r++) {
                    int ptl = wq * 64 + mt * 16 + quad * 4 + r;
                    sF2[ptl * 136 + ch] = (_Float16)fmaxf(acc[mt][nt][r] + bb2, 0.f);
                }
            }
        }
    }

    // ---- l3: f3(128pt x 256ch) = relu(Ew3 @ f2 + b3) -> sF3 + max ----
    {
        v4f acc[4][8];
        #pragma unroll
        for (int i = 0; i < 4; i++)
            #pragma unroll
            for (int j = 0; j < 8; j++)
                acc[i][j] = (v4f){0.f, 0.f, 0.f, 0.f};
        for (int kc = 0; kc < 128; kc += 32) {
            __syncthreads();    // first iter: covers sF2 writes; later: sBst reuse
            {
                #pragma unroll
                for (int i = 0; i < 4; i++) {   // 256 rows x 4 segs = 1024; 4/thread
                    int e = t + i * 256;
                    int r = e >> 2, p = e & 3;
                    *(float4*)&sBst[r * 56 + p * 8] =
                        *(const float4*)&Ew3[(size_t)r * 128 + kc + p * 8];
                }
            }
            __syncthreads();
            h8 af[4], bf[8];
            #pragma unroll
            for (int mt = 0; mt < 4; mt++)
                af[mt] = *(const h8*)&sF2[(wq * 64 + mt * 16 + m) * 136 + kc + quad * 8];
            #pragma unroll
            for (int nt = 0; nt < 8; nt++)
                bf[nt] = *(const h8*)&sBst[(wn * 128 + nt * 16 + m) * 56 + quad * 8];
            #pragma unroll
            for (int mt = 0; mt < 4; mt++)
                #pragma unroll
                for (int nt = 0; nt < 8; nt++)
                    acc[mt][nt] = __builtin_amdgcn_mfma_f32_16x16x32_f16(
                            af[mt], bf[nt], acc[mt][nt], 0, 0, 0);
        }
        #pragma unroll
        for (int nt = 0; nt < 8; nt++) {
            int ch = wn * 128 + nt * 16 + m;
            float bb3 = b3[ch];
            float vmax = 0.f;
            #pragma unroll
            for (int mt = 0; mt < 4; mt++) {
                #pragma unroll
                for (int r = 0; r < 4; r++) {
                    int ptl = wq * 64 + mt * 16 + quad * 4 + r;
                    float v = fmaxf(acc[mt][nt][r] + bb3, 0.f);
                    vmax = fmaxf(vmax, v);
                    sF3[ptl * 264 + ch] = (_Float16)v;
                }
            }
            atomicMax(&smax[ch], __float_as_uint(vmax));
        }
        __syncthreads();
        atomicMax(GM + bb * 256 + t, smax[t]);
    }

    // ---- G-GEMM: G[128pt][256] = Rw1[256x448] @ [sF1|sF2|sF3], kc chunks of 32 ----
    {
        v4f acc[4][8];
        #pragma unroll
        for (int i = 0; i < 4; i++)
            #pragma unroll
            for (int j = 0; j < 8; j++)
                acc[i][j] = (v4f){0.f, 0.f, 0.f, 0.f};
        #pragma unroll
        for (int kc = 0; kc < FCATC; kc += 32) {
            __syncthreads();    // sBst reuse (first iter: already synced above)
            #pragma unroll
            for (int i = 0; i < 4; i++) {       // 256 rows x 4 segs = 1024; 4/thread
                int e = t + i * 256;
                int r = e >> 2, p = e & 3;
                *(float4*)&sBst[r * 56 + p * 8] =
                    *(const float4*)&Rw1[(size_t)r * FCATC + kc + p * 8];
            }
            __syncthreads();
            h8 af[4], bf[8];
            #pragma unroll
            for (int mt = 0; mt < 4; mt++) {
                int row = wq * 64 + mt * 16 + m;
                if (kc < 64)
                    af[mt] = *(const h8*)&sF1[row * 72 + kc + quad * 8];
                else if (kc < 192)
                    af[mt] = *(const h8*)&sF2[row * 136 + (kc - 64) + quad * 8];
                else
                    af[mt] = *(const h8*)&sF3[row * 264 + (kc - 192) + quad * 8];
            }
            #pragma unroll
            for (int nt = 0; nt < 8; nt++)
                bf[nt] = *(const h8*)&sBst[(wn * 128 + nt * 16 + m) * 56 + quad * 8];
            #pragma unroll
            for (int mt = 0; mt < 4; mt++)
                #pragma unroll
                for (int nt = 0; nt < 8; nt++)
                    acc[mt][nt] = __builtin_amdgcn_mfma_f32_16x16x32_f16(
                            af[mt], bf[nt], acc[mt][nt], 0, 0, 0);
        }
        #pragma unroll
        for (int nt = 0; nt < 8; nt++) {
            int ch = wn * 128 + nt * 16 + m;
            #pragma unroll
            for (int mt = 0; mt < 4; mt++) {
                #pragma unroll
                for (int r = 0; r < 4; r++) {
                    int ptl = wq * 64 + mt * 16 + quad * 4 + r;
                    G[(size_t)(P0 + ptl) * 256 + ch] = (_Float16)acc[mt][nt][r];
                }
            }
        }
    }
}

// ---------------- KNN: K=16 MFMA tiles + BRANCHLESS packed-key top-3 ----------------
// Grid 1024 blocks x 512 thr. Block = 32 queries; wave w: query-tile w>>2, quarter w&3.
// Selection: key = (bits(max(d2,0)) & ~0xFF) | local_ordinal(8b). Positive f32 bit
// patterns order identically as float, so fmed3f/fminf do a branchless sorted insert
// with the index riding in the low mantissa bits (keys unique -> total order).
// Quantization err <= 2^-15 rel; absorbed by top-4 slack + exact f32 re-rank (as R4/R5).
#define LEXLT(dx, ix, dy, iy) ((dx) < (dy) || ((dx) == (dy) && (ix) < (iy)))
__global__ __launch_bounds__(512) void k_knn(const float* __restrict__ opts,
        const float* __restrict__ qpts, const _Float16* __restrict__ Atab,
        int* __restrict__ knn_idx, float* __restrict__ knn_w,
        const float* __restrict__ r1, const float* __restrict__ rb1,
        const float* __restrict__ gm, float* __restrict__ cb) {
    __shared__ float scr[256];
    __shared__ float md_s[8][16][4];
    __shared__ int   mi_s[8][16][4];
    int t = threadIdx.x;
    int blk = blockIdx.x;
    int b = blk >> 9;                   // 512 blocks per batch
    int q0b = (blk & 511) * 32;         // 32 queries per block
    // ---- CB rider: blocks 0..511 each compute one cb[o_global = blk] ----
    if (blk < 512) {
        int br = blk >> 8, o = blk & 255;
        if (t < 256) scr[t] = r1[(size_t)o * 707 + 451 + t] * gm[br * 256 + t];
        __syncthreads();
        if (t < 64) {
            float s = (scr[t] + scr[t + 64]) + (scr[t + 128] + scr[t + 192]);
            #pragma unroll
            for (int off = 32; off > 0; off >>= 1) s += __shfl_down(s, off);
            if (t == 0) cb[br * 256 + o] = rb1[o] + s;
        }
    }
    // ---- per-lane setup ----
    int w = t >> 6, l = t & 63;
    int g = l >> 4;                     // lane group (k-chunk / C-row group)
    int tw = w >> 2;                    // query tile within block (0/1)
    int qtr = w & 3;                    // point quarter
    int qcol = q0b + tw * 16 + (l & 15);
    const float* qb = qpts + (size_t)b * 3 * NQ;
    float qx = qb[qcol], qy = qb[NQ + qcol], qz = qb[2 * NQ + qcol];
    float q2 = __fadd_rn(__fadd_rn(__fmul_rn(qx, qx), __fmul_rn(qy, qy)), __fmul_rn(qz, qz));
    h4 bq;
    {
        _Float16 qh0 = (_Float16)qx, qh1 = (_Float16)qy, qh2 = (_Float16)qz;
        _Float16 ql0 = (_Float16)(qx - (float)qh0);
        _Float16 ql1 = (_Float16)(qy - (float)qh1);
        _Float16 ql2 = (_Float16)(qz - (float)qh2);
        _Float16 q2h = (_Float16)q2;
        _Float16 q2lo = (_Float16)(q2 - (float)q2h);
        _Float16 one = (_Float16)1.f, zero = (_Float16)0.f;
        if (g == 0)      { bq[0] = qh0; bq[1] = qh1; bq[2] = qh2; bq[3] = qh0; }
        else if (g == 1) { bq[0] = qh1; bq[1] = qh2; bq[2] = ql0; bq[3] = ql1; }
        else if (g == 2) { bq[0] = ql2; bq[1] = one; bq[2] = one; bq[3] = q2h; }
        else             { bq[0] = q2lo; bq[1] = zero; bq[2] = zero; bq[3] = zero; }
    }
    v4f zacc = (v4f){0.f, 0.f, 0.f, 0.f};
    // packed keys (sorted ascending s0<=s1<=s2); index rides in low 8 bits
    float s0k = 1e30f, s1k = 1e30f, s2k = 1e30f;
#define INS_PK(dv, lb) do {                                                    \
    _Pragma("unroll")                                                          \
    for (int r = 0; r < 4; r++) {                                              \
        float dc = fmaxf((dv)[r], 0.f);                                        \
        unsigned kb = (__float_as_uint(dc) & 0xFFFFFF00u) | (unsigned)((lb) + r); \
        float kf = __uint_as_float(kb);                                        \
        s2k = __builtin_amdgcn_fmed3f(s1k, s2k, kf);                           \
        s1k = __builtin_amdgcn_fmed3f(s0k, s1k, kf);                           \
        s0k = fminf(s0k, kf);                                                  \
    } } while (0)
    // ---- main loop: 64 tiles/quarter, 4-deep register prefetch (8 B/lane coalesced) ----
    const _Float16* ap = Atab + ((size_t)b * NPTS + qtr * 1024) * 16
                       + (size_t)(l & 15) * 16 + (size_t)g * 4;
    h4 a0 = *(const h4*)(ap + 0 * 256);
    h4 a1 = *(const h4*)(ap + 1 * 256);
    h4 a2 = *(const h4*)(ap + 2 * 256);
    h4 a3 = *(const h4*)(ap + 3 * 256);
    for (int tl = 0; tl < 64; tl += 4) {
        v4f dv0 = __builtin_amdgcn_mfma_f32_16x16x16f16(a0, bq, zacc, 0, 0, 0);
        v4f dv1 = __builtin_amdgcn_mfma_f32_16x16x16f16(a1, bq, zacc, 0, 0, 0);
        v4f dv2 = __builtin_amdgcn_mfma_f32_16x16x16f16(a2, bq, zacc, 0, 0, 0);
        v4f dv3 = __builtin_amdgcn_mfma_f32_16x16x16f16(a3, bq, zacc, 0, 0, 0);
        int n0 = tl + 4 < 64 ? tl + 4 : 63;
        int n1 = tl + 5 < 64 ? tl + 5 : 63;
        int n2 = tl + 6 < 64 ? tl + 6 : 63;
        int n3 = tl + 7 < 64 ? tl + 7 : 63;
        a0 = *(const h4*)(ap + (size_t)n0 * 256);
        a1 = *(const h4*)(ap + (size_t)n1 * 256);
        a2 = *(const h4*)(ap + (size_t)n2 * 256);
        a3 = *(const h4*)(ap + (size_t)n3 * 256);
        INS_PK(dv0, (tl + 0) * 4);
        INS_PK(dv1, (tl + 1) * 4);
        INS_PK(dv2, (tl + 2) * 4);
        INS_PK(dv3, (tl + 3) * 4);
    }
    // ---- unpack keys -> (quantized d, global idx) ----
    int nb0 = qtr * 1024 + g * 4;
    unsigned kb0 = __float_as_uint(s0k), kb1 = __float_as_uint(s1k), kb2 = __float_as_uint(s2k);
    int lo0 = kb0 & 0xFF, lo1 = kb1 & 0xFF, lo2 = kb2 & 0xFF;
    float d0 = __uint_as_float(kb0 & 0xFFFFFF00u);
    float d1 = __uint_as_float(kb1 & 0xFFFFFF00u);
    float d2v = __uint_as_float(kb2 & 0xFFFFFF00u);
    int i0 = nb0 + (lo0 >> 2) * 16 + (lo0 & 3);
    int i1 = nb0 + (lo1 >> 2) * 16 + (lo1 & 3);
    int i2 = nb0 + (lo2 >> 2) * 16 + (lo2 & 3);
    // ---- intra-wave merge (xor16 then xor32) into lex top-4; all lanes hold result ----
    float c0 = d0, c1 = d1, c2 = d2v, c3 = 1e30f;
    int   k0 = i0, k1 = i1, k2 = i2, k3 = 0x7fffffff;
#define INS4(dd, ii) do { float _d = (dd); int _i = (ii);                      \
    if (LEXLT(_d, _i, c3, k3)) {                                              \
        if (LEXLT(_d, _i, c2, k2)) { c3 = c2; k3 = k2;                        \
            if (LEXLT(_d, _i, c1, k1)) { c2 = c1; k2 = k1;                    \
                if (LEXLT(_d, _i, c0, k0)) { c1 = c0; k1 = k0; c0 = _d; k0 = _i; } \
                else { c1 = _d; k1 = _i; }                                    \
            } else { c2 = _d; k2 = _i; }                                      \
        } else { c3 = _d; k3 = _i; }                                          \
    } } while (0)
    {
        float e0 = __shfl_xor(d0, 16), e1 = __shfl_xor(d1, 16), e2 = __shfl_xor(d2v, 16);
        int   j0 = __shfl_xor(i0, 16), j1 = __shfl_xor(i1, 16), j2 = __shfl_xor(i2, 16);
        INS4(e0, j0); INS4(e1, j1); INS4(e2, j2);
    }
    {
        float e0 = __shfl_xor(c0, 32), e1 = __shfl_xor(c1, 32),
              e2 = __shfl_xor(c2, 32), e3 = __shfl_xor(c3, 32);
        int   j0 = __shfl_xor(k0, 32), j1 = __shfl_xor(k1, 32),
              j2 = __shfl_xor(k2, 32), j3 = __shfl_xor(k3, 32);
        INS4(e0, j0); INS4(e1, j1); INS4(e2, j2); INS4(e3, j3);
    }
    // ---- cross-wave 4-way merge via LDS (leader wave of each quarter-group) ----
    if (l < 16) {
        md_s[w][l][0] = c0; md_s[w][l][1] = c1; md_s[w][l][2] = c2; md_s[w][l][3] = c3;
        mi_s[w][l][0] = k0; mi_s[w][l][1] = k1; mi_s[w][l][2] = k2; mi_s[w][l][3] = k3;
    }
    __syncthreads();
    if ((w & 3) == 0) {
        int m16 = l & 15;
        #pragma unroll
        for (int pw = 1; pw < 4; pw++) {
            #pragma unroll
            for (int s = 0; s < 4; s++) {
                float dd = md_s[w + pw][m16][s];
                int ii = mi_s[w + pw][m16][s];
                INS4(dd, ii);
            }
        }
        // ---- exact re-rank of the 4 candidates (reference f32 formula, lex ties) ----
        const float* ob = opts + (size_t)b * 3 * NPTS;
        float t0 = 1e30f, t1 = 1e30f, t2 = 1e30f;
        int   u0 = 0x7fffffff, u1 = 0x7fffffff, u2 = 0x7fffffff;
#define INS3X(dd, ii) do { float _d = (dd); int _i = (ii);                     \
    if (LEXLT(_d, _i, t2, u2)) {                                              \
        if (LEXLT(_d, _i, t1, u1)) { t2 = t1; u2 = u1;                        \
            if (LEXLT(_d, _i, t0, u0)) { t1 = t0; u1 = u0; t0 = _d; u0 = _i; } \
            else { t1 = _d; u1 = _i; }                                        \
        } else { t2 = _d; u2 = _i; }                                          \
    } } while (0)
#define EXACTD(idx, dout) do { int _p = (idx);                                 \
    float px = ob[_p], py = ob[NPTS + _p], pz = ob[2 * NPTS + _p];             \
    float o2x = __fadd_rn(__fadd_rn(__fmul_rn(px, px), __fmul_rn(py, py)), __fmul_rn(pz, pz)); \
    float cr  = __fadd_rn(__fadd_rn(__fmul_rn(qx, px), __fmul_rn(qy, py)), __fmul_rn(qz, pz)); \
    dout = __fsub_rn(__fadd_rn(q2, o2x), __fmul_rn(2.f, cr)); } while (0)
        {
            float dx0, dx1, dx2, dx3;
            EXACTD(k0, dx0); EXACTD(k1, dx1); EXACTD(k2, dx2); EXACTD(k3, dx3);
            INS3X(dx0, k0); INS3X(dx1, k1); INS3X(dx2, k2); INS3X(dx3, k3);
        }
        if (l < 16) {
            int ids[3] = {u0, u1, u2};
            float rr[3];
            float s = 0.f;
            #pragma unroll
            for (int mm = 0; mm < 3; mm++) {
                int ii = ids[mm];
                float px = ob[ii], py = ob[NPTS + ii], pz = ob[2 * NPTS + ii];
                float dx = __fsub_rn(px, qx), dy = __fsub_rn(py, qy), dz = __fsub_rn(pz, qz);
                float dd = __fadd_rn(__fadd_rn(__fmul_rn(dx, dx), __fmul_rn(dy, dy)), __fmul_rn(dz, dz));
                float dist = sqrtf(dd);
                rr[mm] = 1.f / (__fadd_rn(dist, 1e-8f));
                s += rr[mm];
            }
            int basei = (b * NQ + qcol) * 3;
            #pragma unroll
            for (int mm = 0; mm < 3; mm++) {
                knn_idx[basei + mm] = ids[mm];
                knn_w[basei + mm]   = rr[mm] / s;
            }
        }
    }
}

// ---------------- k_tail: fused interp(r1-gather) + r2 + r3 + r4, 64 queries/block ----
__global__ __launch_bounds__(256) void k_tail(
        const float* __restrict__ qpts, const _Float16* __restrict__ G,
        const float* __restrict__ CB, const int* __restrict__ knn_idx,
        const float* __restrict__ knn_w, const float* __restrict__ r1,
        const _Float16* __restrict__ Rw2, const float* __restrict__ rb2,
        const _Float16* __restrict__ Rw3, const float* __restrict__ rb3,
        const float* __restrict__ r4, const float* __restrict__ rb4,
        float* __restrict__ out) {
    __shared__ __align__(16) unsigned char arena[48128];
    _Float16* sH1  = (_Float16*)arena;             // [64][264] = 33792 B
    _Float16* sBst = (_Float16*)(arena + 33792);   // r2 B-stage [128][56] = 14336 B
    _Float16* sH2  = (_Float16*)arena;             // [64][136] = 17408 (aliases sH1)
    _Float16* sH3  = (_Float16*)(arena + 17408);   // [64][72]  = 9216
    _Float16* sW3  = (_Float16*)(arena + 33792);   // r3 W-stage [64][56] = 7168
    __shared__ int   s_id[192];
    __shared__ float s_wt[192];
    __shared__ float s_qp[3][64];
    __shared__ float s_wq[3][256];
    __shared__ float s_cb[256];
    __shared__ float sw4[64];
    int t = threadIdx.x;
    int w = t >> 6, lane = t & 63;
    int m = lane & 15, quad = lane >> 4;
    int q0 = blockIdx.x * 64;
    int b = q0 >> 14;
    int qin = q0 & (NQ - 1);

    if (t < 192) {
        s_id[t] = knn_idx[q0 * 3 + t];
        s_wt[t] = knn_w[q0 * 3 + t];
        int d = t >> 6, j = t & 63;
        s_qp[d][j] = qpts[(size_t)b * 3 * NQ + d * NQ + qin + j];
    }
    s_wq[0][t] = r1[(size_t)t * 707 + 0];
    s_wq[1][t] = r1[(size_t)t * 707 + 1];
    s_wq[2][t] = r1[(size_t)t * 707 + 2];
    s_cb[t] = CB[b * 256 + t];
    if (t < 64) sw4[t] = r4[t];
    __syncthreads();

    // ---- interp: build h1 tile [64 q][256 ch] in LDS (same fmaf order as before) ----
    {
        int cg = (t & 31) * 8;
        int js = t >> 5;
        float wq0[8], wq1[8], wq2[8], cbv[8];
        #pragma unroll
        for (int u = 0; u < 8; u++) {
            wq0[u] = s_wq[0][cg + u];
            wq1[u] = s_wq[1][cg + u];
            wq2[u] = s_wq[2][cg + u];
            cbv[u] = s_cb[cg + u];
        }
        const _Float16* Gb = G + (size_t)b * NPTS * 256;
        #pragma unroll
        for (int jj = 0; jj < 8; jj++) {
            int j = js + jj * 8;
            int i0 = s_id[j * 3 + 0], i1 = s_id[j * 3 + 1], i2 = s_id[j * 3 + 2];
            float w0 = s_wt[j * 3 + 0], w1 = s_wt[j * 3 + 1], w2 = s_wt[j * 3 + 2];
            float qx = s_qp[0][j], qy = s_qp[1][j], qz = s_qp[2][j];
            h8 g0 = *(const h8*)&Gb[(size_t)i0 * 256 + cg];
            h8 g1 = *(const h8*)&Gb[(size_t)i1 * 256 + cg];
            h8 g2 = *(const h8*)&Gb[(size_t)i2 * 256 + cg];
            h8 hv;
            #pragma unroll
            for (int u = 0; u < 8; u++) {
                float acc = cbv[u];
                acc = fmaf(wq0[u], qx, acc);
                acc = fmaf(wq1[u], qy, acc);
                acc = fmaf(wq2[u], qz, acc);
                acc = fmaf(w0, (float)g0[u], acc);
                acc = fmaf(w1, (float)g1[u], acc);
                acc = fmaf(w2, (float)g2[u], acc);
                hv[u] = (_Float16)fmaxf(acc, 0.f);
            }
            *(h8*)&sH1[j * 264 + cg] = hv;
        }
    }

    // ---- r2: h2(64q x 128ch) = relu(Rw2 @ h1); A-frags straight from sH1 ----
    float h2v[4][2][4];
    {
        v4f acc[4][2];
        #pragma unroll
        for (int i = 0; i < 4; i++)
            #pragma unroll
            for (int j = 0; j < 2; j++)
                acc[i][j] = (v4f){0.f, 0.f, 0.f, 0.f};
        for (int kc = 0; kc < 256; kc += 32) {
            __syncthreads();   // first: sH1 writes; later: sBst reuse
            #pragma unroll
            for (int i = 0; i < 2; i++) {
                int e = t + i * 256;
                int r = e >> 2, p = e & 3;
                *(float4*)&sBst[r * 56 + p * 8] =
                    *(const float4*)&Rw2[(size_t)r * 256 + kc + p * 8];
            }
            __syncthreads();
            h8 af[4], bf[2];
            #pragma unroll
            for (int mt = 0; mt < 4; mt++)
                af[mt] = *(const h8*)&sH1[(mt * 16 + m) * 264 + kc + quad * 8];
            #pragma unroll
            for (int nt = 0; nt < 2; nt++)
                bf[nt] = *(const h8*)&sBst[(w * 32 + nt * 16 + m) * 56 + quad * 8];
            #pragma unroll
            for (int mt = 0; mt < 4; mt++)
                #pragma unroll
                for (int nt = 0; nt < 2; nt++)
                    acc[mt][nt] = __builtin_amdgcn_mfma_f32_16x16x32_f16(
                            af[mt], bf[nt], acc[mt][nt], 0, 0, 0);
        }
        #pragma unroll
        for (int nt = 0; nt < 2; nt++) {
            int ch = w * 32 + nt * 16 + m;
            float bb2 = rb2[ch];
            #pragma unroll
            for (int mt = 0; mt < 4; mt++)
                #pragma unroll
                for (int r = 0; r < 4; r++)
                    h2v[mt][nt][r] = fmaxf(acc[mt][nt][r] + bb2, 0.f);
        }
    }
    __syncthreads();   // all sH1 reads done -> safe to overwrite with sH2
    {
        #pragma unroll
        for (int nt = 0; nt < 2; nt++) {
            int ch = w * 32 + nt * 16 + m;
            #pragma unroll
            for (int mt = 0; mt < 4; mt++)
                #pragma unroll
                for (int r = 0; r < 4; r++) {
                    int ql = mt * 16 + quad * 4 + r;
                    sH2[ql * 136 + ch] = (_Float16)h2v[mt][nt][r];
                }
        }
    }

    // ---- r3: h3(64q x 64ch) = relu(Rw3 @ h2) ----
    float h3v[4][4];
    {
        v4f acc[4];
        #pragma unroll
        for (int i = 0; i < 4; i++) acc[i] = (v4f){0.f, 0.f, 0.f, 0.f};
        for (int kc = 0; kc < 128; kc += 32) {
            __syncthreads();   // first: sH2 writes; later: sW3 reuse
            if (t < 256) {     // 64 rows x 4 segs = 256; 1 per thread
                int r = t >> 2, p = t & 3;
                *(float4*)&sW3[r * 56 + p * 8] =
                    *(const float4*)&Rw3[(size_t)r * 128 + kc + p * 8];
            }
            __syncthreads();
            h8 af[4], bf;
            #pragma unroll
            for (int mt = 0; mt < 4; mt++)
                af[mt] = *(const h8*)&sH2[(mt * 16 + m) * 136 + kc + quad * 8];
            bf = *(const h8*)&sW3[(w * 16 + m) * 56 + quad * 8];
            #pragma unroll
            for (int mt = 0; mt < 4; mt++)
                acc[mt] = __builtin_amdgcn_mfma_f32_16x16x32_f16(
                        af[mt], bf, acc[mt], 0, 0, 0);
        }
        int ch = w * 16 + m;
        float bb3 = rb3[ch];
        #pragma unroll
        for (int mt = 0; mt < 4; mt++)
            #pragma unroll
            for (int r = 0; r < 4; r++)
                h3v[mt][r] = fmaxf(acc[mt][r] + bb3, 0.f);
    }
    __syncthreads();
    {
        int ch = w * 16 + m;
        #pragma unroll
        for (int mt = 0; mt < 4; mt++)
            #pragma unroll
            for (int r = 0; r < 4; r++) {
                int ql = mt * 16 + quad * 4 + r;
                sH3[ch * 72 + ql] = (_Float16)h3v[mt][r];
            }
    }
    __syncthreads();

    // ---- r4: out = r4 . h3 + rb4 ----
    if (t < 64) {
        float acc = rb4[0];
        #pragma unroll 16
        for (int c = 0; c < 64; c++)
            acc = fmaf((float)sH3[c * 72 + t], sw4[c], acc);
        out[q0 + t] = acc;
    }
}

extern "C" void kernel_launch(void* const* d_in, const int* in_sizes, int n_in,
                              void* d_out, int out_size, void* d_ws, size_t ws_size,
                              hipStream_t stream) {
    const float* opts = (const float*)d_in[0];
    const float* qpts = (const float*)d_in[1];
    const float* w1  = (const float*)d_in[2];
    const float* b1  = (const float*)d_in[3];
    const float* w2  = (const float*)d_in[4];
    const float* b2  = (const float*)d_in[5];
    const float* w3  = (const float*)d_in[6];
    const float* b3  = (const float*)d_in[7];
    const float* r1  = (const float*)d_in[8];
    const float* rb1 = (const float*)d_in[9];
    const float* r2  = (const float*)d_in[10];
    const float* rb2 = (const float*)d_in[11];
    const float* r3  = (const float*)d_in[12];
    const float* rb3 = (const float*)d_in[13];
    const float* r4  = (const float*)d_in[14];
    const float* rb4 = (const float*)d_in[15];
    float* out = (float*)d_out;

    unsigned char* p = (unsigned char*)d_ws;
    float* GM = (float*)p;          p += (size_t)NB * 256 * 4;
    float* CB = (float*)p;          p += (size_t)NB * 256 * 4;
    int*   IDX = (int*)p;           p += (size_t)NB * NQ * 3 * 4;
    float* WT = (float*)p;          p += (size_t)NB * NQ * 3 * 4;
    _Float16* Rw1 = (_Float16*)p;   p += (size_t)256 * FCATC * 2;
    _Float16* Rw2 = (_Float16*)p;   p += (size_t)128 * 256 * 2;
    _Float16* Rw3 = (_Float16*)p;   p += (size_t)64 * 128 * 2;
    _Float16* Ew2 = (_Float16*)p;   p += (size_t)128 * 64 * 2;
    _Float16* Ew3 = (_Float16*)p;   p += (size_t)256 * 128 * 2;
    _Float16* Atab = (_Float16*)p;  p += (size_t)NB * NPTS * 16 * 2;
    _Float16* G = (_Float16*)p;     p += (size_t)NB * NPTS * 256 * 2;

    k_pre<<<801, 256, 0, stream>>>(r1, r2, r3, w2, w3, opts,
                                   Rw1, Rw2, Rw3, Ew2, Ew3, Atab, GM);
    // fe also produces G (old k_gemm folded in); Fcat never touches global
    k_fe<<<NB * NPTS / 128, 256, 0, stream>>>(opts, w1, b1, Ew2, b2, Ew3, b3,
                                              Rw1, G, (unsigned*)GM);
    // K=16 MFMA knn, branchless packed-key selection; 1024 blocks x 512 thr
    k_knn<<<1024, 512, 0, stream>>>(opts, qpts, Atab, IDX, WT, r1, rb1, GM, CB);
    k_tail<<<QTOT / 64, 256, 0, stream>>>(qpts, G, CB, IDX, WT, r1,
                                          Rw2, rb2, Rw3, rb3, r4, rb4, out);
}

// Round 7
// 160.656 us; speedup vs baseline: 1.2874x; 1.0294x over previous
//
#include <hip/hip_runtime.h>
#include <math.h>

#define NB 2
#define NPTS 4096
#define NQ 16384
#define QTOT (NB * NQ)   // 32768 queries, batch folded into row index
#define FCATC 448        // 64+128+256 concatenated feature channels per point

typedef _Float16 h8 __attribute__((ext_vector_type(8)));
typedef _Float16 h4 __attribute__((ext_vector_type(4)));
typedef float v4f __attribute__((ext_vector_type(4)));

// ---------------- k_pre: weight casts + GM zero + knn A-table build (K=16) ----------------
__global__ __launch_bounds__(256) void k_pre(
        const float* __restrict__ r1, const float* __restrict__ r2,
        const float* __restrict__ r3, const float* __restrict__ w2,
        const float* __restrict__ w3, const float* __restrict__ opts,
        _Float16* __restrict__ Rw1, _Float16* __restrict__ Rw2,
        _Float16* __restrict__ Rw3, _Float16* __restrict__ Ew2,
        _Float16* __restrict__ Ew3, _Float16* __restrict__ Atab,
        float* __restrict__ GM) {
    int blk = blockIdx.x;
    int t = threadIdx.x;
    if (blk < 768) {
        int g = blk * 256 + t;
        if (g < 114688) {                       // Rw1 = r1[:,3:451] (256 x 448)
            int o = g / FCATC, k = g - o * FCATC;
            Rw1[g] = (_Float16)r1[(size_t)o * 707 + 3 + k];
        } else if (g < 147456) {                // Rw2 = r2 (128x256)
            int i = g - 114688;
            Rw2[i] = (_Float16)r2[i];
        } else if (g < 155648) {                // Rw3 = r3 (64x128)
            int i = g - 147456;
            Rw3[i] = (_Float16)r3[i];
        } else if (g < 163840) {                // Ew2 = w2 (128x64)
            int i = g - 155648;
            Ew2[i] = (_Float16)w2[i];
        } else {                                // Ew3 = w3 (256x128)
            int i = g - 163840;
            Ew3[i] = (_Float16)w3[i];
        }
    } else if (blk == 768) {
        GM[t] = 0.f;
        GM[256 + t] = 0.f;
    } else {                                    // blocks 769..800: Atab (8192 points)
        int gi = (blk - 769) * 256 + t;
        int bb = gi >> 12, pp = gi & (NPTS - 1);
        const float* ob = opts + (size_t)bb * 3 * NPTS;
        float x = ob[pp], y = ob[NPTS + pp], z = ob[2 * NPTS + pp];
        float o2 = __fadd_rn(__fadd_rn(__fmul_rn(x, x), __fmul_rn(y, y)), __fmul_rn(z, z));
        _Float16 xh = (_Float16)x, yh = (_Float16)y, zh = (_Float16)z;
        _Float16 xl = (_Float16)(x - (float)xh);
        _Float16 yl = (_Float16)(y - (float)yh);
        _Float16 zl = (_Float16)(z - (float)zh);
        _Float16 o2h = (_Float16)o2;
        _Float16 o2l = (_Float16)(o2 - (float)o2h);
        _Float16 nxh = (_Float16)(-2.f * (float)xh);   // exact pow2 scale
        _Float16 nyh = (_Float16)(-2.f * (float)yh);
        _Float16 nzh = (_Float16)(-2.f * (float)zh);
        _Float16 nxl = (_Float16)(-2.f * (float)xl);
        _Float16 nyl = (_Float16)(-2.f * (float)yl);
        _Float16 nzl = (_Float16)(-2.f * (float)zl);
        _Float16 one = (_Float16)1.f, zero = (_Float16)0.f;
        h8 v0, v1;
        v0[0] = nxh; v0[1] = nyh; v0[2] = nzh; v0[3] = nxl;
        v0[4] = nyl; v0[5] = nzl; v0[6] = nxh; v0[7] = nyh;
        v1[0] = nzh; v1[1] = o2h; v1[2] = o2l; v1[3] = one;
        v1[4] = one; v1[5] = zero; v1[6] = zero; v1[7] = zero;
        _Float16* dst = Atab + (size_t)gi * 16;
        *(h8*)dst = v0;
        *(h8*)(dst + 8) = v1;
    }
}

// ---------------- k_fe: fused l1+l2+l3+max+G-GEMM, 32 points/block x 256 blocks ----------
// Chip-filling remap of the 128-pt version (64 blocks -> 256). Per-point MFMA chains keep
// identical A-row data, B operands and kc order -> bit-identical f2/f3/G outputs.
__global__ __launch_bounds__(256) void k_fe(const float* __restrict__ pts,
        const float* __restrict__ w1, const float* __restrict__ b1,
        const _Float16* __restrict__ Ew2, const float* __restrict__ b2,
        const _Float16* __restrict__ Ew3, const float* __restrict__ b3,
        const _Float16* __restrict__ Rw1, _Float16* __restrict__ G,
        unsigned* __restrict__ GM) {
    __shared__ __align__(16) unsigned char arena[58880];
    _Float16* sF1  = (_Float16*)arena;             // [32][72]  = 4608 B
    _Float16* sF2  = (_Float16*)(arena + 4608);    // [32][136] = 8704 B
    _Float16* sF3  = (_Float16*)(arena + 13312);   // [32][264] = 16896 B
    _Float16* sBst = (_Float16*)(arena + 30208);   // [256][56] = 28672 B
    __shared__ float sW1[192];
    __shared__ float sB1[64];
    __shared__ unsigned smax[256];
    int t = threadIdx.x;
    int w = t >> 6, lane = t & 63;
    int m = lane & 15, quad = lane >> 4;
    int wq = w & 1, wn = w >> 1;   // wq: 16-row M half; wn: N half
    int P0 = blockIdx.x * 32;
    int bb = P0 >> 12;
    int p0in = P0 & (NPTS - 1);

    if (t < 192) sW1[t] = w1[t];
    if (t < 64)  sB1[t] = b1[t];
    smax[t] = 0u;
    __syncthreads();

    // ---- l1: f1 = relu(W1 @ pts + b1) -> sF1 (32 pts, 8 ch/thread) ----
    {
        int pt = t >> 3;
        int cs = (t & 7) * 8;
        const float* pb = pts + (size_t)bb * 3 * NPTS + p0in;
        float px = pb[pt], py = pb[NPTS + pt], pz = pb[2 * NPTS + pt];
        #pragma unroll 8
        for (int c = cs; c < cs + 8; c++) {
            float v = fmaf(sW1[c*3+0], px,
                      fmaf(sW1[c*3+1], py,
                      fmaf(sW1[c*3+2], pz, sB1[c])));
            sF1[pt * 72 + c] = (_Float16)fmaxf(v, 0.f);
        }
    }

    // ---- l2: f2(32pt x 128ch) = relu(Ew2 @ f1 + b2) -> sF2 ----
    {
        v4f acc[4];
        #pragma unroll
        for (int j = 0; j < 4; j++) acc[j] = (v4f){0.f, 0.f, 0.f, 0.f};
        for (int kc = 0; kc < 64; kc += 32) {
            __syncthreads();    // first iter: covers sF1 writes; later: sBst reuse
            #pragma unroll
            for (int i = 0; i < 2; i++) {       // 128 rows x 4 segs = 512; 2/thread
                int e = t + i * 256;
                int r = e >> 2, p = e & 3;
                *(float4*)&sBst[r * 56 + p * 8] =
                    *(const float4*)&Ew2[(size_t)r * 64 + kc + p * 8];
            }
            __syncthreads();
            h8 af = *(const h8*)&sF1[(wq * 16 + m) * 72 + kc + quad * 8];
            h8 bf[4];
            #pragma unroll
            for (int nt = 0; nt < 4; nt++)
                bf[nt] = *(const h8*)&sBst[(wn * 64 + nt * 16 + m) * 56 + quad * 8];
            #pragma unroll
            for (int nt = 0; nt < 4; nt++)
                acc[nt] = __builtin_amdgcn_mfma_f32_16x16x32_f16(
                        af, bf[nt], acc[nt], 0, 0, 0);
        }
        #pragma unroll
        for (int nt = 0; nt < 4; nt++) {
            int ch = wn * 64 + nt * 16 + m;
            float bb2 = b2[ch];
            #pragma unroll
            for (int r = 0; r < 4; r++) {
                int ptl = wq * 16 + quad * 4 + r;
                sF2[ptl * 136 + ch] = (_Float16)fmaxf(acc[nt][r] + bb2, 0.f);
            }
        }
    }

    // ---- l3: f3(32pt x 256ch) = relu(Ew3 @ f2 + b3) -> sF3 + max ----
    {
        v4f acc[8];
        #pragma unroll
        for (int j = 0; j < 8; j++) acc[j] = (v4f){0.f, 0.f, 0.f, 0.f};
        for (int kc = 0; kc < 128; kc += 32) {
            __syncthreads();    // first iter: covers sF2 writes; later: sBst reuse
            #pragma unroll
            for (int i = 0; i < 4; i++) {       // 256 rows x 4 segs = 1024; 4/thread
                int e = t + i * 256;
                int r = e >> 2, p = e & 3;
                *(float4*)&sBst[r * 56 + p * 8] =
                    *(const float4*)&Ew3[(size_t)r * 128 + kc + p * 8];
            }
            __syncthreads();
            h8 af = *(const h8*)&sF2[(wq * 16 + m) * 136 + kc + quad * 8];
            h8 bf[8];
            #pragma unroll
            for (int nt = 0; nt < 8; nt++)
                bf[nt] = *(const h8*)&sBst[(wn * 128 + nt * 16 + m) * 56 + quad * 8];
            #pragma unroll
            for (int nt = 0; nt < 8; nt++)
                acc[nt] = __builtin_amdgcn_mfma_f32_16x16x32_f16(
                        af, bf[nt], acc[nt], 0, 0, 0);
        }
        #pragma unroll
        for (int nt = 0; nt < 8; nt++) {
            int ch = wn * 128 + nt * 16 + m;
            float bb3 = b3[ch];
            float vmax = 0.f;
            #pragma unroll
            for (int r = 0; r < 4; r++) {
                int ptl = wq * 16 + quad * 4 + r;
                float v = fmaxf(acc[nt][r] + bb3, 0.f);
                vmax = fmaxf(vmax, v);
                sF3[ptl * 264 + ch] = (_Float16)v;
            }
            atomicMax(&smax[ch], __float_as_uint(vmax));
        }
        __syncthreads();
        atomicMax(GM + bb * 256 + t, smax[t]);
    }

    // ---- G-GEMM: G[32pt][256] = Rw1[256x448] @ [sF1|sF2|sF3], kc chunks of 32 ----
    {
        v4f acc[8];
        #pragma unroll
        for (int j = 0; j < 8; j++) acc[j] = (v4f){0.f, 0.f, 0.f, 0.f};
        #pragma unroll
        for (int kc = 0; kc < FCATC; kc += 32) {
            __syncthreads();    // sBst reuse
            #pragma unroll
            for (int i = 0; i < 4; i++) {       // 256 rows x 4 segs = 1024; 4/thread
                int e = t + i * 256;
                int r = e >> 2, p = e & 3;
                *(float4*)&sBst[r * 56 + p * 8] =
                    *(const float4*)&Rw1[(size_t)r * FCATC + kc + p * 8];
            }
            __syncthreads();
            int row = wq * 16 + m;
            h8 af;
            if (kc < 64)
                af = *(const h8*)&sF1[row * 72 + kc + quad * 8];
            else if (kc < 192)
                af = *(const h8*)&sF2[row * 136 + (kc - 64) + quad * 8];
            else
                af = *(const h8*)&sF3[row * 264 + (kc - 192) + quad * 8];
            h8 bf[8];
            #pragma unroll
            for (int nt = 0; nt < 8; nt++)
                bf[nt] = *(const h8*)&sBst[(wn * 128 + nt * 16 + m) * 56 + quad * 8];
            #pragma unroll
            for (int nt = 0; nt < 8; nt++)
                acc[nt] = __builtin_amdgcn_mfma_f32_16x16x32_f16(
                        af, bf[nt], acc[nt], 0, 0, 0);
        }
        #pragma unroll
        for (int nt = 0; nt < 8; nt++) {
            int ch = wn * 128 + nt * 16 + m;
            #pragma unroll
            for (int r = 0; r < 4; r++) {
                int ptl = wq * 16 + quad * 4 + r;
                G[(size_t)(P0 + ptl) * 256 + ch] = (_Float16)acc[nt][r];
            }
        }
    }
}

// ---------------- KNN: K=16 MFMA tiles + branchless packed-key top-3 (R6, unchanged) ----
#define LEXLT(dx, ix, dy, iy) ((dx) < (dy) || ((dx) == (dy) && (ix) < (iy)))
__global__ __launch_bounds__(512) void k_knn(const float* __restrict__ opts,
        const float* __restrict__ qpts, const _Float16* __restrict__ Atab,
        int* __restrict__ knn_idx, float* __restrict__ knn_w,
        const float* __restrict__ r1, const float* __restrict__ rb1,
        const float* __restrict__ gm, float* __restrict__ cb) {
    __shared__ float scr[256];
    __shared__ float md_s[8][16][4];
    __shared__ int   mi_s[8][16][4];
    int t = threadIdx.x;
    int blk = blockIdx.x;
    int b = blk >> 9;                   // 512 blocks per batch
    int q0b = (blk & 511) * 32;         // 32 queries per block
    // ---- CB rider: blocks 0..511 each compute one cb[o_global = blk] ----
    if (blk < 512) {
        int br = blk >> 8, o = blk & 255;
        if (t < 256) scr[t] = r1[(size_t)o * 707 + 451 + t] * gm[br * 256 + t];
        __syncthreads();
        if (t < 64) {
            float s = (scr[t] + scr[t + 64]) + (scr[t + 128] + scr[t + 192]);
            #pragma unroll
            for (int off = 32; off > 0; off >>= 1) s += __shfl_down(s, off);
            if (t == 0) cb[br * 256 + o] = rb1[o] + s;
        }
    }
    // ---- per-lane setup ----
    int w = t >> 6, l = t & 63;
    int g = l >> 4;                     // lane group (k-chunk / C-row group)
    int tw = w >> 2;                    // query tile within block (0/1)
    int qtr = w & 3;                    // point quarter
    int qcol = q0b + tw * 16 + (l & 15);
    const float* qb = qpts + (size_t)b * 3 * NQ;
    float qx = qb[qcol], qy = qb[NQ + qcol], qz = qb[2 * NQ + qcol];
    float q2 = __fadd_rn(__fadd_rn(__fmul_rn(qx, qx), __fmul_rn(qy, qy)), __fmul_rn(qz, qz));
    h4 bq;
    {
        _Float16 qh0 = (_Float16)qx, qh1 = (_Float16)qy, qh2 = (_Float16)qz;
        _Float16 ql0 = (_Float16)(qx - (float)qh0);
        _Float16 ql1 = (_Float16)(qy - (float)qh1);
        _Float16 ql2 = (_Float16)(qz - (float)qh2);
        _Float16 q2h = (_Float16)q2;
        _Float16 q2lo = (_Float16)(q2 - (float)q2h);
        _Float16 one = (_Float16)1.f, zero = (_Float16)0.f;
        if (g == 0)      { bq[0] = qh0; bq[1] = qh1; bq[2] = qh2; bq[3] = qh0; }
        else if (g == 1) { bq[0] = qh1; bq[1] = qh2; bq[2] = ql0; bq[3] = ql1; }
        else if (g == 2) { bq[0] = ql2; bq[1] = one; bq[2] = one; bq[3] = q2h; }
        else             { bq[0] = q2lo; bq[1] = zero; bq[2] = zero; bq[3] = zero; }
    }
    v4f zacc = (v4f){0.f, 0.f, 0.f, 0.f};
    float s0k = 1e30f, s1k = 1e30f, s2k = 1e30f;
#define INS_PK(dv, lb) do {                                                    \
    _Pragma("unroll")                                                          \
    for (int r = 0; r < 4; r++) {                                              \
        float dc = fmaxf((dv)[r], 0.f);                                        \
        unsigned kb = (__float_as_uint(dc) & 0xFFFFFF00u) | (unsigned)((lb) + r); \
        float kf = __uint_as_float(kb);                                        \
        s2k = __builtin_amdgcn_fmed3f(s1k, s2k, kf);                           \
        s1k = __builtin_amdgcn_fmed3f(s0k, s1k, kf);                           \
        s0k = fminf(s0k, kf);                                                  \
    } } while (0)
    const _Float16* ap = Atab + ((size_t)b * NPTS + qtr * 1024) * 16
                       + (size_t)(l & 15) * 16 + (size_t)g * 4;
    h4 a0 = *(const h4*)(ap + 0 * 256);
    h4 a1 = *(const h4*)(ap + 1 * 256);
    h4 a2 = *(const h4*)(ap + 2 * 256);
    h4 a3 = *(const h4*)(ap + 3 * 256);
    for (int tl = 0; tl < 64; tl += 4) {
        v4f dv0 = __builtin_amdgcn_mfma_f32_16x16x16f16(a0, bq, zacc, 0, 0, 0);
        v4f dv1 = __builtin_amdgcn_mfma_f32_16x16x16f16(a1, bq, zacc, 0, 0, 0);
        v4f dv2 = __builtin_amdgcn_mfma_f32_16x16x16f16(a2, bq, zacc, 0, 0, 0);
        v4f dv3 = __builtin_amdgcn_mfma_f32_16x16x16f16(a3, bq, zacc, 0, 0, 0);
        int n0 = tl + 4 < 64 ? tl + 4 : 63;
        int n1 = tl + 5 < 64 ? tl + 5 : 63;
        int n2 = tl + 6 < 64 ? tl + 6 : 63;
        int n3 = tl + 7 < 64 ? tl + 7 : 63;
        a0 = *(const h4*)(ap + (size_t)n0 * 256);
        a1 = *(const h4*)(ap + (size_t)n1 * 256);
        a2 = *(const h4*)(ap + (size_t)n2 * 256);
        a3 = *(const h4*)(ap + (size_t)n3 * 256);
        INS_PK(dv0, (tl + 0) * 4);
        INS_PK(dv1, (tl + 1) * 4);
        INS_PK(dv2, (tl + 2) * 4);
        INS_PK(dv3, (tl + 3) * 4);
    }
    int nb0 = qtr * 1024 + g * 4;
    unsigned kb0 = __float_as_uint(s0k), kb1 = __float_as_uint(s1k), kb2 = __float_as_uint(s2k);
    int lo0 = kb0 & 0xFF, lo1 = kb1 & 0xFF, lo2 = kb2 & 0xFF;
    float d0 = __uint_as_float(kb0 & 0xFFFFFF00u);
    float d1 = __uint_as_float(kb1 & 0xFFFFFF00u);
    float d2v = __uint_as_float(kb2 & 0xFFFFFF00u);
    int i0 = nb0 + (lo0 >> 2) * 16 + (lo0 & 3);
    int i1 = nb0 + (lo1 >> 2) * 16 + (lo1 & 3);
    int i2 = nb0 + (lo2 >> 2) * 16 + (lo2 & 3);
    float c0 = d0, c1 = d1, c2 = d2v, c3 = 1e30f;
    int   k0 = i0, k1 = i1, k2 = i2, k3 = 0x7fffffff;
#define INS4(dd, ii) do { float _d = (dd); int _i = (ii);                      \
    if (LEXLT(_d, _i, c3, k3)) {                                              \
        if (LEXLT(_d, _i, c2, k2)) { c3 = c2; k3 = k2;                        \
            if (LEXLT(_d, _i, c1, k1)) { c2 = c1; k2 = k1;                    \
                if (LEXLT(_d, _i, c0, k0)) { c1 = c0; k1 = k0; c0 = _d; k0 = _i; } \
                else { c1 = _d; k1 = _i; }                                    \
            } else { c2 = _d; k2 = _i; }                                      \
        } else { c3 = _d; k3 = _i; }                                          \
    } } while (0)
    {
        float e0 = __shfl_xor(d0, 16), e1 = __shfl_xor(d1, 16), e2 = __shfl_xor(d2v, 16);
        int   j0 = __shfl_xor(i0, 16), j1 = __shfl_xor(i1, 16), j2 = __shfl_xor(i2, 16);
        INS4(e0, j0); INS4(e1, j1); INS4(e2, j2);
    }
    {
        float e0 = __shfl_xor(c0, 32), e1 = __shfl_xor(c1, 32),
              e2 = __shfl_xor(c2, 32), e3 = __shfl_xor(c3, 32);
        int   j0 = __shfl_xor(k0, 32), j1 = __shfl_xor(k1, 32),
              j2 = __shfl_xor(k2, 32), j3 = __shfl_xor(k3, 32);
        INS4(e0, j0); INS4(e1, j1); INS4(e2, j2); INS4(e3, j3);
    }
    if (l < 16) {
        md_s[w][l][0] = c0; md_s[w][l][1] = c1; md_s[w][l][2] = c2; md_s[w][l][3] = c3;
        mi_s[w][l][0] = k0; mi_s[w][l][1] = k1; mi_s[w][l][2] = k2; mi_s[w][l][3] = k3;
    }
    __syncthreads();
    if ((w & 3) == 0) {
        int m16 = l & 15;
        #pragma unroll
        for (int pw = 1; pw < 4; pw++) {
            #pragma unroll
            for (int s = 0; s < 4; s++) {
                float dd = md_s[w + pw][m16][s];
                int ii = mi_s[w + pw][m16][s];
                INS4(dd, ii);
            }
        }
        const float* ob = opts + (size_t)b * 3 * NPTS;
        float t0 = 1e30f, t1 = 1e30f, t2 = 1e30f;
        int   u0 = 0x7fffffff, u1 = 0x7fffffff, u2 = 0x7fffffff;
#define INS3X(dd, ii) do { float _d = (dd); int _i = (ii);                     \
    if (LEXLT(_d, _i, t2, u2)) {                                              \
        if (LEXLT(_d, _i, t1, u1)) { t2 = t1; u2 = u1;                        \
            if (LEXLT(_d, _i, t0, u0)) { t1 = t0; u1 = u0; t0 = _d; u0 = _i; } \
            else { t1 = _d; u1 = _i; }                                        \
        } else { t2 = _d; u2 = _i; }                                          \
    } } while (0)
#define EXACTD(idx, dout) do { int _p = (idx);                                 \
    float px = ob[_p], py = ob[NPTS + _p], pz = ob[2 * NPTS + _p];             \
    float o2x = __fadd_rn(__fadd_rn(__fmul_rn(px, px), __fmul_rn(py, py)), __fmul_rn(pz, pz)); \
    float cr  = __fadd_rn(__fadd_rn(__fmul_rn(qx, px), __fmul_rn(qy, py)), __fmul_rn(qz, pz)); \
    dout = __fsub_rn(__fadd_rn(q2, o2x), __fmul_rn(2.f, cr)); } while (0)
        {
            float dx0, dx1, dx2, dx3;
            EXACTD(k0, dx0); EXACTD(k1, dx1); EXACTD(k2, dx2); EXACTD(k3, dx3);
            INS3X(dx0, k0); INS3X(dx1, k1); INS3X(dx2, k2); INS3X(dx3, k3);
        }
        if (l < 16) {
            int ids[3] = {u0, u1, u2};
            float rr[3];
            float s = 0.f;
            #pragma unroll
            for (int mm = 0; mm < 3; mm++) {
                int ii = ids[mm];
                float px = ob[ii], py = ob[NPTS + ii], pz = ob[2 * NPTS + ii];
                float dx = __fsub_rn(px, qx), dy = __fsub_rn(py, qy), dz = __fsub_rn(pz, qz);
                float dd = __fadd_rn(__fadd_rn(__fmul_rn(dx, dx), __fmul_rn(dy, dy)), __fmul_rn(dz, dz));
                float dist = sqrtf(dd);
                rr[mm] = 1.f / (__fadd_rn(dist, 1e-8f));
                s += rr[mm];
            }
            int basei = (b * NQ + qcol) * 3;
            #pragma unroll
            for (int mm = 0; mm < 3; mm++) {
                knn_idx[basei + mm] = ids[mm];
                knn_w[basei + mm]   = rr[mm] / s;
            }
        }
    }
}

// ---------------- k_tail: fused interp + r2 + r3 + r4, 32 queries/block x 1024 blocks ----
// Machine-filling remap of the 64-q version (LDS 48K->31K, 2->4 blocks/CU). Per-query
// MFMA chains keep identical operands and kc order -> bit-identical outputs.
__global__ __launch_bounds__(256) void k_tail(
        const float* __restrict__ qpts, const _Float16* __restrict__ G,
        const float* __restrict__ CB, const int* __restrict__ knn_idx,
        const float* __restrict__ knn_w, const float* __restrict__ r1,
        const _Float16* __restrict__ Rw2, const float* __restrict__ rb2,
        const _Float16* __restrict__ Rw3, const float* __restrict__ rb3,
        const float* __restrict__ r4, const float* __restrict__ rb4,
        float* __restrict__ out) {
    __shared__ __align__(16) unsigned char arena[31232];
    _Float16* sH1  = (_Float16*)arena;             // [32][264] = 16896 B
    _Float16* sBst = (_Float16*)(arena + 16896);   // r2 B-stage [128][56] = 14336 B
    _Float16* sH2  = (_Float16*)arena;             // [32][136] = 8704 (aliases sH1)
    _Float16* sH3  = (_Float16*)(arena + 8704);    // [64ch][72] = 9216 (32 cols used)
    _Float16* sW3  = (_Float16*)(arena + 17920);   // r3 W-stage [64][56] = 7168
    __shared__ int   s_id[96];
    __shared__ float s_wt[96];
    __shared__ float s_qp[3][32];
    __shared__ float s_wq[3][256];
    __shared__ float s_cb[256];
    __shared__ float sw4[64];
    int t = threadIdx.x;
    int w = t >> 6, lane = t & 63;
    int m = lane & 15, quad = lane >> 4;
    int q0 = blockIdx.x * 32;
    int b = q0 >> 14;
    int qin = q0 & (NQ - 1);

    if (t < 96) {
        s_id[t] = knn_idx[q0 * 3 + t];
        s_wt[t] = knn_w[q0 * 3 + t];
        int d = t >> 5, j = t & 31;
        s_qp[d][j] = qpts[(size_t)b * 3 * NQ + d * NQ + qin + j];
    }
    s_wq[0][t] = r1[(size_t)t * 707 + 0];
    s_wq[1][t] = r1[(size_t)t * 707 + 1];
    s_wq[2][t] = r1[(size_t)t * 707 + 2];
    s_cb[t] = CB[b * 256 + t];
    if (t < 64) sw4[t] = r4[t];
    __syncthreads();

    // ---- interp: build h1 tile [32 q][256 ch] in LDS (same fmaf order as before) ----
    {
        int cg = (t & 31) * 8;
        int js = t >> 5;
        float wq0[8], wq1[8], wq2[8], cbv[8];
        #pragma unroll
        for (int u = 0; u < 8; u++) {
            wq0[u] = s_wq[0][cg + u];
            wq1[u] = s_wq[1][cg + u];
            wq2[u] = s_wq[2][cg + u];
            cbv[u] = s_cb[cg + u];
        }
        const _Float16* Gb = G + (size_t)b * NPTS * 256;
        #pragma unroll
        for (int jj = 0; jj < 4; jj++) {
            int j = js + jj * 8;
            int i0 = s_id[j * 3 + 0], i1 = s_id[j * 3 + 1], i2 = s_id[j * 3 + 2];
            float w0 = s_wt[j * 3 + 0], w1 = s_wt[j * 3 + 1], w2 = s_wt[j * 3 + 2];
            float qx = s_qp[0][j], qy = s_qp[1][j], qz = s_qp[2][j];
            h8 g0 = *(const h8*)&Gb[(size_t)i0 * 256 + cg];
            h8 g1 = *(const h8*)&Gb[(size_t)i1 * 256 + cg];
            h8 g2 = *(const h8*)&Gb[(size_t)i2 * 256 + cg];
            h8 hv;
            #pragma unroll
            for (int u = 0; u < 8; u++) {
                float acc = cbv[u];
                acc = fmaf(wq0[u], qx, acc);
                acc = fmaf(wq1[u], qy, acc);
                acc = fmaf(wq2[u], qz, acc);
                acc = fmaf(w0, (float)g0[u], acc);
                acc = fmaf(w1, (float)g1[u], acc);
                acc = fmaf(w2, (float)g2[u], acc);
                hv[u] = (_Float16)fmaxf(acc, 0.f);
            }
            *(h8*)&sH1[j * 264 + cg] = hv;
        }
    }

    // ---- r2: h2(32q x 128ch) = relu(Rw2 @ h1); A-frags straight from sH1 ----
    float h2v[2][2][4];
    {
        v4f acc[2][2];
        #pragma unroll
        for (int i = 0; i < 2; i++)
            #pragma unroll
            for (int j = 0; j < 2; j++)
                acc[i][j] = (v4f){0.f, 0.f, 0.f, 0.f};
        for (int kc = 0; kc < 256; kc += 32) {
            __syncthreads();   // first: sH1 writes; later: sBst reuse
            #pragma unroll
            for (int i = 0; i < 2; i++) {
                int e = t + i * 256;
                int r = e >> 2, p = e & 3;
                *(float4*)&sBst[r * 56 + p * 8] =
                    *(const float4*)&Rw2[(size_t)r * 256 + kc + p * 8];
            }
            __syncthreads();
            h8 af[2], bf[2];
            #pragma unroll
            for (int mt = 0; mt < 2; mt++)
                af[mt] = *(const h8*)&sH1[(mt * 16 + m) * 264 + kc + quad * 8];
            #pragma unroll
            for (int nt = 0; nt < 2; nt++)
                bf[nt] = *(const h8*)&sBst[(w * 32 + nt * 16 + m) * 56 + quad * 8];
            #pragma unroll
            for (int mt = 0; mt < 2; mt++)
                #pragma unroll
                for (int nt = 0; nt < 2; nt++)
                    acc[mt][nt] = __builtin_amdgcn_mfma_f32_16x16x32_f16(
                            af[mt], bf[nt], acc[mt][nt], 0, 0, 0);
        }
        #pragma unroll
        for (int nt = 0; nt < 2; nt++) {
            int ch = w * 32 + nt * 16 + m;
            float bb2 = rb2[ch];
            #pragma unroll
            for (int mt = 0; mt < 2; mt++)
                #pragma unroll
                for (int r = 0; r < 4; r++)
                    h2v[mt][nt][r] = fmaxf(acc[mt][nt][r] + bb2, 0.f);
        }
    }
    __syncthreads();   // all sH1 reads done -> safe to overwrite with sH2
    {
        #pragma unroll
        for (int nt = 0; nt < 2; nt++) {
            int ch = w * 32 + nt * 16 + m;
            #pragma unroll
            for (int mt = 0; mt < 2; mt++)
                #pragma unroll
                for (int r = 0; r < 4; r++) {
                    int ql = mt * 16 + quad * 4 + r;
                    sH2[ql * 136 + ch] = (_Float16)h2v[mt][nt][r];
                }
        }
    }

    // ---- r3: h3(32q x 64ch) = relu(Rw3 @ h2) ----
    float h3v[2][4];
    {
        v4f acc[2];
        #pragma unroll
        for (int i = 0; i < 2; i++) acc[i] = (v4f){0.f, 0.f, 0.f, 0.f};
        for (int kc = 0; kc < 128; kc += 32) {
            __syncthreads();   // first: sH2 writes; later: sW3 reuse
            if (t < 256) {     // 64 rows x 4 segs = 256; 1 per thread
                int r = t >> 2, p = t & 3;
                *(float4*)&sW3[r * 56 + p * 8] =
                    *(const float4*)&Rw3[(size_t)r * 128 + kc + p * 8];
            }
            __syncthreads();
            h8 af[2], bf;
            #pragma unroll
            for (int mt = 0; mt < 2; mt++)
                af[mt] = *(const h8*)&sH2[(mt * 16 + m) * 136 + kc + quad * 8];
            bf = *(const h8*)&sW3[(w * 16 + m) * 56 + quad * 8];
            #pragma unroll
            for (int mt = 0; mt < 2; mt++)
                acc[mt] = __builtin_amdgcn_mfma_f32_16x16x32_f16(
                        af[mt], bf, acc[mt], 0, 0, 0);
        }
        int ch = w * 16 + m;
        float bb3 = rb3[ch];
        #pragma unroll
        for (int mt = 0; mt < 2; mt++)
            #pragma unroll
            for (int r = 0; r < 4; r++)
                h3v[mt][r] = fmaxf(acc[mt][r] + bb3, 0.f);
    }
    __syncthreads();
    {
        int ch = w * 16 + m;
        #pragma unroll
        for (int mt = 0; mt < 2; mt++)
            #pragma unroll
            for (int r = 0; r < 4; r++) {
                int ql = mt * 16 + quad * 4 + r;
                sH3[ch * 72 + ql] = (_Float16)h3v[mt][r];
            }
    }
    __syncthreads();

    // ---- r4: out = r4 . h3 + rb4 ----
    if (t < 32) {
        float acc = rb4[0];
        #pragma unroll 16
        for (int c = 0; c < 64; c++)
            acc = fmaf((float)sH3[c * 72 + t], sw4[c], acc);
        out[q0 + t] = acc;
    }
}

extern "C" void kernel_launch(void* const* d_in, const int* in_sizes, int n_in,
                              void* d_out, int out_size, void* d_ws, size_t ws_size,
                              hipStream_t stream) {
    const float* opts = (const float*)d_in[0];
    const float* qpts = (const float*)d_in[1];
    const float* w1  = (const float*)d_in[2];
    const float* b1  = (const float*)d_in[3];
    const float* w2  = (const float*)d_in[4];
    const float* b2  = (const float*)d_in[5];
    const float* w3  = (const float*)d_in[6];
    const float* b3  = (const float*)d_in[7];
    const float* r1  = (const float*)d_in[8];
    const float* rb1 = (const float*)d_in[9];
    const float* r2  = (const float*)d_in[10];
    const float* rb2 = (const float*)d_in[11];
    const float* r3  = (const float*)d_in[12];
    const float* rb3 = (const float*)d_in[13];
    const float* r4  = (const float*)d_in[14];
    const float* rb4 = (const float*)d_in[15];
    float* out = (float*)d_out;

    unsigned char* p = (unsigned char*)d_ws;
    float* GM = (float*)p;          p += (size_t)NB * 256 * 4;
    float* CB = (float*)p;          p += (size_t)NB * 256 * 4;
    int*   IDX = (int*)p;           p += (size_t)NB * NQ * 3 * 4;
    float* WT = (float*)p;          p += (size_t)NB * NQ * 3 * 4;
    _Float16* Rw1 = (_Float16*)p;   p += (size_t)256 * FCATC * 2;
    _Float16* Rw2 = (_Float16*)p;   p += (size_t)128 * 256 * 2;
    _Float16* Rw3 = (_Float16*)p;   p += (size_t)64 * 128 * 2;
    _Float16* Ew2 = (_Float16*)p;   p += (size_t)128 * 64 * 2;
    _Float16* Ew3 = (_Float16*)p;   p += (size_t)256 * 128 * 2;
    _Float16* Atab = (_Float16*)p;  p += (size_t)NB * NPTS * 16 * 2;
    _Float16* G = (_Float16*)p;     p += (size_t)NB * NPTS * 256 * 2;

    k_pre<<<801, 256, 0, stream>>>(r1, r2, r3, w2, w3, opts,
                                   Rw1, Rw2, Rw3, Ew2, Ew3, Atab, GM);
    // fe: 32 pts/block x 256 blocks (chip-filling; produces G + GM)
    k_fe<<<NB * NPTS / 32, 256, 0, stream>>>(opts, w1, b1, Ew2, b2, Ew3, b3,
                                             Rw1, G, (unsigned*)GM);
    // K=16 MFMA knn, branchless packed-key selection; 1024 blocks x 512 thr
    k_knn<<<1024, 512, 0, stream>>>(opts, qpts, Atab, IDX, WT, r1, rb1, GM, CB);
    // tail: 32 q/block x 1024 blocks (4 blocks/CU)
    k_tail<<<QTOT / 32, 256, 0, stream>>>(qpts, G, CB, IDX, WT, r1,
                                          Rw2, rb2, Rw3, rb3, r4, rb4, out);
}